// Round 1
// baseline (5807.022 us; speedup 1.0000x reference)
//
#include <hip/hip_runtime.h>
#include <stdint.h>
#include <algorithm>

#define BB  32
#define LL  512
#define NCI 21
#define DD  512
#define NH  8
#define EHH 64
#define NDFF 2048
#define NM  32
#define NEL 3
#define NCC 10

struct Modes { int v[NM]; };

__device__ __forceinline__ float gelu_f(float x) {
    return 0.5f * x * (1.0f + erff(x * 0.7071067811865475f));
}

// ---------------- embedding: circular conv1d(k=3) + positional encoding ----------------
__global__ void k_embed(const float* __restrict__ xe, const float* __restrict__ tw,
                        float* __restrict__ X) {
    int lc = blockIdx.x;        // 16 chunks of 32 l's
    int dh = blockIdx.y;        // 0/1
    int b  = blockIdx.z;
    int t  = threadIdx.x;       // 256
    int d  = dh * 256 + t;
    __shared__ float s_xe[34][NCI];
    int l0 = lc * 32;
    for (int i = t; i < 34 * NCI; i += 256) {
        int r = i / NCI, c = i % NCI;
        int ls = (l0 - 1 + r + LL) & (LL - 1);
        s_xe[r][c] = xe[(b * LL + ls) * NCI + c];
    }
    __syncthreads();
    int a = d & ~1;
    float freq = expf((float)a * (-9.210340371976184f / 512.0f)); // exp(-a*ln(1e4)/D)
    for (int li = 0; li < 32; ++li) {
        int l = l0 + li;
        float acc = 0.f;
        #pragma unroll
        for (int k = 0; k < 3; ++k)
            for (int c = 0; c < NCI; ++c)
                acc = fmaf(s_xe[li + k][c], tw[(k * NCI + c) * DD + d], acc);
        float v = (float)l * freq;
        float pe = (d & 1) ? cosf(v) : sinf(v);
        X[((size_t)(b * LL + l)) * DD + d] = acc + pe;
    }
}

// ---------------- generic fp32 tiled GEMM: C = act(A[M,K] @ B[K,N] + bias) ----------------
#define GBM 128
#define GBN 64
#define GBK 16
__global__ __launch_bounds__(256) void k_gemm(const float* __restrict__ A,
        const float* __restrict__ Bm, const float* __restrict__ bias,
        float* __restrict__ C, int M, int N, int K, int act) {
    __shared__ float As[GBK][GBM + 1];
    __shared__ float Bs[GBK][GBN];
    int t = threadIdx.x;
    int m0 = blockIdx.x * GBM;
    int n0 = blockIdx.y * GBN;
    int tr = t >> 4, tc = t & 15;
    int ar = t >> 2, aq = t & 3;
    int bkr = t >> 4, bnq = t & 15;
    float acc[8][4] = {};
    for (int k0 = 0; k0 < K; k0 += GBK) {
        float4 a0 = *(const float4*)&A[(size_t)(m0 + ar) * K + k0 + aq * 4];
        float4 a1 = *(const float4*)&A[(size_t)(m0 + ar + 64) * K + k0 + aq * 4];
        float4 bv = *(const float4*)&Bm[(size_t)(k0 + bkr) * N + n0 + bnq * 4];
        As[aq * 4 + 0][ar] = a0.x; As[aq * 4 + 1][ar] = a0.y;
        As[aq * 4 + 2][ar] = a0.z; As[aq * 4 + 3][ar] = a0.w;
        As[aq * 4 + 0][ar + 64] = a1.x; As[aq * 4 + 1][ar + 64] = a1.y;
        As[aq * 4 + 2][ar + 64] = a1.z; As[aq * 4 + 3][ar + 64] = a1.w;
        *(float4*)&Bs[bkr][bnq * 4] = bv;
        __syncthreads();
        #pragma unroll
        for (int kk = 0; kk < GBK; ++kk) {
            float av[8], bb[4];
            #pragma unroll
            for (int j = 0; j < 8; ++j) av[j] = As[kk][tr * 8 + j];
            #pragma unroll
            for (int i = 0; i < 4; ++i) bb[i] = Bs[kk][tc * 4 + i];
            #pragma unroll
            for (int j = 0; j < 8; ++j)
                #pragma unroll
                for (int i = 0; i < 4; ++i)
                    acc[j][i] = fmaf(av[j], bb[i], acc[j][i]);
        }
        __syncthreads();
    }
    #pragma unroll
    for (int j = 0; j < 8; ++j) {
        int row = m0 + tr * 8 + j;
        #pragma unroll
        for (int i = 0; i < 4; ++i) {
            int col = n0 + tc * 4 + i;
            float v = acc[j][i];
            if (bias) v += bias[col];
            if (act) v = gelu_f(v);
            C[(size_t)row * N + col] = v;
        }
    }
}

// ---------------- DFT: xg[b,h,e,m] = sum_l q[b,l,(h,e)] * exp(-2pi i * idx[m] * l / L) ----
__global__ void k_dft(const float* __restrict__ Q, float* __restrict__ XGr,
                      float* __restrict__ XGi, Modes mi) {
    int bd = blockIdx.x;            // b*512 + d, d = h*64+e
    int t = threadIdx.x;            // 64
    __shared__ float s_q[LL];
    __shared__ float s_sin[LL];
    int b = bd >> 9, d = bd & 511;
    const float w0 = 6.283185307179586f / 512.0f;
    for (int i = t; i < LL; i += 64) {
        s_q[i] = Q[((size_t)(b * LL + i)) * DD + d];
        s_sin[i] = sinf(w0 * (float)i);
    }
    __syncthreads();
    int m = t >> 1, part = t & 1;
    int im = mi.v[m];
    float acc = 0.f;
    int r = 0;
    for (int l = 0; l < LL; ++l) {
        int rr = part ? r : ((r + 128) & 511);   // cos(x)=sin(x+pi/2)
        acc = fmaf(s_q[l], s_sin[rr], acc);
        r = (r + im) & 511;
    }
    if (part) acc = -acc;                        // rfft imag = -sum q sin
    int off = bd * NM + m;
    if (part) XGi[off] = acc; else XGr[off] = acc;
}

// ---------------- og[b,h,o,m] = sum_e xg[b,h,e,m] * (fwr+i*fwi)[h,e,o,m] -----------------
__global__ void k_og(const float* __restrict__ XGr, const float* __restrict__ XGi,
                     const float* __restrict__ fwr, const float* __restrict__ fwi,
                     float* __restrict__ OGr, float* __restrict__ OGi, int li) {
    int id = blockIdx.x;            // (b*8+h)*32 + m
    int m = id & 31, bh = id >> 5, h = bh & 7;
    int t = threadIdx.x;            // o
    __shared__ float sr[EHH], si[EHH];
    sr[t] = XGr[(bh * EHH + t) * NM + m];
    si[t] = XGi[(bh * EHH + t) * NM + m];
    __syncthreads();
    const float* wr = fwr + ((size_t)(li * NH + h)) * EHH * EHH * NM;
    const float* wi = fwi + ((size_t)(li * NH + h)) * EHH * EHH * NM;
    float ar = 0.f, ai = 0.f;
    for (int e = 0; e < EHH; ++e) {
        float wrv = wr[(e * EHH + t) * NM + m];
        float wiv = wi[(e * EHH + t) * NM + m];
        ar = fmaf(sr[e], wrv, fmaf(-si[e], wiv, ar));
        ai = fmaf(sr[e], wiv, fmaf( si[e], wrv, ai));
    }
    OGr[(bh * EHH + t) * NM + m] = ar;
    OGi[(bh * EHH + t) * NM + m] = ai;
}

// ---------------- irfft with dense 32-bin prefix; Im(bin0) dropped ------------------------
__global__ void k_irfft(const float* __restrict__ OGr, const float* __restrict__ OGi,
                        float* __restrict__ O) {
    int bi = blockIdx.x;            // b*512 + (h*64+o)
    int t = threadIdx.x;            // 64
    __shared__ float gr[NM], gi[NM], s_sin[LL];
    if (t < NM) { gr[t] = OGr[bi * NM + t]; gi[t] = OGi[bi * NM + t]; }
    const float w0 = 6.283185307179586f / 512.0f;
    for (int i = t; i < LL; i += 64) s_sin[i] = sinf(w0 * (float)i);
    __syncthreads();
    for (int l = t; l < LL; l += 64) {
        float acc = gr[0];
        #pragma unroll
        for (int m = 1; m < NM; ++m) {
            int r = (m * l) & 511;
            acc += 2.f * (gr[m] * s_sin[(r + 128) & 511] - gi[m] * s_sin[r]);
        }
        O[(size_t)bi * LL + l] = acc * (1.0f / 512.0f);
    }
}

// ---------------- s = P + Q;  out = s - movavg25(s, edge-replicated) ---------------------
__global__ void k_add_decomp(const float* __restrict__ P, const float* __restrict__ Q,
                             float* __restrict__ Out) {
    int tid = blockIdx.x * blockDim.x + threadIdx.x;  // 16384 = B*D
    int b = tid >> 9, d = tid & 511;
    const float* p = P + (size_t)b * LL * DD + d;
    const float* q = Q + (size_t)b * LL * DD + d;
    float* o = Out + (size_t)b * LL * DD + d;
    float s0 = p[0] + q[0];
    float sum = 13.f * s0;
    for (int j = 1; j <= 12; ++j) sum += p[j * DD] + q[j * DD];
    for (int l = 0; l < LL; ++l) {
        if (l >= 1) {
            int lp = l + 12 > 511 ? 511 : l + 12;
            int lm = l - 13 < 0 ? 0 : l - 13;
            sum += (p[lp * DD] + q[lp * DD]) - (p[lm * DD] + q[lm * DD]);
        }
        float sv = p[l * DD] + q[l * DD];
        o[l * DD] = sv - sum * (1.0f / 25.0f);
    }
}

// ---------------- LayerNorm over D ----------------
__global__ void k_ln(const float* __restrict__ Xin, const float* __restrict__ lw,
                     const float* __restrict__ lb, float* __restrict__ Out) {
    int row = blockIdx.x;
    int t = threadIdx.x;  // 64
    const float4* x4 = (const float4*)(Xin + (size_t)row * DD);
    float4 v0 = x4[t], v1 = x4[t + 64];
    float s = v0.x + v0.y + v0.z + v0.w + v1.x + v1.y + v1.z + v1.w;
    #pragma unroll
    for (int o = 32; o; o >>= 1) s += __shfl_down(s, o);
    float mu = __shfl(s, 0) * (1.0f / 512.0f);
    float d0 = v0.x - mu, d1 = v0.y - mu, d2 = v0.z - mu, d3 = v0.w - mu;
    float d4 = v1.x - mu, d5 = v1.y - mu, d6 = v1.z - mu, d7 = v1.w - mu;
    float vs = d0*d0 + d1*d1 + d2*d2 + d3*d3 + d4*d4 + d5*d5 + d6*d6 + d7*d7;
    #pragma unroll
    for (int o = 32; o; o >>= 1) vs += __shfl_down(vs, o);
    float var = __shfl(vs, 0) * (1.0f / 512.0f);
    float rstd = rsqrtf(var + 1e-5f);
    float4 w0 = ((const float4*)lw)[t], w1 = ((const float4*)lw)[t + 64];
    float4 b0 = ((const float4*)lb)[t], b1 = ((const float4*)lb)[t + 64];
    float4 r0, r1;
    r0.x = d0 * rstd * w0.x + b0.x; r0.y = d1 * rstd * w0.y + b0.y;
    r0.z = d2 * rstd * w0.z + b0.z; r0.w = d3 * rstd * w0.w + b0.w;
    r1.x = d4 * rstd * w1.x + b1.x; r1.y = d5 * rstd * w1.y + b1.y;
    r1.z = d6 * rstd * w1.z + b1.z; r1.w = d7 * rstd * w1.w + b1.w;
    float4* o4 = (float4*)(Out + (size_t)row * DD);
    o4[t] = r0; o4[t + 64] = r1;
}

// ---------------- column (temporal) mean over L per (b,d) ----------------
__global__ void k_colmean(const float* __restrict__ A, float* __restrict__ CM) {
    int tid = blockIdx.x * blockDim.x + threadIdx.x;  // 16384
    int b = tid >> 9, d = tid & 511;
    const float* a = A + (size_t)b * LL * DD + d;
    float s = 0.f;
    for (int l = 0; l < LL; ++l) s += a[l * DD];
    CM[tid] = s * (1.0f / 512.0f);
}

__global__ void k_gelu_sub(float* __restrict__ A, const float* __restrict__ CM) {
    int i = blockIdx.x * 256 + threadIdx.x;     // 8388608 total
    int b = i >> 18, d = i & 511;
    float v = A[i] - CM[(b << 9) | d];
    A[i] = gelu_f(v);
}

// ---------------- final projection [B, L*D] @ [L*D, 10] ----------------
__global__ __launch_bounds__(256) void k_proj_partial(const float* __restrict__ A,
        const float* __restrict__ PW, float* __restrict__ PP) {
    int b = blockIdx.x, c = blockIdx.y;
    int t = threadIdx.x;
    float acc[NCC] = {};
    const float* a = A + (size_t)b * LL * DD;
    int i0 = c * 16384, i1 = i0 + 16384;
    for (int i = i0 + t; i < i1; i += 256) {
        float v = a[i];
        const float* w = PW + (size_t)i * NCC;
        #pragma unroll
        for (int n = 0; n < NCC; ++n) acc[n] = fmaf(v, w[n], acc[n]);
    }
    __shared__ float red[4][NCC];
    int lane = t & 63, wv = t >> 6;
    #pragma unroll
    for (int n = 0; n < NCC; ++n) {
        float s = acc[n];
        #pragma unroll
        for (int o = 32; o; o >>= 1) s += __shfl_down(s, o);
        if (lane == 0) red[wv][n] = s;
    }
    __syncthreads();
    if (t < NCC) {
        PP[(b * 16 + c) * NCC + t] = red[0][t] + red[1][t] + red[2][t] + red[3][t];
    }
}

__global__ void k_proj_final(const float* __restrict__ PP, const float* __restrict__ pb,
                             float* __restrict__ out) {
    int t = threadIdx.x;
    if (t >= BB * NCC) return;
    int b = t / NCC, n = t % NCC;
    float s = pb[n];
    for (int c = 0; c < 16; ++c) s += PP[(b * 16 + c) * NCC + n];
    out[t] = s;
}

// ---------------- numpy legacy RandomState(0) modes replication ----------------
static void compute_modes(int* out) {
    static uint32_t mt[624];
    uint32_t s = 0u;
    mt[0] = s;
    for (int i = 1; i < 624; ++i)
        mt[i] = 1812433253u * (mt[i - 1] ^ (mt[i - 1] >> 30)) + (uint32_t)i;
    int mti = 624;
    auto genrand = [&]() -> uint32_t {
        if (mti >= 624) {
            for (int k = 0; k < 624; ++k) {
                uint32_t y = (mt[k] & 0x80000000u) | (mt[(k + 1) % 624] & 0x7fffffffu);
                mt[k] = mt[(k + 397) % 624] ^ (y >> 1) ^ ((y & 1u) ? 2567483615u : 0u);
            }
            mti = 0;
        }
        uint32_t y = mt[mti++];
        y ^= y >> 11;
        y ^= (y << 7) & 2636928640u;
        y ^= (y << 15) & 4022730752u;
        y ^= y >> 18;
        return y;
    };
    int idx[256];
    for (int i = 0; i < 256; ++i) idx[i] = i;
    for (int i = 255; i >= 1; --i) {
        uint32_t mx = (uint32_t)i;
        uint32_t mask = mx;
        mask |= mask >> 1; mask |= mask >> 2; mask |= mask >> 4;
        mask |= mask >> 8; mask |= mask >> 16;
        uint32_t j;
        while ((j = (genrand() & mask)) > mx) {}
        int tmp = idx[i]; idx[i] = idx[j]; idx[j] = tmp;
    }
    int sel[NM];
    for (int i = 0; i < NM; ++i) sel[i] = idx[i];
    std::sort(sel, sel + NM);
    for (int i = 0; i < NM; ++i) out[i] = sel[i];
}

extern "C" void kernel_launch(void* const* d_in, const int* in_sizes, int n_in,
                              void* d_out, int out_size, void* d_ws, size_t ws_size,
                              hipStream_t stream) {
    const float* xe  = (const float*)d_in[0];
    const float* tw  = (const float*)d_in[1];
    const float* Wq  = (const float*)d_in[2];
    const float* bq  = (const float*)d_in[3];
    // d_in[4..7]: Wk,bk,Wv,bv — computed-but-unused in reference; skipped.
    const float* Wo  = (const float*)d_in[8];
    const float* bo  = (const float*)d_in[9];
    const float* fwr = (const float*)d_in[10];
    const float* fwi = (const float*)d_in[11];
    const float* W1  = (const float*)d_in[12];
    const float* W2  = (const float*)d_in[13];
    const float* lw  = (const float*)d_in[14];
    const float* lb  = (const float*)d_in[15];
    const float* pw  = (const float*)d_in[16];
    const float* pb  = (const float*)d_in[17];
    float* out = (float*)d_out;

    const size_t NX = (size_t)BB * LL * DD;        // 8388608
    const size_t NH_ = (size_t)BB * LL * NDFF;     // 33554432
    const size_t NXG = (size_t)BB * NH * EHH * NM; // 524288
    float* ws = (float*)d_ws;
    float* X1 = ws;
    float* X2 = X1 + NX;
    float* TB = X2 + NX;
    float* HM = TB + NX;           // also reused as irfft output O (first NX floats)
    float* XGr = HM + NH_;
    float* XGi = XGr + NXG;
    float* OGr = XGi + NXG;
    float* OGi = OGr + NXG;
    size_t need = (size_t)(OGi + NXG - ws) * sizeof(float);
    if (ws_size < need) return;    // insufficient workspace; avoid OOB

    Modes mi;
    compute_modes(mi.v);

    k_embed<<<dim3(16, 2, BB), 256, 0, stream>>>(xe, tw, X1);

    float* cur = X1;
    float* alt = X2;
    for (int li = 0; li < NEL; ++li) {
        // q projection
        k_gemm<<<dim3(128, 8), 256, 0, stream>>>(cur, Wq + (size_t)li * DD * DD,
                                                 bq + li * DD, TB, BB * LL, DD, DD, 0);
        // 32-mode DFT over time
        k_dft<<<BB * DD, 64, 0, stream>>>(TB, XGr, XGi, mi);
        // per-mode complex matmul
        k_og<<<BB * NH * NM, EHH, 0, stream>>>(XGr, XGi, fwr, fwi, OGr, OGi, li);
        // irfft (dense 32-bin prefix) -> O stored [B, (h,e), L] in HM
        k_irfft<<<BB * DD, 64, 0, stream>>>(OGr, OGi, HM);
        // new_x = O @ Wo + bo   (rows are (h,e), contraction over l)
        k_gemm<<<dim3(128, 8), 256, 0, stream>>>(HM, Wo + (size_t)li * DD * DD,
                                                 bo + li * DD, TB, BB * LL, DD, DD, 0);
        // x = decomp(x + new_x)
        k_add_decomp<<<64, 256, 0, stream>>>(cur, TB, alt);
        { float* t_ = cur; cur = alt; alt = t_; }
        // FFN
        k_gemm<<<dim3(128, 32), 256, 0, stream>>>(cur, W1 + (size_t)li * DD * NDFF,
                                                  nullptr, HM, BB * LL, NDFF, DD, 1);
        k_gemm<<<dim3(128, 8), 256, 0, stream>>>(HM, W2 + (size_t)li * NDFF * DD,
                                                 nullptr, TB, BB * LL, DD, NDFF, 0);
        k_add_decomp<<<64, 256, 0, stream>>>(cur, TB, alt);
        { float* t_ = cur; cur = alt; alt = t_; }
    }

    // final: LayerNorm -> subtract temporal mean -> gelu -> projection
    k_ln<<<BB * LL, 64, 0, stream>>>(cur, lw, lb, TB);
    float* CM = XGr;   // reuse
    float* PP = XGi;   // reuse
    k_colmean<<<64, 256, 0, stream>>>(TB, CM);
    k_gelu_sub<<<32768, 256, 0, stream>>>(TB, CM);
    k_proj_partial<<<dim3(BB, 16), 256, 0, stream>>>(TB, pw, PP);
    k_proj_final<<<1, 320, 0, stream>>>(PP, pb, out);
}

// Round 2
// 2262.769 us; speedup vs baseline: 2.5663x; 2.5663x over previous
//
#include <hip/hip_runtime.h>
#include <hip/hip_bf16.h>
#include <stdint.h>
#include <algorithm>

#define BB  32
#define LL  512
#define NCI 21
#define DD  512
#define NH  8
#define EHH 64
#define NDFF 2048
#define NM  32
#define NEL 3
#define NCC 10

struct Modes { int v[NM]; };

typedef __bf16 bf16x8 __attribute__((ext_vector_type(8)));
typedef float f32x4 __attribute__((ext_vector_type(4)));

__device__ __forceinline__ float gelu_f(float x) {
    return 0.5f * x * (1.0f + erff(x * 0.7071067811865475f));
}

__device__ __forceinline__ void gload_lds16(const void* g, void* l) {
    __builtin_amdgcn_global_load_lds((const __attribute__((address_space(1))) void*)g,
                                     (__attribute__((address_space(3))) void*)l, 16, 0, 0);
}

// ---------------- embedding: circular conv1d(k=3) + positional encoding (dual write) -----
__global__ void k_embed(const float* __restrict__ xe, const float* __restrict__ tw,
                        float* __restrict__ X, __hip_bfloat16* __restrict__ Xb) {
    int lc = blockIdx.x;        // 16 chunks of 32 l's
    int dh = blockIdx.y;        // 0/1
    int b  = blockIdx.z;
    int t  = threadIdx.x;       // 256
    int d  = dh * 256 + t;
    __shared__ float s_xe[34][NCI];
    int l0 = lc * 32;
    for (int i = t; i < 34 * NCI; i += 256) {
        int r = i / NCI, c = i % NCI;
        int ls = (l0 - 1 + r + LL) & (LL - 1);
        s_xe[r][c] = xe[(b * LL + ls) * NCI + c];
    }
    __syncthreads();
    int a = d & ~1;
    float freq = expf((float)a * (-9.210340371976184f / 512.0f));
    for (int li = 0; li < 32; ++li) {
        int l = l0 + li;
        float acc = 0.f;
        #pragma unroll
        for (int k = 0; k < 3; ++k)
            for (int c = 0; c < NCI; ++c)
                acc = fmaf(s_xe[li + k][c], tw[(k * NCI + c) * DD + d], acc);
        float v = (float)l * freq;
        float pe = (d & 1) ? cosf(v) : sinf(v);
        float r = acc + pe;
        size_t off = ((size_t)(b * LL + l)) * DD + d;
        X[off] = r;
        Xb[off] = __float2bfloat16(r);
    }
}

// ---------------- weight convert+transpose: W[K][N] fp32 -> WT[N][K] bf16 ----------------
__global__ void k_wt(const float* __restrict__ W, __hip_bfloat16* __restrict__ WT,
                     int K, int N) {
    __shared__ float s[32][33];
    int bx = blockIdx.x;   // along N
    int by = blockIdx.y;   // along K
    int t = threadIdx.x;   // 256
    int r = t >> 5, c = t & 31;
    #pragma unroll
    for (int i = 0; i < 4; ++i)
        s[r + i * 8][c] = W[(size_t)(by * 32 + r + i * 8) * N + bx * 32 + c];
    __syncthreads();
    #pragma unroll
    for (int i = 0; i < 4; ++i) {
        int n = bx * 32 + r + i * 8;
        WT[(size_t)n * K + by * 32 + c] = __float2bfloat16(s[c][r + i * 8]);
    }
}

// ---------------- bf16 MFMA GEMM: C = epi(A[M,K] @ Bt[N,K]^T + bias) ---------------------
// m97 structure: 128x128 tile, BK=32, 256 thr (4 waves, 2x2), 4x4 16x16x32 frags/wave.
// EPI: 0 = +bias, fp32 out; 1 = gelu, bf16 out; 2 = plain fp32 out
template<int EPI>
__global__ __launch_bounds__(256) void k_mm(const __hip_bfloat16* __restrict__ A,
        const __hip_bfloat16* __restrict__ Bt, const float* __restrict__ bias,
        float* __restrict__ C, __hip_bfloat16* __restrict__ Cb, int M, int N, int K) {
    __shared__ __hip_bfloat16 As[128 * 32];
    __shared__ __hip_bfloat16 Bs[128 * 32];
    int t = threadIdx.x;
    int m0 = blockIdx.x * 128, n0 = blockIdx.y * 128;
    int w = t >> 6, ln = t & 63;
    int wr = w >> 1, wc = w & 1;
    f32x4 acc[4][4] = {};
    for (int k0 = 0; k0 < K; k0 += 32) {
        #pragma unroll
        for (int i = 0; i < 2; ++i) {
            int s = i * 256 + t;
            int row = s >> 2, q = s & 3;
            const __hip_bfloat16* ga = A + (size_t)(m0 + row) * K + k0 + q * 8;
            const __hip_bfloat16* gb = Bt + (size_t)(n0 + row) * K + k0 + q * 8;
            char* la = (char*)As + i * 4096 + w * 1024;
            char* lb = (char*)Bs + i * 4096 + w * 1024;
            gload_lds16(ga, la);
            gload_lds16(gb, lb);
        }
        __syncthreads();
        bf16x8 af[4], bfr[4];
        int lr = ln & 15, kc = (ln >> 4) * 8;
        #pragma unroll
        for (int mi = 0; mi < 4; ++mi)
            af[mi] = *(const bf16x8*)&As[(wr * 64 + mi * 16 + lr) * 32 + kc];
        #pragma unroll
        for (int ni = 0; ni < 4; ++ni)
            bfr[ni] = *(const bf16x8*)&Bs[(wc * 64 + ni * 16 + lr) * 32 + kc];
        #pragma unroll
        for (int mi = 0; mi < 4; ++mi)
            #pragma unroll
            for (int ni = 0; ni < 4; ++ni)
                acc[mi][ni] = __builtin_amdgcn_mfma_f32_16x16x32_bf16(
                    af[mi], bfr[ni], acc[mi][ni], 0, 0, 0);
        __syncthreads();
    }
    int rb = (ln >> 4) * 4, cb = ln & 15;
    #pragma unroll
    for (int mi = 0; mi < 4; ++mi) {
        #pragma unroll
        for (int ni = 0; ni < 4; ++ni) {
            int col = n0 + wc * 64 + ni * 16 + cb;
            int rowb = m0 + wr * 64 + mi * 16 + rb;
            float bv = (EPI == 0) ? bias[col] : 0.f;
            #pragma unroll
            for (int j = 0; j < 4; ++j) {
                float v = acc[mi][ni][j] + bv;
                size_t off = (size_t)(rowb + j) * N + col;
                if (EPI == 1) Cb[off] = __float2bfloat16(gelu_f(v));
                else C[off] = v;
            }
        }
    }
}

// ---------------- DFT: xg[b,h,e,m] = sum_l q[b,l,(h,e)] * exp(-2pi i * idx[m] * l / L) ----
__global__ void k_dft(const float* __restrict__ Q, float* __restrict__ XGr,
                      float* __restrict__ XGi, Modes mi) {
    int bd = blockIdx.x;            // b*512 + d
    int t = threadIdx.x;            // 64
    __shared__ float s_q[LL];
    __shared__ float s_sin[LL];
    int b = bd >> 9, d = bd & 511;
    const float w0 = 6.283185307179586f / 512.0f;
    for (int i = t; i < LL; i += 64) {
        s_q[i] = Q[((size_t)(b * LL + i)) * DD + d];
        s_sin[i] = sinf(w0 * (float)i);
    }
    __syncthreads();
    int m = t >> 1, part = t & 1;
    int im = mi.v[m];
    float acc = 0.f;
    int r = 0;
    for (int l = 0; l < LL; ++l) {
        int rr = part ? r : ((r + 128) & 511);
        acc = fmaf(s_q[l], s_sin[rr], acc);
        r = (r + im) & 511;
    }
    if (part) acc = -acc;
    int off = bd * NM + m;
    if (part) XGi[off] = acc; else XGr[off] = acc;
}

// ---------------- og[b,h,o,m] = sum_e xg[b,h,e,m] * (fwr+i*fwi)[h,e,o,m] -----------------
__global__ void k_og(const float* __restrict__ XGr, const float* __restrict__ XGi,
                     const float* __restrict__ fwr, const float* __restrict__ fwi,
                     float* __restrict__ OGr, float* __restrict__ OGi, int li) {
    int id = blockIdx.x;            // (b*8+h)*32 + m
    int m = id & 31, bh = id >> 5, h = bh & 7;
    int t = threadIdx.x;            // o = 64
    __shared__ float sr[EHH], si[EHH];
    sr[t] = XGr[(bh * EHH + t) * NM + m];
    si[t] = XGi[(bh * EHH + t) * NM + m];
    __syncthreads();
    const float* wr = fwr + ((size_t)(li * NH + h)) * EHH * EHH * NM;
    const float* wi = fwi + ((size_t)(li * NH + h)) * EHH * EHH * NM;
    float ar = 0.f, ai = 0.f;
    for (int e = 0; e < EHH; ++e) {
        float wrv = wr[(e * EHH + t) * NM + m];
        float wiv = wi[(e * EHH + t) * NM + m];
        ar = fmaf(sr[e], wrv, fmaf(-si[e], wiv, ar));
        ai = fmaf(sr[e], wiv, fmaf( si[e], wrv, ai));
    }
    OGr[(bh * EHH + t) * NM + m] = ar;
    OGi[(bh * EHH + t) * NM + m] = ai;
}

// ---------------- irfft with dense 32-bin prefix; Im(bin0) dropped; bf16 out -------------
__global__ void k_irfft(const float* __restrict__ OGr, const float* __restrict__ OGi,
                        __hip_bfloat16* __restrict__ O) {
    int bi = blockIdx.x;            // b*512 + (h*64+o)
    int t = threadIdx.x;            // 64
    __shared__ float gr[NM], gi[NM], s_sin[LL];
    if (t < NM) { gr[t] = OGr[bi * NM + t]; gi[t] = OGi[bi * NM + t]; }
    const float w0 = 6.283185307179586f / 512.0f;
    for (int i = t; i < LL; i += 64) s_sin[i] = sinf(w0 * (float)i);
    __syncthreads();
    for (int l = t; l < LL; l += 64) {
        float acc = gr[0];
        #pragma unroll
        for (int m = 1; m < NM; ++m) {
            int r = (m * l) & 511;
            acc += 2.f * (gr[m] * s_sin[(r + 128) & 511] - gi[m] * s_sin[r]);
        }
        O[(size_t)bi * LL + l] = __float2bfloat16(acc * (1.0f / 512.0f));
    }
}

// ---------------- s = P + Q; out = s - movavg25(s); dual fp32+bf16, L-chunked ------------
__global__ void k_add_decomp(const float* __restrict__ P, const float* __restrict__ Q,
                             float* __restrict__ Out, __hip_bfloat16* __restrict__ Outb) {
    int b = blockIdx.x >> 3;
    int l0 = (blockIdx.x & 7) * 64;
    int d = threadIdx.x;            // 512
    const float* p = P + (size_t)b * LL * DD + d;
    const float* q = Q + (size_t)b * LL * DD + d;
    float* o = Out + (size_t)b * LL * DD + d;
    __hip_bfloat16* ob = Outb + (size_t)b * LL * DD + d;
    float sum = 0.f;
    for (int j = l0 - 12; j <= l0 + 12; ++j) {
        int jc = j < 0 ? 0 : (j > 511 ? 511 : j);
        sum += p[jc * DD] + q[jc * DD];
    }
    for (int l = l0; l < l0 + 64; ++l) {
        float sv = p[l * DD] + q[l * DD];
        float r = sv - sum * (1.0f / 25.0f);
        o[l * DD] = r;
        ob[l * DD] = __float2bfloat16(r);
        int lp = l + 13 > 511 ? 511 : l + 13;
        int lm = l - 12 < 0 ? 0 : l - 12;
        sum += (p[lp * DD] + q[lp * DD]) - (p[lm * DD] + q[lm * DD]);
    }
}

// ---------------- LayerNorm over D ----------------
__global__ void k_ln(const float* __restrict__ Xin, const float* __restrict__ lw,
                     const float* __restrict__ lb, float* __restrict__ Out) {
    int row = blockIdx.x;
    int t = threadIdx.x;  // 64
    const float4* x4 = (const float4*)(Xin + (size_t)row * DD);
    float4 v0 = x4[t], v1 = x4[t + 64];
    float s = v0.x + v0.y + v0.z + v0.w + v1.x + v1.y + v1.z + v1.w;
    #pragma unroll
    for (int o = 32; o; o >>= 1) s += __shfl_down(s, o);
    float mu = __shfl(s, 0) * (1.0f / 512.0f);
    float d0 = v0.x - mu, d1 = v0.y - mu, d2 = v0.z - mu, d3 = v0.w - mu;
    float d4 = v1.x - mu, d5 = v1.y - mu, d6 = v1.z - mu, d7 = v1.w - mu;
    float vs = d0*d0 + d1*d1 + d2*d2 + d3*d3 + d4*d4 + d5*d5 + d6*d6 + d7*d7;
    #pragma unroll
    for (int o = 32; o; o >>= 1) vs += __shfl_down(vs, o);
    float var = __shfl(vs, 0) * (1.0f / 512.0f);
    float rstd = rsqrtf(var + 1e-5f);
    float4 w0 = ((const float4*)lw)[t], w1 = ((const float4*)lw)[t + 64];
    float4 b0 = ((const float4*)lb)[t], b1 = ((const float4*)lb)[t + 64];
    float4 r0, r1;
    r0.x = d0 * rstd * w0.x + b0.x; r0.y = d1 * rstd * w0.y + b0.y;
    r0.z = d2 * rstd * w0.z + b0.z; r0.w = d3 * rstd * w0.w + b0.w;
    r1.x = d4 * rstd * w1.x + b1.x; r1.y = d5 * rstd * w1.y + b1.y;
    r1.z = d6 * rstd * w1.z + b1.z; r1.w = d7 * rstd * w1.w + b1.w;
    float4* o4 = (float4*)(Out + (size_t)row * DD);
    o4[t] = r0; o4[t + 64] = r1;
}

// ---------------- column (temporal) mean over L per (b,d) ----------------
__global__ void k_colmean(const float* __restrict__ A, float* __restrict__ CM) {
    int tid = blockIdx.x * blockDim.x + threadIdx.x;  // 16384
    int b = tid >> 9, d = tid & 511;
    const float* a = A + (size_t)b * LL * DD + d;
    float s = 0.f;
    for (int l = 0; l < LL; ++l) s += a[l * DD];
    CM[tid] = s * (1.0f / 512.0f);
}

__global__ void k_gelu_sub(float* __restrict__ A, const float* __restrict__ CM) {
    int i = blockIdx.x * 256 + threadIdx.x;
    int b = i >> 18, d = i & 511;
    float v = A[i] - CM[(b << 9) | d];
    A[i] = gelu_f(v);
}

// ---------------- final projection [B, L*D] @ [L*D, 10] ----------------
__global__ __launch_bounds__(256) void k_proj_partial(const float* __restrict__ A,
        const float* __restrict__ PW, float* __restrict__ PP) {
    int b = blockIdx.x, c = blockIdx.y;
    int t = threadIdx.x;
    float acc[NCC] = {};
    const float* a = A + (size_t)b * LL * DD;
    int i0 = c * 16384, i1 = i0 + 16384;
    for (int i = i0 + t; i < i1; i += 256) {
        float v = a[i];
        const float* w = PW + (size_t)i * NCC;
        #pragma unroll
        for (int n = 0; n < NCC; ++n) acc[n] = fmaf(v, w[n], acc[n]);
    }
    __shared__ float red[4][NCC];
    int lane = t & 63, wv = t >> 6;
    #pragma unroll
    for (int n = 0; n < NCC; ++n) {
        float s = acc[n];
        #pragma unroll
        for (int o = 32; o; o >>= 1) s += __shfl_down(s, o);
        if (lane == 0) red[wv][n] = s;
    }
    __syncthreads();
    if (t < NCC) {
        PP[(b * 16 + c) * NCC + t] = red[0][t] + red[1][t] + red[2][t] + red[3][t];
    }
}

__global__ void k_proj_final(const float* __restrict__ PP, const float* __restrict__ pb,
                             float* __restrict__ out) {
    int t = threadIdx.x;
    if (t >= BB * NCC) return;
    int b = t / NCC, n = t % NCC;
    float s = pb[n];
    for (int c = 0; c < 16; ++c) s += PP[(b * 16 + c) * NCC + n];
    out[t] = s;
}

// ---------------- numpy legacy RandomState(0) modes replication ----------------
static void compute_modes(int* out) {
    static uint32_t mt[624];
    uint32_t s = 0u;
    mt[0] = s;
    for (int i = 1; i < 624; ++i)
        mt[i] = 1812433253u * (mt[i - 1] ^ (mt[i - 1] >> 30)) + (uint32_t)i;
    int mti = 624;
    auto genrand = [&]() -> uint32_t {
        if (mti >= 624) {
            for (int k = 0; k < 624; ++k) {
                uint32_t y = (mt[k] & 0x80000000u) | (mt[(k + 1) % 624] & 0x7fffffffu);
                mt[k] = mt[(k + 397) % 624] ^ (y >> 1) ^ ((y & 1u) ? 2567483615u : 0u);
            }
            mti = 0;
        }
        uint32_t y = mt[mti++];
        y ^= y >> 11;
        y ^= (y << 7) & 2636928640u;
        y ^= (y << 15) & 4022730752u;
        y ^= y >> 18;
        return y;
    };
    int idx[256];
    for (int i = 0; i < 256; ++i) idx[i] = i;
    for (int i = 255; i >= 1; --i) {
        uint32_t mx = (uint32_t)i;
        uint32_t mask = mx;
        mask |= mask >> 1; mask |= mask >> 2; mask |= mask >> 4;
        mask |= mask >> 8; mask |= mask >> 16;
        uint32_t j;
        while ((j = (genrand() & mask)) > mx) {}
        int tmp = idx[i]; idx[i] = idx[j]; idx[j] = tmp;
    }
    int sel[NM];
    for (int i = 0; i < NM; ++i) sel[i] = idx[i];
    std::sort(sel, sel + NM);
    for (int i = 0; i < NM; ++i) out[i] = sel[i];
}

extern "C" void kernel_launch(void* const* d_in, const int* in_sizes, int n_in,
                              void* d_out, int out_size, void* d_ws, size_t ws_size,
                              hipStream_t stream) {
    const float* xe  = (const float*)d_in[0];
    const float* tw  = (const float*)d_in[1];
    const float* Wq  = (const float*)d_in[2];
    const float* bq  = (const float*)d_in[3];
    const float* Wo  = (const float*)d_in[8];
    const float* bo  = (const float*)d_in[9];
    const float* fwr = (const float*)d_in[10];
    const float* fwi = (const float*)d_in[11];
    const float* W1  = (const float*)d_in[12];
    const float* W2  = (const float*)d_in[13];
    const float* lw  = (const float*)d_in[14];
    const float* lb  = (const float*)d_in[15];
    const float* pw  = (const float*)d_in[16];
    const float* pb  = (const float*)d_in[17];
    float* out = (float*)d_out;

    const size_t NX = (size_t)BB * LL * DD;        // 8388608
    const size_t NHF = (size_t)BB * LL * NDFF;     // 33554432
    const size_t NXG = (size_t)BB * NH * EHH * NM; // 524288
    const size_t NWT = (size_t)NDFF * DD;          // 1048576 (max weight elems)

    char* wsb = (char*)d_ws;
    size_t off = 0;
    float* X1  = (float*)(wsb + off); off += NX * 4;
    float* X2  = (float*)(wsb + off); off += NX * 4;
    float* TB  = (float*)(wsb + off); off += NX * 4;
    float* XGr = (float*)(wsb + off); off += NXG * 4;
    float* XGi = (float*)(wsb + off); off += NXG * 4;
    float* OGr = (float*)(wsb + off); off += NXG * 4;
    float* OGi = (float*)(wsb + off); off += NXG * 4;
    __hip_bfloat16* X1b = (__hip_bfloat16*)(wsb + off); off += NX * 2;
    __hip_bfloat16* X2b = (__hip_bfloat16*)(wsb + off); off += NX * 2;
    __hip_bfloat16* Ob  = (__hip_bfloat16*)(wsb + off); off += NX * 2;
    __hip_bfloat16* HMb = (__hip_bfloat16*)(wsb + off); off += NHF * 2;
    __hip_bfloat16* WT  = (__hip_bfloat16*)(wsb + off); off += NWT * 2;
    if (ws_size < off) return;

    Modes mi;
    compute_modes(mi.v);

    k_embed<<<dim3(16, 2, BB), 256, 0, stream>>>(xe, tw, X1, X1b);

    float* cur = X1;            float* alt = X2;
    __hip_bfloat16* curb = X1b; __hip_bfloat16* altb = X2b;
    const int M = BB * LL;      // 16384

    for (int li = 0; li < NEL; ++li) {
        // ---- q projection: TB = curb @ Wq + bq ----
        k_wt<<<dim3(DD / 32, DD / 32), 256, 0, stream>>>(Wq + (size_t)li * DD * DD, WT, DD, DD);
        k_mm<0><<<dim3(M / 128, DD / 128), 256, 0, stream>>>(curb, WT, bq + li * DD,
                                                             TB, nullptr, M, DD, DD);
        // ---- 32-mode DFT over time ----
        k_dft<<<BB * DD, 64, 0, stream>>>(TB, XGr, XGi, mi);
        // ---- per-mode complex matmul ----
        k_og<<<BB * NH * NM, EHH, 0, stream>>>(XGr, XGi, fwr, fwi, OGr, OGi, li);
        // ---- irfft -> Ob [B,(h,e),L] bf16 ----
        k_irfft<<<BB * DD, 64, 0, stream>>>(OGr, OGi, Ob);
        // ---- new_x = Ob @ Wo + bo -> TB fp32 ----
        k_wt<<<dim3(DD / 32, DD / 32), 256, 0, stream>>>(Wo + (size_t)li * DD * DD, WT, DD, DD);
        k_mm<0><<<dim3(M / 128, DD / 128), 256, 0, stream>>>(Ob, WT, bo + li * DD,
                                                             TB, nullptr, M, DD, DD);
        // ---- x = decomp(x + new_x) ----
        k_add_decomp<<<BB * 8, DD, 0, stream>>>(cur, TB, alt, altb);
        { float* t_ = cur; cur = alt; alt = t_; }
        { __hip_bfloat16* t_ = curb; curb = altb; altb = t_; }
        // ---- FFN: HMb = gelu(curb @ W1) bf16; TB = HMb @ W2 fp32 ----
        k_wt<<<dim3(NDFF / 32, DD / 32), 256, 0, stream>>>(W1 + (size_t)li * DD * NDFF, WT, DD, NDFF);
        k_mm<1><<<dim3(M / 128, NDFF / 128), 256, 0, stream>>>(curb, WT, nullptr,
                                                               nullptr, HMb, M, NDFF, DD);
        k_wt<<<dim3(DD / 32, NDFF / 32), 256, 0, stream>>>(W2 + (size_t)li * NDFF * DD, WT, NDFF, DD);
        k_mm<2><<<dim3(M / 128, DD / 128), 256, 0, stream>>>(HMb, WT, nullptr,
                                                             TB, nullptr, M, DD, NDFF);
        k_add_decomp<<<BB * 8, DD, 0, stream>>>(cur, TB, alt, altb);
        { float* t_ = cur; cur = alt; alt = t_; }
        { __hip_bfloat16* t_ = curb; curb = altb; altb = t_; }
    }

    // ---- final: LayerNorm -> subtract temporal mean -> gelu -> projection ----
    k_ln<<<BB * LL, 64, 0, stream>>>(cur, lw, lb, TB);
    float* CM = XGr;
    float* PP = XGi;
    k_colmean<<<64, 256, 0, stream>>>(TB, CM);
    k_gelu_sub<<<32768, 256, 0, stream>>>(TB, CM);
    k_proj_partial<<<dim3(BB, 16), 256, 0, stream>>>(TB, pw, PP);
    k_proj_final<<<1, 320, 0, stream>>>(PP, pb, out);
}

// Round 3
// 1770.336 us; speedup vs baseline: 3.2802x; 1.2782x over previous
//
#include <hip/hip_runtime.h>
#include <hip/hip_bf16.h>
#include <stdint.h>
#include <algorithm>

#define BB  32
#define LL  512
#define NCI 21
#define DD  512
#define NH  8
#define EHH 64
#define NDFF 2048
#define NM  32
#define NEL 3
#define NCC 10

struct Modes { int v[NM]; };

typedef __bf16 bf16x8 __attribute__((ext_vector_type(8)));
typedef float f32x4 __attribute__((ext_vector_type(4)));

__device__ __forceinline__ float gelu_f(float x) {
    return 0.5f * x * (1.0f + erff(x * 0.7071067811865475f));
}

__device__ __forceinline__ void gload_lds16(const void* g, void* l) {
    __builtin_amdgcn_global_load_lds((const __attribute__((address_space(1))) void*)g,
                                     (__attribute__((address_space(3))) void*)l, 16, 0, 0);
}

// ---------------- embedding: circular conv1d(k=3) + positional encoding (dual write) -----
__global__ void k_embed(const float* __restrict__ xe, const float* __restrict__ tw,
                        float* __restrict__ X, __hip_bfloat16* __restrict__ Xb) {
    int lc = blockIdx.x;        // 16 chunks of 32 l's
    int dh = blockIdx.y;        // 0/1
    int b  = blockIdx.z;
    int t  = threadIdx.x;       // 256
    int d  = dh * 256 + t;
    __shared__ float s_xe[34][NCI];
    int l0 = lc * 32;
    for (int i = t; i < 34 * NCI; i += 256) {
        int r = i / NCI, c = i % NCI;
        int ls = (l0 - 1 + r + LL) & (LL - 1);
        s_xe[r][c] = xe[(b * LL + ls) * NCI + c];
    }
    __syncthreads();
    int a = d & ~1;
    float freq = expf((float)a * (-9.210340371976184f / 512.0f));
    for (int li = 0; li < 32; ++li) {
        int l = l0 + li;
        float acc = 0.f;
        #pragma unroll
        for (int k = 0; k < 3; ++k)
            for (int c = 0; c < NCI; ++c)
                acc = fmaf(s_xe[li + k][c], tw[(k * NCI + c) * DD + d], acc);
        float v = (float)l * freq;
        float pe = (d & 1) ? cosf(v) : sinf(v);
        float r = acc + pe;
        size_t off = ((size_t)(b * LL + l)) * DD + d;
        X[off] = r;
        Xb[off] = __float2bfloat16(r);
    }
}

// ---------------- weight convert+transpose: W[K][N] fp32 -> WT[N][K] bf16 ----------------
__global__ void k_wt(const float* __restrict__ W, __hip_bfloat16* __restrict__ WT,
                     int K, int N) {
    __shared__ float s[32][33];
    int bx = blockIdx.x;   // along N
    int by = blockIdx.y;   // along K
    int t = threadIdx.x;   // 256
    int r = t >> 5, c = t & 31;
    #pragma unroll
    for (int i = 0; i < 4; ++i)
        s[r + i * 8][c] = W[(size_t)(by * 32 + r + i * 8) * N + bx * 32 + c];
    __syncthreads();
    #pragma unroll
    for (int i = 0; i < 4; ++i) {
        int n = bx * 32 + r + i * 8;
        WT[(size_t)n * K + by * 32 + c] = __float2bfloat16(s[c][r + i * 8]);
    }
}

// ---------------- fourier weight transpose: fw[h,e,o,m] -> WM[h][m][e][o] float2 ---------
__global__ void k_wfm(const float* __restrict__ fwr, const float* __restrict__ fwi,
                      float2* __restrict__ WM, int li) {
    int blk = blockIdx.x;        // h*64 + e
    int h = blk >> 6, e = blk & 63;
    int t = threadIdx.x;         // 256
    __shared__ float2 s[32][65]; // [m][o] padded
    const float* br = fwr + (((size_t)(li * NH + h) * EHH + e) * EHH) * NM;
    const float* bi = fwi + (((size_t)(li * NH + h) * EHH + e) * EHH) * NM;
    for (int i = t; i < 2048; i += 256) {
        int o = i >> 5, m = i & 31;
        s[m][o] = make_float2(br[i], bi[i]);
    }
    __syncthreads();
    int mr = t >> 6, o = t & 63;
    for (int m = mr; m < 32; m += 4)
        WM[((size_t)(h * 32 + m)) * 4096 + e * 64 + o] = s[m][o];
}

// ---------------- bf16 MFMA GEMM: C = epi(A[M,K] @ Bt[N,K]^T + bias) ---------------------
template<int EPI>
__global__ __launch_bounds__(256) void k_mm(const __hip_bfloat16* __restrict__ A,
        const __hip_bfloat16* __restrict__ Bt, const float* __restrict__ bias,
        float* __restrict__ C, __hip_bfloat16* __restrict__ Cb, int M, int N, int K) {
    __shared__ __hip_bfloat16 As[128 * 32];
    __shared__ __hip_bfloat16 Bs[128 * 32];
    int t = threadIdx.x;
    int m0 = blockIdx.x * 128, n0 = blockIdx.y * 128;
    int w = t >> 6, ln = t & 63;
    int wr = w >> 1, wc = w & 1;
    f32x4 acc[4][4] = {};
    for (int k0 = 0; k0 < K; k0 += 32) {
        #pragma unroll
        for (int i = 0; i < 2; ++i) {
            int s = i * 256 + t;
            int row = s >> 2, q = s & 3;
            const __hip_bfloat16* ga = A + (size_t)(m0 + row) * K + k0 + q * 8;
            const __hip_bfloat16* gb = Bt + (size_t)(n0 + row) * K + k0 + q * 8;
            char* la = (char*)As + i * 4096 + w * 1024;
            char* lb = (char*)Bs + i * 4096 + w * 1024;
            gload_lds16(ga, la);
            gload_lds16(gb, lb);
        }
        __syncthreads();
        bf16x8 af[4], bfr[4];
        int lr = ln & 15, kc = (ln >> 4) * 8;
        #pragma unroll
        for (int mi = 0; mi < 4; ++mi)
            af[mi] = *(const bf16x8*)&As[(wr * 64 + mi * 16 + lr) * 32 + kc];
        #pragma unroll
        for (int ni = 0; ni < 4; ++ni)
            bfr[ni] = *(const bf16x8*)&Bs[(wc * 64 + ni * 16 + lr) * 32 + kc];
        #pragma unroll
        for (int mi = 0; mi < 4; ++mi)
            #pragma unroll
            for (int ni = 0; ni < 4; ++ni)
                acc[mi][ni] = __builtin_amdgcn_mfma_f32_16x16x32_bf16(
                    af[mi], bfr[ni], acc[mi][ni], 0, 0, 0);
        __syncthreads();
    }
    int rb = (ln >> 4) * 4, cb = ln & 15;
    #pragma unroll
    for (int mi = 0; mi < 4; ++mi) {
        #pragma unroll
        for (int ni = 0; ni < 4; ++ni) {
            int col = n0 + wc * 64 + ni * 16 + cb;
            int rowb = m0 + wr * 64 + mi * 16 + rb;
            float bv = (EPI == 0) ? bias[col] : 0.f;
            #pragma unroll
            for (int j = 0; j < 4; ++j) {
                float v = acc[mi][ni][j] + bv;
                size_t off = (size_t)(rowb + j) * N + col;
                if (EPI == 1) Cb[off] = __float2bfloat16(gelu_f(v));
                else C[off] = v;
            }
        }
    }
}

// ---------------- DFT -> XG[h*32+m][e*32+b] ----------------------------------------------
__global__ void k_dft(const float* __restrict__ Q, float* __restrict__ XGr,
                      float* __restrict__ XGi, Modes mi) {
    int bd = blockIdx.x;            // b*512 + d
    int t = threadIdx.x;            // 64
    __shared__ float s_q[LL];
    __shared__ float s_sin[LL];
    int b = bd >> 9, d = bd & 511;
    const float w0 = 6.283185307179586f / 512.0f;
    for (int i = t; i < LL; i += 64) {
        s_q[i] = Q[((size_t)(b * LL + i)) * DD + d];
        s_sin[i] = sinf(w0 * (float)i);
    }
    __syncthreads();
    int m = t >> 1, part = t & 1;
    int im = mi.v[m];
    float acc = 0.f;
    int r = 0;
    for (int l = 0; l < LL; ++l) {
        int rr = part ? r : ((r + 128) & 511);
        acc = fmaf(s_q[l], s_sin[rr], acc);
        r = (r + im) & 511;
    }
    if (part) acc = -acc;
    int h = d >> 6, e = d & 63;
    int off = (h * 32 + m) * 2048 + e * 32 + b;
    if (part) XGi[off] = acc; else XGr[off] = acc;
}

// ---------------- og: per (h,m) complex GEMM, weights read once --------------------------
// XG[hm][e*32+b] x WM[hm][e][o] -> OG[hm][b*64+o]
__global__ __launch_bounds__(256) void k_og(const float* __restrict__ XGr,
        const float* __restrict__ XGi, const float2* __restrict__ WM,
        float* __restrict__ OGr, float* __restrict__ OGi) {
    int hm = blockIdx.x;      // 256
    int t = threadIdx.x;      // 256
    __shared__ float2 sw[4096];      // [e][o]
    __shared__ float sxr[2048], sxi[2048];  // [e][b]
    const float2* w = WM + (size_t)hm * 4096;
    for (int i = t; i < 4096; i += 256) sw[i] = w[i];
    const float* xr = XGr + hm * 2048;
    const float* xi = XGi + hm * 2048;
    for (int i = t; i < 2048; i += 256) { sxr[i] = xr[i]; sxi[i] = xi[i]; }
    __syncthreads();
    int b = t >> 3, o0 = (t & 7) * 8;
    float ar[8] = {}, ai[8] = {};
    for (int e = 0; e < 64; ++e) {
        float xrv = sxr[e * 32 + b], xiv = sxi[e * 32 + b];
        #pragma unroll
        for (int j = 0; j < 8; ++j) {
            float2 wv = sw[e * 64 + o0 + j];
            ar[j] = fmaf(xrv, wv.x, fmaf(-xiv, wv.y, ar[j]));
            ai[j] = fmaf(xrv, wv.y, fmaf( xiv, wv.x, ai[j]));
        }
    }
    int base = hm * 2048 + b * 64 + o0;
    #pragma unroll
    for (int j = 0; j < 8; ++j) {
        OGr[base + j] = ar[j];
        OGi[base + j] = ai[j];
    }
}

// ---------------- irfft with dense 32-bin prefix; Im(bin0) dropped; bf16 out -------------
__global__ void k_irfft(const float* __restrict__ OGr, const float* __restrict__ OGi,
                        __hip_bfloat16* __restrict__ O) {
    int bi = blockIdx.x;            // b*512 + (h*64+o)
    int t = threadIdx.x;            // 64
    __shared__ float gr[NM], gi[NM], s_sin[LL];
    int b = bi >> 9, d = bi & 511, h = d >> 6, o = d & 63;
    if (t < NM) {
        gr[t] = OGr[(h * 32 + t) * 2048 + b * 64 + o];
        gi[t] = OGi[(h * 32 + t) * 2048 + b * 64 + o];
    }
    const float w0 = 6.283185307179586f / 512.0f;
    for (int i = t; i < LL; i += 64) s_sin[i] = sinf(w0 * (float)i);
    __syncthreads();
    for (int l = t; l < LL; l += 64) {
        float acc = gr[0];
        #pragma unroll
        for (int m = 1; m < NM; ++m) {
            int r = (m * l) & 511;
            acc += 2.f * (gr[m] * s_sin[(r + 128) & 511] - gi[m] * s_sin[r]);
        }
        O[(size_t)bi * LL + l] = __float2bfloat16(acc * (1.0f / 512.0f));
    }
}

// ---------------- s = P + Q; out = s - movavg25(s); dual fp32+bf16, L-chunked ------------
__global__ void k_add_decomp(const float* __restrict__ P, const float* __restrict__ Q,
                             float* __restrict__ Out, __hip_bfloat16* __restrict__ Outb) {
    int b = blockIdx.x >> 3;
    int l0 = (blockIdx.x & 7) * 64;
    int d = threadIdx.x;            // 512
    const float* p = P + (size_t)b * LL * DD + d;
    const float* q = Q + (size_t)b * LL * DD + d;
    float* o = Out + (size_t)b * LL * DD + d;
    __hip_bfloat16* ob = Outb + (size_t)b * LL * DD + d;
    float sum = 0.f;
    for (int j = l0 - 12; j <= l0 + 12; ++j) {
        int jc = j < 0 ? 0 : (j > 511 ? 511 : j);
        sum += p[jc * DD] + q[jc * DD];
    }
    for (int l = l0; l < l0 + 64; ++l) {
        float sv = p[l * DD] + q[l * DD];
        float r = sv - sum * (1.0f / 25.0f);
        o[l * DD] = r;
        ob[l * DD] = __float2bfloat16(r);
        int lp = l + 13 > 511 ? 511 : l + 13;
        int lm = l - 12 < 0 ? 0 : l - 12;
        sum += (p[lp * DD] + q[lp * DD]) - (p[lm * DD] + q[lm * DD]);
    }
}

// ---------------- LayerNorm over D ----------------
__global__ void k_ln(const float* __restrict__ Xin, const float* __restrict__ lw,
                     const float* __restrict__ lb, float* __restrict__ Out) {
    int row = blockIdx.x;
    int t = threadIdx.x;  // 64
    const float4* x4 = (const float4*)(Xin + (size_t)row * DD);
    float4 v0 = x4[t], v1 = x4[t + 64];
    float s = v0.x + v0.y + v0.z + v0.w + v1.x + v1.y + v1.z + v1.w;
    #pragma unroll
    for (int o = 32; o; o >>= 1) s += __shfl_down(s, o);
    float mu = __shfl(s, 0) * (1.0f / 512.0f);
    float d0 = v0.x - mu, d1 = v0.y - mu, d2 = v0.z - mu, d3 = v0.w - mu;
    float d4 = v1.x - mu, d5 = v1.y - mu, d6 = v1.z - mu, d7 = v1.w - mu;
    float vs = d0*d0 + d1*d1 + d2*d2 + d3*d3 + d4*d4 + d5*d5 + d6*d6 + d7*d7;
    #pragma unroll
    for (int o = 32; o; o >>= 1) vs += __shfl_down(vs, o);
    float var = __shfl(vs, 0) * (1.0f / 512.0f);
    float rstd = rsqrtf(var + 1e-5f);
    float4 w0 = ((const float4*)lw)[t], w1 = ((const float4*)lw)[t + 64];
    float4 b0 = ((const float4*)lb)[t], b1 = ((const float4*)lb)[t + 64];
    float4 r0, r1;
    r0.x = d0 * rstd * w0.x + b0.x; r0.y = d1 * rstd * w0.y + b0.y;
    r0.z = d2 * rstd * w0.z + b0.z; r0.w = d3 * rstd * w0.w + b0.w;
    r1.x = d4 * rstd * w1.x + b1.x; r1.y = d5 * rstd * w1.y + b1.y;
    r1.z = d6 * rstd * w1.z + b1.z; r1.w = d7 * rstd * w1.w + b1.w;
    float4* o4 = (float4*)(Out + (size_t)row * DD);
    o4[t] = r0; o4[t + 64] = r1;
}

// ---------------- column (temporal) mean over L per (b,d) ----------------
__global__ void k_colmean(const float* __restrict__ A, float* __restrict__ CM) {
    int tid = blockIdx.x * blockDim.x + threadIdx.x;  // 16384
    int b = tid >> 9, d = tid & 511;
    const float* a = A + (size_t)b * LL * DD + d;
    float s = 0.f;
    for (int l = 0; l < LL; ++l) s += a[l * DD];
    CM[tid] = s * (1.0f / 512.0f);
}

__global__ void k_gelu_sub(float* __restrict__ A, const float* __restrict__ CM) {
    int i = blockIdx.x * 256 + threadIdx.x;
    int b = i >> 18, d = i & 511;
    float v = A[i] - CM[(b << 9) | d];
    A[i] = gelu_f(v);
}

// ---------------- final projection [B, L*D] @ [L*D, 10] ----------------
__global__ __launch_bounds__(256) void k_proj_partial(const float* __restrict__ A,
        const float* __restrict__ PW, float* __restrict__ PP) {
    int b = blockIdx.x, c = blockIdx.y;
    int t = threadIdx.x;
    float acc[NCC] = {};
    const float* a = A + (size_t)b * LL * DD;
    int i0 = c * 16384, i1 = i0 + 16384;
    for (int i = i0 + t; i < i1; i += 256) {
        float v = a[i];
        const float* w = PW + (size_t)i * NCC;
        #pragma unroll
        for (int n = 0; n < NCC; ++n) acc[n] = fmaf(v, w[n], acc[n]);
    }
    __shared__ float red[4][NCC];
    int lane = t & 63, wv = t >> 6;
    #pragma unroll
    for (int n = 0; n < NCC; ++n) {
        float s = acc[n];
        #pragma unroll
        for (int o = 32; o; o >>= 1) s += __shfl_down(s, o);
        if (lane == 0) red[wv][n] = s;
    }
    __syncthreads();
    if (t < NCC) {
        PP[(b * 16 + c) * NCC + t] = red[0][t] + red[1][t] + red[2][t] + red[3][t];
    }
}

__global__ void k_proj_final(const float* __restrict__ PP, const float* __restrict__ pb,
                             float* __restrict__ out) {
    int t = threadIdx.x;
    if (t >= BB * NCC) return;
    int b = t / NCC, n = t % NCC;
    float s = pb[n];
    for (int c = 0; c < 16; ++c) s += PP[(b * 16 + c) * NCC + n];
    out[t] = s;
}

// ---------------- numpy legacy RandomState(0) modes replication ----------------
static void compute_modes(int* out) {
    static uint32_t mt[624];
    uint32_t s = 0u;
    mt[0] = s;
    for (int i = 1; i < 624; ++i)
        mt[i] = 1812433253u * (mt[i - 1] ^ (mt[i - 1] >> 30)) + (uint32_t)i;
    int mti = 624;
    auto genrand = [&]() -> uint32_t {
        if (mti >= 624) {
            for (int k = 0; k < 624; ++k) {
                uint32_t y = (mt[k] & 0x80000000u) | (mt[(k + 1) % 624] & 0x7fffffffu);
                mt[k] = mt[(k + 397) % 624] ^ (y >> 1) ^ ((y & 1u) ? 2567483615u : 0u);
            }
            mti = 0;
        }
        uint32_t y = mt[mti++];
        y ^= y >> 11;
        y ^= (y << 7) & 2636928640u;
        y ^= (y << 15) & 4022730752u;
        y ^= y >> 18;
        return y;
    };
    int idx[256];
    for (int i = 0; i < 256; ++i) idx[i] = i;
    for (int i = 255; i >= 1; --i) {
        uint32_t mx = (uint32_t)i;
        uint32_t mask = mx;
        mask |= mask >> 1; mask |= mask >> 2; mask |= mask >> 4;
        mask |= mask >> 8; mask |= mask >> 16;
        uint32_t j;
        while ((j = (genrand() & mask)) > mx) {}
        int tmp = idx[i]; idx[i] = idx[j]; idx[j] = tmp;
    }
    int sel[NM];
    for (int i = 0; i < NM; ++i) sel[i] = idx[i];
    std::sort(sel, sel + NM);
    for (int i = 0; i < NM; ++i) out[i] = sel[i];
}

extern "C" void kernel_launch(void* const* d_in, const int* in_sizes, int n_in,
                              void* d_out, int out_size, void* d_ws, size_t ws_size,
                              hipStream_t stream) {
    const float* xe  = (const float*)d_in[0];
    const float* tw  = (const float*)d_in[1];
    const float* Wq  = (const float*)d_in[2];
    const float* bq  = (const float*)d_in[3];
    const float* Wo  = (const float*)d_in[8];
    const float* bo  = (const float*)d_in[9];
    const float* fwr = (const float*)d_in[10];
    const float* fwi = (const float*)d_in[11];
    const float* W1  = (const float*)d_in[12];
    const float* W2  = (const float*)d_in[13];
    const float* lw  = (const float*)d_in[14];
    const float* lb  = (const float*)d_in[15];
    const float* pw  = (const float*)d_in[16];
    const float* pb  = (const float*)d_in[17];
    float* out = (float*)d_out;

    const size_t NX = (size_t)BB * LL * DD;        // 8388608
    const size_t NHF = (size_t)BB * LL * NDFF;     // 33554432
    const size_t NXG = (size_t)BB * NH * EHH * NM; // 524288
    const size_t NWT = (size_t)NDFF * DD;          // 1048576
    const size_t NWM = (size_t)NH * NM * EHH * EHH;// 1048576 float2

    char* wsb = (char*)d_ws;
    size_t off = 0;
    float* X1  = (float*)(wsb + off); off += NX * 4;
    float* X2  = (float*)(wsb + off); off += NX * 4;
    float* TB  = (float*)(wsb + off); off += NX * 4;
    float* XGr = (float*)(wsb + off); off += NXG * 4;
    float* XGi = (float*)(wsb + off); off += NXG * 4;
    float* OGr = (float*)(wsb + off); off += NXG * 4;
    float* OGi = (float*)(wsb + off); off += NXG * 4;
    __hip_bfloat16* X1b = (__hip_bfloat16*)(wsb + off); off += NX * 2;
    __hip_bfloat16* X2b = (__hip_bfloat16*)(wsb + off); off += NX * 2;
    __hip_bfloat16* Ob  = (__hip_bfloat16*)(wsb + off); off += NX * 2;
    __hip_bfloat16* HMb = (__hip_bfloat16*)(wsb + off); off += NHF * 2;
    __hip_bfloat16* WT  = (__hip_bfloat16*)(wsb + off); off += NWT * 2;
    float2* WM          = (float2*)(wsb + off);         off += NWM * 8;
    if (ws_size < off) return;

    Modes mi;
    compute_modes(mi.v);

    k_embed<<<dim3(16, 2, BB), 256, 0, stream>>>(xe, tw, X1, X1b);

    float* cur = X1;            float* alt = X2;
    __hip_bfloat16* curb = X1b; __hip_bfloat16* altb = X2b;
    const int M = BB * LL;      // 16384

    for (int li = 0; li < NEL; ++li) {
        // ---- q projection: TB = curb @ Wq + bq ----
        k_wt<<<dim3(DD / 32, DD / 32), 256, 0, stream>>>(Wq + (size_t)li * DD * DD, WT, DD, DD);
        k_mm<0><<<dim3(M / 128, DD / 128), 256, 0, stream>>>(curb, WT, bq + li * DD,
                                                             TB, nullptr, M, DD, DD);
        // ---- fourier weight transpose for this layer ----
        k_wfm<<<NH * EHH, 256, 0, stream>>>(fwr, fwi, WM, li);
        // ---- 32-mode DFT over time -> XG[hm][e*32+b] ----
        k_dft<<<BB * DD, 64, 0, stream>>>(TB, XGr, XGi, mi);
        // ---- per-(h,m) complex GEMM ----
        k_og<<<NH * NM, 256, 0, stream>>>(XGr, XGi, WM, OGr, OGi);
        // ---- irfft -> Ob [B,(h,e),L] bf16 ----
        k_irfft<<<BB * DD, 64, 0, stream>>>(OGr, OGi, Ob);
        // ---- new_x = Ob @ Wo + bo -> TB fp32 ----
        k_wt<<<dim3(DD / 32, DD / 32), 256, 0, stream>>>(Wo + (size_t)li * DD * DD, WT, DD, DD);
        k_mm<0><<<dim3(M / 128, DD / 128), 256, 0, stream>>>(Ob, WT, bo + li * DD,
                                                             TB, nullptr, M, DD, DD);
        // ---- x = decomp(x + new_x) ----
        k_add_decomp<<<BB * 8, DD, 0, stream>>>(cur, TB, alt, altb);
        { float* t_ = cur; cur = alt; alt = t_; }
        { __hip_bfloat16* t_ = curb; curb = altb; altb = t_; }
        // ---- FFN ----
        k_wt<<<dim3(NDFF / 32, DD / 32), 256, 0, stream>>>(W1 + (size_t)li * DD * NDFF, WT, DD, NDFF);
        k_mm<1><<<dim3(M / 128, NDFF / 128), 256, 0, stream>>>(curb, WT, nullptr,
                                                               nullptr, HMb, M, NDFF, DD);
        k_wt<<<dim3(DD / 32, NDFF / 32), 256, 0, stream>>>(W2 + (size_t)li * NDFF * DD, WT, NDFF, DD);
        k_mm<2><<<dim3(M / 128, DD / 128), 256, 0, stream>>>(HMb, WT, nullptr,
                                                             TB, nullptr, M, DD, NDFF);
        k_add_decomp<<<BB * 8, DD, 0, stream>>>(cur, TB, alt, altb);
        { float* t_ = cur; cur = alt; alt = t_; }
        { __hip_bfloat16* t_ = curb; curb = altb; altb = t_; }
    }

    // ---- final: LayerNorm -> subtract temporal mean -> gelu -> projection ----
    k_ln<<<BB * LL, 64, 0, stream>>>(cur, lw, lb, TB);
    float* CM = XGr;
    float* PP = XGi;
    k_colmean<<<64, 256, 0, stream>>>(TB, CM);
    k_gelu_sub<<<32768, 256, 0, stream>>>(TB, CM);
    k_proj_partial<<<dim3(BB, 16), 256, 0, stream>>>(TB, pw, PP);
    k_proj_final<<<1, 320, 0, stream>>>(PP, pb, out);
}

// Round 4
// 1297.643 us; speedup vs baseline: 4.4751x; 1.3643x over previous
//
#include <hip/hip_runtime.h>
#include <hip/hip_bf16.h>
#include <stdint.h>
#include <algorithm>

#define BB  32
#define LL  512
#define NCI 21
#define DD  512
#define NH  8
#define EHH 64
#define NDFF 2048
#define NM  32
#define NEL 3
#define NCC 10

struct Modes { int v[NM]; };

typedef __bf16 bf16x8 __attribute__((ext_vector_type(8)));
typedef float f32x4 __attribute__((ext_vector_type(4)));

__device__ __forceinline__ float gelu_f(float x) {
    return 0.5f * x * (1.0f + erff(x * 0.7071067811865475f));
}

__device__ __forceinline__ void gload_lds16(const void* g, void* l) {
    __builtin_amdgcn_global_load_lds((const __attribute__((address_space(1))) void*)g,
                                     (__attribute__((address_space(3))) void*)l, 16, 0, 0);
}

// ---------------- embedding: circular conv1d(k=3) + positional encoding (dual write) -----
__global__ void k_embed(const float* __restrict__ xe, const float* __restrict__ tw,
                        float* __restrict__ X, __hip_bfloat16* __restrict__ Xb) {
    int lc = blockIdx.x;
    int dh = blockIdx.y;
    int b  = blockIdx.z;
    int t  = threadIdx.x;
    int d  = dh * 256 + t;
    __shared__ float s_xe[34][NCI];
    int l0 = lc * 32;
    for (int i = t; i < 34 * NCI; i += 256) {
        int r = i / NCI, c = i % NCI;
        int ls = (l0 - 1 + r + LL) & (LL - 1);
        s_xe[r][c] = xe[(b * LL + ls) * NCI + c];
    }
    __syncthreads();
    int a = d & ~1;
    float freq = expf((float)a * (-9.210340371976184f / 512.0f));
    for (int li = 0; li < 32; ++li) {
        int l = l0 + li;
        float acc = 0.f;
        #pragma unroll
        for (int k = 0; k < 3; ++k)
            for (int c = 0; c < NCI; ++c)
                acc = fmaf(s_xe[li + k][c], tw[(k * NCI + c) * DD + d], acc);
        float v = (float)l * freq;
        float pe = (d & 1) ? cosf(v) : sinf(v);
        float r = acc + pe;
        size_t off = ((size_t)(b * LL + l)) * DD + d;
        X[off] = r;
        Xb[off] = __float2bfloat16(r);
    }
}

// ---------------- weight convert+transpose: W[K][N] fp32 -> WT[N][K] bf16 ----------------
__global__ void k_wt(const float* __restrict__ W, __hip_bfloat16* __restrict__ WT,
                     int K, int N) {
    __shared__ float s[32][33];
    int bx = blockIdx.x;
    int by = blockIdx.y;
    int t = threadIdx.x;
    int r = t >> 5, c = t & 31;
    #pragma unroll
    for (int i = 0; i < 4; ++i)
        s[r + i * 8][c] = W[(size_t)(by * 32 + r + i * 8) * N + bx * 32 + c];
    __syncthreads();
    #pragma unroll
    for (int i = 0; i < 4; ++i) {
        int n = bx * 32 + r + i * 8;
        WT[(size_t)n * K + by * 32 + c] = __float2bfloat16(s[c][r + i * 8]);
    }
}

// ---------------- fourier weight transpose: fw[h,e,o,m] -> WM[h][m][e][o] float2 ---------
__global__ void k_wfm(const float* __restrict__ fwr, const float* __restrict__ fwi,
                      float2* __restrict__ WM, int li) {
    int blk = blockIdx.x;        // h*64 + e
    int h = blk >> 6, e = blk & 63;
    int t = threadIdx.x;
    __shared__ float2 s[32][65];
    const float* br = fwr + (((size_t)(li * NH + h) * EHH + e) * EHH) * NM;
    const float* bi = fwi + (((size_t)(li * NH + h) * EHH + e) * EHH) * NM;
    for (int i = t; i < 2048; i += 256) {
        int o = i >> 5, m = i & 31;
        s[m][o] = make_float2(br[i], bi[i]);
    }
    __syncthreads();
    int mr = t >> 6, o = t & 63;
    for (int m = mr; m < 32; m += 4)
        WM[((size_t)(h * 32 + m)) * 4096 + e * 64 + o] = s[m][o];
}

// ---------------- twiddle matrix: T[2m][l]=cos(w0*im*l), T[2m+1][l]=sin ------------------
__global__ void k_tgen(__hip_bfloat16* __restrict__ Tb, Modes md) {
    int r = blockIdx.x;          // 64
    int m = r >> 1;
    int im = md.v[m];
    const float w0 = 6.283185307179586f / 512.0f;
    for (int l = threadIdx.x; l < LL; l += 64) {
        int red = (im * l) & 511;
        float ang = w0 * (float)red;
        float v = (r & 1) ? sinf(ang) : cosf(ang);
        Tb[r * 512 + l] = __float2bfloat16(v);
    }
}

// ---------------- global sin table ----------------
__global__ void k_stab(float* __restrict__ ST) {
    int t = blockIdx.x * 64 + threadIdx.x;
    const float w0 = 6.283185307179586f / 512.0f;
    if (t < 512) ST[t] = sinf(w0 * (float)t);
}

// ---------------- transpose: X[b][l][d] fp32 -> XT[b][d][l] bf16 -------------------------
__global__ __launch_bounds__(256) void k_xt(const float* __restrict__ X,
                                            __hip_bfloat16* __restrict__ XT) {
    int b = blockIdx.z;
    int l0 = blockIdx.x * 64, d0 = blockIdx.y * 64;
    __shared__ float s[64][65];
    const float* xb = X + (size_t)b * LL * DD;
    int t = threadIdx.x;
    #pragma unroll
    for (int i = 0; i < 16; ++i) {
        int e = i * 256 + t;
        int lr = e >> 6, dc = e & 63;
        s[lr][dc] = xb[(size_t)(l0 + lr) * DD + d0 + dc];
    }
    __syncthreads();
    __hip_bfloat16* xt = XT + (size_t)b * DD * LL;
    #pragma unroll
    for (int i = 0; i < 16; ++i) {
        int e = i * 256 + t;
        int dr = e >> 6, lc = e & 63;
        xt[(size_t)(d0 + dr) * LL + l0 + lc] = __float2bfloat16(s[lc][dr]);
    }
}

// ---------------- TX[b] = T[64x512] @ X[b]^T-form: MFMA, M=64,N=512,K=512(l) -------------
__global__ __launch_bounds__(256) void k_tx(const __hip_bfloat16* __restrict__ Tb,
        const __hip_bfloat16* __restrict__ XT, __hip_bfloat16* __restrict__ TX) {
    __shared__ __hip_bfloat16 Ts[64 * 32];
    __shared__ __hip_bfloat16 Xs[128 * 32];
    int b = blockIdx.x, n0 = blockIdx.y * 128;
    int t = threadIdx.x, w = t >> 6, ln = t & 63;
    const __hip_bfloat16* xb = XT + (size_t)b * DD * LL;
    f32x4 acc[4][2] = {};
    for (int k0 = 0; k0 < 512; k0 += 32) {
        {
            int row = w * 16 + (ln >> 2), q = ln & 3;
            gload_lds16(Tb + row * 512 + k0 + q * 8, (char*)Ts + w * 1024);
        }
        #pragma unroll
        for (int i = 0; i < 2; ++i) {
            int s = i * 256 + t;
            int row = s >> 2, q = s & 3;
            gload_lds16(xb + (size_t)(n0 + row) * LL + k0 + q * 8,
                        (char*)Xs + i * 4096 + w * 1024);
        }
        __syncthreads();
        int lr = ln & 15, kc = (ln >> 4) * 8;
        bf16x8 af[4], bfr[2];
        #pragma unroll
        for (int mi = 0; mi < 4; ++mi)
            af[mi] = *(const bf16x8*)&Ts[(mi * 16 + lr) * 32 + kc];
        #pragma unroll
        for (int ni = 0; ni < 2; ++ni)
            bfr[ni] = *(const bf16x8*)&Xs[(w * 32 + ni * 16 + lr) * 32 + kc];
        #pragma unroll
        for (int mi = 0; mi < 4; ++mi)
            #pragma unroll
            for (int ni = 0; ni < 2; ++ni)
                acc[mi][ni] = __builtin_amdgcn_mfma_f32_16x16x32_bf16(
                    af[mi], bfr[ni], acc[mi][ni], 0, 0, 0);
        __syncthreads();
    }
    int rb = (ln >> 4) * 4, cb = ln & 15;
    #pragma unroll
    for (int mi = 0; mi < 4; ++mi)
        #pragma unroll
        for (int ni = 0; ni < 2; ++ni)
            #pragma unroll
            for (int j = 0; j < 4; ++j) {
                int m = mi * 16 + rb + j;
                int col = n0 + w * 32 + ni * 16 + cb;
                TX[(size_t)(b * 64 + m) * 512 + col] =
                    __float2bfloat16(acc[mi][ni][j]);
            }
}

// ---------------- XG = TX @ Wq (+bias for im==0), scatter to [hm][e*32+b] ----------------
__global__ __launch_bounds__(256) void k_xg(const __hip_bfloat16* __restrict__ A,
        const __hip_bfloat16* __restrict__ Bt, const float* __restrict__ bq,
        float* __restrict__ XGr, float* __restrict__ XGi, Modes md) {
    __shared__ __hip_bfloat16 As[128 * 32];
    __shared__ __hip_bfloat16 Bs[128 * 32];
    int t = threadIdx.x;
    int m0 = blockIdx.x * 128, n0 = blockIdx.y * 128;
    int w = t >> 6, ln = t & 63;
    int wr = w >> 1, wc = w & 1;
    const int K = 512;
    f32x4 acc[4][4] = {};
    for (int k0 = 0; k0 < K; k0 += 32) {
        #pragma unroll
        for (int i = 0; i < 2; ++i) {
            int s = i * 256 + t;
            int row = s >> 2, q = s & 3;
            gload_lds16(A + (size_t)(m0 + row) * K + k0 + q * 8,
                        (char*)As + i * 4096 + w * 1024);
            gload_lds16(Bt + (size_t)(n0 + row) * K + k0 + q * 8,
                        (char*)Bs + i * 4096 + w * 1024);
        }
        __syncthreads();
        bf16x8 af[4], bfr[4];
        int lr = ln & 15, kc = (ln >> 4) * 8;
        #pragma unroll
        for (int mi = 0; mi < 4; ++mi)
            af[mi] = *(const bf16x8*)&As[(wr * 64 + mi * 16 + lr) * 32 + kc];
        #pragma unroll
        for (int ni = 0; ni < 4; ++ni)
            bfr[ni] = *(const bf16x8*)&Bs[(wc * 64 + ni * 16 + lr) * 32 + kc];
        #pragma unroll
        for (int mi = 0; mi < 4; ++mi)
            #pragma unroll
            for (int ni = 0; ni < 4; ++ni)
                acc[mi][ni] = __builtin_amdgcn_mfma_f32_16x16x32_bf16(
                    af[mi], bfr[ni], acc[mi][ni], 0, 0, 0);
        __syncthreads();
    }
    int rb = (ln >> 4) * 4, cb = ln & 15;
    #pragma unroll
    for (int mi = 0; mi < 4; ++mi) {
        #pragma unroll
        for (int ni = 0; ni < 4; ++ni) {
            int col = n0 + wc * 64 + ni * 16 + cb;
            int h = col >> 6, e = col & 63;
            #pragma unroll
            for (int j = 0; j < 4; ++j) {
                int row = m0 + wr * 64 + mi * 16 + rb + j;
                int b = row >> 6, r = row & 63, m = r >> 1;
                float v = acc[mi][ni][j];
                int off = (h * 32 + m) * 2048 + e * 32 + b;
                if ((r & 1) == 0)
                    XGr[off] = v + (md.v[m] == 0 ? 512.f * bq[col] : 0.f);
                else
                    XGi[off] = -v;
            }
        }
    }
}

// ---------------- bf16 MFMA GEMM: C = epi(A[M,K] @ Bt[N,K]^T + bias) ---------------------
template<int EPI>
__global__ __launch_bounds__(256) void k_mm(const __hip_bfloat16* __restrict__ A,
        const __hip_bfloat16* __restrict__ Bt, const float* __restrict__ bias,
        float* __restrict__ C, __hip_bfloat16* __restrict__ Cb, int M, int N, int K) {
    __shared__ __hip_bfloat16 As[128 * 32];
    __shared__ __hip_bfloat16 Bs[128 * 32];
    int t = threadIdx.x;
    int m0 = blockIdx.x * 128, n0 = blockIdx.y * 128;
    int w = t >> 6, ln = t & 63;
    int wr = w >> 1, wc = w & 1;
    f32x4 acc[4][4] = {};
    for (int k0 = 0; k0 < K; k0 += 32) {
        #pragma unroll
        for (int i = 0; i < 2; ++i) {
            int s = i * 256 + t;
            int row = s >> 2, q = s & 3;
            gload_lds16(A + (size_t)(m0 + row) * K + k0 + q * 8,
                        (char*)As + i * 4096 + w * 1024);
            gload_lds16(Bt + (size_t)(n0 + row) * K + k0 + q * 8,
                        (char*)Bs + i * 4096 + w * 1024);
        }
        __syncthreads();
        bf16x8 af[4], bfr[4];
        int lr = ln & 15, kc = (ln >> 4) * 8;
        #pragma unroll
        for (int mi = 0; mi < 4; ++mi)
            af[mi] = *(const bf16x8*)&As[(wr * 64 + mi * 16 + lr) * 32 + kc];
        #pragma unroll
        for (int ni = 0; ni < 4; ++ni)
            bfr[ni] = *(const bf16x8*)&Bs[(wc * 64 + ni * 16 + lr) * 32 + kc];
        #pragma unroll
        for (int mi = 0; mi < 4; ++mi)
            #pragma unroll
            for (int ni = 0; ni < 4; ++ni)
                acc[mi][ni] = __builtin_amdgcn_mfma_f32_16x16x32_bf16(
                    af[mi], bfr[ni], acc[mi][ni], 0, 0, 0);
        __syncthreads();
    }
    int rb = (ln >> 4) * 4, cb = ln & 15;
    #pragma unroll
    for (int mi = 0; mi < 4; ++mi) {
        #pragma unroll
        for (int ni = 0; ni < 4; ++ni) {
            int col = n0 + wc * 64 + ni * 16 + cb;
            int rowb = m0 + wr * 64 + mi * 16 + rb;
            float bv = (EPI == 0) ? bias[col] : 0.f;
            #pragma unroll
            for (int j = 0; j < 4; ++j) {
                float v = acc[mi][ni][j] + bv;
                size_t off = (size_t)(rowb + j) * N + col;
                if (EPI == 1) Cb[off] = __float2bfloat16(gelu_f(v));
                else C[off] = v;
            }
        }
    }
}

// ---------------- og: per (h,m) complex GEMM, weights read once --------------------------
__global__ __launch_bounds__(256) void k_og(const float* __restrict__ XGr,
        const float* __restrict__ XGi, const float2* __restrict__ WM,
        float* __restrict__ OGr, float* __restrict__ OGi) {
    int hm = blockIdx.x;
    int t = threadIdx.x;
    __shared__ float2 sw[4096];
    __shared__ float sxr[2048], sxi[2048];
    const float2* w = WM + (size_t)hm * 4096;
    for (int i = t; i < 4096; i += 256) sw[i] = w[i];
    const float* xr = XGr + hm * 2048;
    const float* xi = XGi + hm * 2048;
    for (int i = t; i < 2048; i += 256) { sxr[i] = xr[i]; sxi[i] = xi[i]; }
    __syncthreads();
    int b = t >> 3, o0 = (t & 7) * 8;
    float ar[8] = {}, ai[8] = {};
    for (int e = 0; e < 64; ++e) {
        float xrv = sxr[e * 32 + b], xiv = sxi[e * 32 + b];
        #pragma unroll
        for (int j = 0; j < 8; ++j) {
            float2 wv = sw[e * 64 + o0 + j];
            ar[j] = fmaf(xrv, wv.x, fmaf(-xiv, wv.y, ar[j]));
            ai[j] = fmaf(xrv, wv.y, fmaf( xiv, wv.x, ai[j]));
        }
    }
    int base = hm * 2048 + b * 64 + o0;
    #pragma unroll
    for (int j = 0; j < 8; ++j) {
        OGr[base + j] = ar[j];
        OGi[base + j] = ai[j];
    }
}

// ---------------- irfft with dense 32-bin prefix; Im(bin0) dropped; bf16 out -------------
__global__ void k_irfft(const float* __restrict__ OGr, const float* __restrict__ OGi,
                        const float* __restrict__ ST, __hip_bfloat16* __restrict__ O) {
    int bi = blockIdx.x;
    int t = threadIdx.x;
    __shared__ float gr[NM], gi[NM], s_sin[LL];
    int b = bi >> 9, d = bi & 511, h = d >> 6, o = d & 63;
    if (t < NM) {
        gr[t] = OGr[(h * 32 + t) * 2048 + b * 64 + o];
        gi[t] = OGi[(h * 32 + t) * 2048 + b * 64 + o];
    }
    for (int i = t; i < LL; i += 64) s_sin[i] = ST[i];
    __syncthreads();
    for (int l = t; l < LL; l += 64) {
        float acc = gr[0];
        #pragma unroll
        for (int m = 1; m < NM; ++m) {
            int r = (m * l) & 511;
            acc += 2.f * (gr[m] * s_sin[(r + 128) & 511] - gi[m] * s_sin[r]);
        }
        O[(size_t)bi * LL + l] = __float2bfloat16(acc * (1.0f / 512.0f));
    }
}

// ---------------- s = P + Q; out = s - movavg25(s); dual fp32+bf16, L-chunked ------------
__global__ void k_add_decomp(const float* __restrict__ P, const float* __restrict__ Q,
                             float* __restrict__ Out, __hip_bfloat16* __restrict__ Outb) {
    int b = blockIdx.x >> 3;
    int l0 = (blockIdx.x & 7) * 64;
    int d = threadIdx.x;
    const float* p = P + (size_t)b * LL * DD + d;
    const float* q = Q + (size_t)b * LL * DD + d;
    float* o = Out + (size_t)b * LL * DD + d;
    __hip_bfloat16* ob = Outb + (size_t)b * LL * DD + d;
    float sum = 0.f;
    for (int j = l0 - 12; j <= l0 + 12; ++j) {
        int jc = j < 0 ? 0 : (j > 511 ? 511 : j);
        sum += p[jc * DD] + q[jc * DD];
    }
    for (int l = l0; l < l0 + 64; ++l) {
        float sv = p[l * DD] + q[l * DD];
        float r = sv - sum * (1.0f / 25.0f);
        o[l * DD] = r;
        ob[l * DD] = __float2bfloat16(r);
        int lp = l + 13 > 511 ? 511 : l + 13;
        int lm = l - 12 < 0 ? 0 : l - 12;
        sum += (p[lp * DD] + q[lp * DD]) - (p[lm * DD] + q[lm * DD]);
    }
}

// ---------------- LayerNorm over D ----------------
__global__ void k_ln(const float* __restrict__ Xin, const float* __restrict__ lw,
                     const float* __restrict__ lb, float* __restrict__ Out) {
    int row = blockIdx.x;
    int t = threadIdx.x;
    const float4* x4 = (const float4*)(Xin + (size_t)row * DD);
    float4 v0 = x4[t], v1 = x4[t + 64];
    float s = v0.x + v0.y + v0.z + v0.w + v1.x + v1.y + v1.z + v1.w;
    #pragma unroll
    for (int o = 32; o; o >>= 1) s += __shfl_down(s, o);
    float mu = __shfl(s, 0) * (1.0f / 512.0f);
    float d0 = v0.x - mu, d1 = v0.y - mu, d2 = v0.z - mu, d3 = v0.w - mu;
    float d4 = v1.x - mu, d5 = v1.y - mu, d6 = v1.z - mu, d7 = v1.w - mu;
    float vs = d0*d0 + d1*d1 + d2*d2 + d3*d3 + d4*d4 + d5*d5 + d6*d6 + d7*d7;
    #pragma unroll
    for (int o = 32; o; o >>= 1) vs += __shfl_down(vs, o);
    float var = __shfl(vs, 0) * (1.0f / 512.0f);
    float rstd = rsqrtf(var + 1e-5f);
    float4 w0 = ((const float4*)lw)[t], w1 = ((const float4*)lw)[t + 64];
    float4 b0 = ((const float4*)lb)[t], b1 = ((const float4*)lb)[t + 64];
    float4 r0, r1;
    r0.x = d0 * rstd * w0.x + b0.x; r0.y = d1 * rstd * w0.y + b0.y;
    r0.z = d2 * rstd * w0.z + b0.z; r0.w = d3 * rstd * w0.w + b0.w;
    r1.x = d4 * rstd * w1.x + b1.x; r1.y = d5 * rstd * w1.y + b1.y;
    r1.z = d6 * rstd * w1.z + b1.z; r1.w = d7 * rstd * w1.w + b1.w;
    float4* o4 = (float4*)(Out + (size_t)row * DD);
    o4[t] = r0; o4[t + 64] = r1;
}

// ---------------- column (temporal) mean over L per (b,d) ----------------
__global__ void k_colmean(const float* __restrict__ A, float* __restrict__ CM) {
    int tid = blockIdx.x * blockDim.x + threadIdx.x;
    int b = tid >> 9, d = tid & 511;
    const float* a = A + (size_t)b * LL * DD + d;
    float s = 0.f;
    for (int l = 0; l < LL; ++l) s += a[l * DD];
    CM[tid] = s * (1.0f / 512.0f);
}

__global__ void k_gelu_sub(float* __restrict__ A, const float* __restrict__ CM) {
    int i = blockIdx.x * 256 + threadIdx.x;
    int b = i >> 18, d = i & 511;
    float v = A[i] - CM[(b << 9) | d];
    A[i] = gelu_f(v);
}

// ---------------- final projection [B, L*D] @ [L*D, 10] ----------------
__global__ __launch_bounds__(256) void k_proj_partial(const float* __restrict__ A,
        const float* __restrict__ PW, float* __restrict__ PP) {
    int b = blockIdx.x, c = blockIdx.y;
    int t = threadIdx.x;
    float acc[NCC] = {};
    const float* a = A + (size_t)b * LL * DD;
    int i0 = c * 16384, i1 = i0 + 16384;
    for (int i = i0 + t; i < i1; i += 256) {
        float v = a[i];
        const float* w = PW + (size_t)i * NCC;
        #pragma unroll
        for (int n = 0; n < NCC; ++n) acc[n] = fmaf(v, w[n], acc[n]);
    }
    __shared__ float red[4][NCC];
    int lane = t & 63, wv = t >> 6;
    #pragma unroll
    for (int n = 0; n < NCC; ++n) {
        float s = acc[n];
        #pragma unroll
        for (int o = 32; o; o >>= 1) s += __shfl_down(s, o);
        if (lane == 0) red[wv][n] = s;
    }
    __syncthreads();
    if (t < NCC) {
        PP[(b * 16 + c) * NCC + t] = red[0][t] + red[1][t] + red[2][t] + red[3][t];
    }
}

__global__ void k_proj_final(const float* __restrict__ PP, const float* __restrict__ pb,
                             float* __restrict__ out) {
    int t = threadIdx.x;
    if (t >= BB * NCC) return;
    int b = t / NCC, n = t % NCC;
    float s = pb[n];
    for (int c = 0; c < 16; ++c) s += PP[(b * 16 + c) * NCC + n];
    out[t] = s;
}

// ---------------- numpy legacy RandomState(0) modes replication ----------------
static void compute_modes(int* out) {
    static uint32_t mt[624];
    uint32_t s = 0u;
    mt[0] = s;
    for (int i = 1; i < 624; ++i)
        mt[i] = 1812433253u * (mt[i - 1] ^ (mt[i - 1] >> 30)) + (uint32_t)i;
    int mti = 624;
    auto genrand = [&]() -> uint32_t {
        if (mti >= 624) {
            for (int k = 0; k < 624; ++k) {
                uint32_t y = (mt[k] & 0x80000000u) | (mt[(k + 1) % 624] & 0x7fffffffu);
                mt[k] = mt[(k + 397) % 624] ^ (y >> 1) ^ ((y & 1u) ? 2567483615u : 0u);
            }
            mti = 0;
        }
        uint32_t y = mt[mti++];
        y ^= y >> 11;
        y ^= (y << 7) & 2636928640u;
        y ^= (y << 15) & 4022730752u;
        y ^= y >> 18;
        return y;
    };
    int idx[256];
    for (int i = 0; i < 256; ++i) idx[i] = i;
    for (int i = 255; i >= 1; --i) {
        uint32_t mx = (uint32_t)i;
        uint32_t mask = mx;
        mask |= mask >> 1; mask |= mask >> 2; mask |= mask >> 4;
        mask |= mask >> 8; mask |= mask >> 16;
        uint32_t j;
        while ((j = (genrand() & mask)) > mx) {}
        int tmp = idx[i]; idx[i] = idx[j]; idx[j] = tmp;
    }
    int sel[NM];
    for (int i = 0; i < NM; ++i) sel[i] = idx[i];
    std::sort(sel, sel + NM);
    for (int i = 0; i < NM; ++i) out[i] = sel[i];
}

extern "C" void kernel_launch(void* const* d_in, const int* in_sizes, int n_in,
                              void* d_out, int out_size, void* d_ws, size_t ws_size,
                              hipStream_t stream) {
    const float* xe  = (const float*)d_in[0];
    const float* tw  = (const float*)d_in[1];
    const float* Wq  = (const float*)d_in[2];
    const float* bq  = (const float*)d_in[3];
    const float* Wo  = (const float*)d_in[8];
    const float* bo  = (const float*)d_in[9];
    const float* fwr = (const float*)d_in[10];
    const float* fwi = (const float*)d_in[11];
    const float* W1  = (const float*)d_in[12];
    const float* W2  = (const float*)d_in[13];
    const float* lw  = (const float*)d_in[14];
    const float* lb  = (const float*)d_in[15];
    const float* pw  = (const float*)d_in[16];
    const float* pb  = (const float*)d_in[17];
    float* out = (float*)d_out;

    const size_t NX = (size_t)BB * LL * DD;        // 8388608
    const size_t NHF = (size_t)BB * LL * NDFF;     // 33554432
    const size_t NXG = (size_t)BB * NH * EHH * NM; // 524288
    const size_t NWT = (size_t)NDFF * DD;          // 1048576
    const size_t NWM = (size_t)NH * NM * EHH * EHH;// 1048576 float2

    char* wsb = (char*)d_ws;
    size_t off = 0;
    float* X1  = (float*)(wsb + off); off += NX * 4;
    float* X2  = (float*)(wsb + off); off += NX * 4;
    float* TB  = (float*)(wsb + off); off += NX * 4;
    float* XGr = (float*)(wsb + off); off += NXG * 4;
    float* XGi = (float*)(wsb + off); off += NXG * 4;
    float* OGr = (float*)(wsb + off); off += NXG * 4;
    float* OGi = (float*)(wsb + off); off += NXG * 4;
    __hip_bfloat16* X1b = (__hip_bfloat16*)(wsb + off); off += NX * 2;
    __hip_bfloat16* X2b = (__hip_bfloat16*)(wsb + off); off += NX * 2;
    __hip_bfloat16* Ob  = (__hip_bfloat16*)(wsb + off); off += NX * 2;
    __hip_bfloat16* HMb = (__hip_bfloat16*)(wsb + off); off += NHF * 2;
    __hip_bfloat16* WT  = (__hip_bfloat16*)(wsb + off); off += NWT * 2;
    float2* WM          = (float2*)(wsb + off);         off += NWM * 8;
    __hip_bfloat16* TXb = (__hip_bfloat16*)(wsb + off); off += (size_t)BB * 64 * 512 * 2;
    __hip_bfloat16* Tb  = (__hip_bfloat16*)(wsb + off); off += (size_t)64 * 512 * 2;
    float* ST           = (float*)(wsb + off);          off += 512 * 4;
    if (ws_size < off) return;

    // XTb (16.8 MB) aliases TB (33.5 MB): TB is dead from layer start until the Wo GEMM.
    __hip_bfloat16* XTb = (__hip_bfloat16*)TB;

    Modes mi;
    compute_modes(mi.v);

    k_embed<<<dim3(16, 2, BB), 256, 0, stream>>>(xe, tw, X1, X1b);
    k_tgen<<<64, 64, 0, stream>>>(Tb, mi);
    k_stab<<<8, 64, 0, stream>>>(ST);

    float* cur = X1;            float* alt = X2;
    __hip_bfloat16* curb = X1b; __hip_bfloat16* altb = X2b;
    const int M = BB * LL;      // 16384

    for (int li = 0; li < NEL; ++li) {
        // ---- fourier weight transpose for this layer ----
        k_wfm<<<NH * EHH, 256, 0, stream>>>(fwr, fwi, WM, li);
        // ---- X^T bf16 ----
        k_xt<<<dim3(8, 8, BB), 256, 0, stream>>>(cur, XTb);
        // ---- TX = T @ X[b] (contraction over l) ----
        k_tx<<<dim3(BB, 4), 256, 0, stream>>>(Tb, XTb, TXb);
        // ---- XG = TX @ Wq (+bias), scattered into [hm][e*32+b] ----
        k_wt<<<dim3(DD / 32, DD / 32), 256, 0, stream>>>(Wq + (size_t)li * DD * DD, WT, DD, DD);
        k_xg<<<dim3(16, 4), 256, 0, stream>>>(TXb, WT, bq + li * DD, XGr, XGi, mi);
        // ---- per-(h,m) complex GEMM ----
        k_og<<<NH * NM, 256, 0, stream>>>(XGr, XGi, WM, OGr, OGi);
        // ---- irfft -> Ob [B,(h,e),L] bf16 ----
        k_irfft<<<BB * DD, 64, 0, stream>>>(OGr, OGi, ST, Ob);
        // ---- new_x = Ob @ Wo + bo -> TB fp32 ----
        k_wt<<<dim3(DD / 32, DD / 32), 256, 0, stream>>>(Wo + (size_t)li * DD * DD, WT, DD, DD);
        k_mm<0><<<dim3(M / 128, DD / 128), 256, 0, stream>>>(Ob, WT, bo + li * DD,
                                                             TB, nullptr, M, DD, DD);
        // ---- x = decomp(x + new_x) ----
        k_add_decomp<<<BB * 8, DD, 0, stream>>>(cur, TB, alt, altb);
        { float* t_ = cur; cur = alt; alt = t_; }
        { __hip_bfloat16* t_ = curb; curb = altb; altb = t_; }
        // ---- FFN ----
        k_wt<<<dim3(NDFF / 32, DD / 32), 256, 0, stream>>>(W1 + (size_t)li * DD * NDFF, WT, DD, NDFF);
        k_mm<1><<<dim3(M / 128, NDFF / 128), 256, 0, stream>>>(curb, WT, nullptr,
                                                               nullptr, HMb, M, NDFF, DD);
        k_wt<<<dim3(DD / 32, NDFF / 32), 256, 0, stream>>>(W2 + (size_t)li * NDFF * DD, WT, NDFF, DD);
        k_mm<2><<<dim3(M / 128, DD / 128), 256, 0, stream>>>(HMb, WT, nullptr,
                                                             TB, nullptr, M, DD, NDFF);
        k_add_decomp<<<BB * 8, DD, 0, stream>>>(cur, TB, alt, altb);
        { float* t_ = cur; cur = alt; alt = t_; }
        { __hip_bfloat16* t_ = curb; curb = altb; altb = t_; }
    }

    // ---- final: LayerNorm -> subtract temporal mean -> gelu -> projection ----
    k_ln<<<BB * LL, 64, 0, stream>>>(cur, lw, lb, TB);
    float* CM = XGr;
    float* PP = XGi;
    k_colmean<<<64, 256, 0, stream>>>(TB, CM);
    k_gelu_sub<<<32768, 256, 0, stream>>>(TB, CM);
    k_proj_partial<<<dim3(BB, 16), 256, 0, stream>>>(TB, pw, PP);
    k_proj_final<<<1, 320, 0, stream>>>(PP, pb, out);
}

// Round 6
// 1047.517 us; speedup vs baseline: 5.5436x; 1.2388x over previous
//
#include <hip/hip_runtime.h>
#include <hip/hip_bf16.h>
#include <stdint.h>
#include <algorithm>

#define BB  32
#define LL  512
#define NCI 21
#define DD  512
#define NH  8
#define EHH 64
#define NDFF 2048
#define NM  32
#define NEL 3
#define NCC 10

struct Modes { int v[NM]; };

typedef __bf16 bf16x8 __attribute__((ext_vector_type(8)));
typedef float f32x4 __attribute__((ext_vector_type(4)));

__device__ __forceinline__ float gelu_f(float x) {
    return 0.5f * x * (1.0f + erff(x * 0.7071067811865475f));
}

__device__ __forceinline__ void gload_lds16(const void* g, void* l) {
    __builtin_amdgcn_global_load_lds((const __attribute__((address_space(1))) void*)g,
                                     (__attribute__((address_space(3))) void*)l, 16, 0, 0);
}

// ---------------- embedding: circular conv1d(k=3) + positional encoding (dual write) -----
__global__ void k_embed(const float* __restrict__ xe, const float* __restrict__ tw,
                        float* __restrict__ X, __hip_bfloat16* __restrict__ Xb) {
    int lc = blockIdx.x;
    int dh = blockIdx.y;
    int b  = blockIdx.z;
    int t  = threadIdx.x;
    int d  = dh * 256 + t;
    __shared__ float s_xe[34][NCI];
    int l0 = lc * 32;
    for (int i = t; i < 34 * NCI; i += 256) {
        int r = i / NCI, c = i % NCI;
        int ls = (l0 - 1 + r + LL) & (LL - 1);
        s_xe[r][c] = xe[(b * LL + ls) * NCI + c];
    }
    __syncthreads();
    int a = d & ~1;
    float freq = expf((float)a * (-9.210340371976184f / 512.0f));
    for (int li = 0; li < 32; ++li) {
        int l = l0 + li;
        float acc = 0.f;
        #pragma unroll
        for (int k = 0; k < 3; ++k)
            for (int c = 0; c < NCI; ++c)
                acc = fmaf(s_xe[li + k][c], tw[(k * NCI + c) * DD + d], acc);
        float v = (float)l * freq;
        float pe = (d & 1) ? cosf(v) : sinf(v);
        float r = acc + pe;
        size_t off = ((size_t)(b * LL + l)) * DD + d;
        X[off] = r;
        Xb[off] = __float2bfloat16(r);
    }
}

// ---------------- weight convert+transpose: W[K][N] fp32 -> WT[N][K] bf16 ----------------
__global__ void k_wt(const float* __restrict__ W, __hip_bfloat16* __restrict__ WT,
                     int K, int N) {
    __shared__ float s[32][33];
    int bx = blockIdx.x;
    int by = blockIdx.y;
    int t = threadIdx.x;
    int r = t >> 5, c = t & 31;
    #pragma unroll
    for (int i = 0; i < 4; ++i)
        s[r + i * 8][c] = W[(size_t)(by * 32 + r + i * 8) * N + bx * 32 + c];
    __syncthreads();
    #pragma unroll
    for (int i = 0; i < 4; ++i) {
        int n = bx * 32 + r + i * 8;
        WT[(size_t)n * K + by * 32 + c] = __float2bfloat16(s[c][r + i * 8]);
    }
}

// ---------------- fourier weight transpose: fw[h,e,o,m] -> WM[h][m][e][o] float2 ---------
__global__ void k_wfm(const float* __restrict__ fwr, const float* __restrict__ fwi,
                      float2* __restrict__ WM, int li) {
    int blk = blockIdx.x;        // h*64 + e
    int h = blk >> 6, e = blk & 63;
    int t = threadIdx.x;
    __shared__ float2 s[32][65];
    const float* br = fwr + (((size_t)(li * NH + h) * EHH + e) * EHH) * NM;
    const float* bi = fwi + (((size_t)(li * NH + h) * EHH + e) * EHH) * NM;
    for (int i = t; i < 2048; i += 256) {
        int o = i >> 5, m = i & 31;
        s[m][o] = make_float2(br[i], bi[i]);
    }
    __syncthreads();
    int mr = t >> 6, o = t & 63;
    for (int m = mr; m < 32; m += 4)
        WM[((size_t)(h * 32 + m)) * 4096 + e * 64 + o] = s[m][o];
}

// ---------------- twiddle matrix: T[2m][l]=cos(w0*im*l), T[2m+1][l]=sin ------------------
__global__ void k_tgen(__hip_bfloat16* __restrict__ Tb, Modes md) {
    int r = blockIdx.x;          // 64
    int m = r >> 1;
    int im = md.v[m];
    const float w0 = 6.283185307179586f / 512.0f;
    for (int l = threadIdx.x; l < LL; l += 64) {
        int red = (im * l) & 511;
        float ang = w0 * (float)red;
        float v = (r & 1) ? sinf(ang) : cosf(ang);
        Tb[r * 512 + l] = __float2bfloat16(v);
    }
}

// ---------------- synthesis matrix (k-major): Sk[k][l] ----------------------------------
// Sk[2m][l]=cos(w0 m l)*(2-d_m0)/512, Sk[2m+1][l]=-2 sin(w0 m l)/512 (m=0 row is 0:
// pocketfft drops Im(bin 0)).
__global__ void k_sgen(__hip_bfloat16* __restrict__ Sk) {
    int k = blockIdx.x;          // 64
    int m = k >> 1;
    const float w0 = 6.283185307179586f / 512.0f;
    for (int l = threadIdx.x; l < LL; l += 64) {
        int red = (m * l) & 511;
        float ang = w0 * (float)red;
        float v;
        if ((k & 1) == 0) v = cosf(ang) * (m == 0 ? (1.0f / 512.0f) : (2.0f / 512.0f));
        else              v = -sinf(ang) * (2.0f / 512.0f);
        Sk[k * 512 + l] = __float2bfloat16(v);
    }
}

// ---------------- transpose: X[b][l][d] fp32 -> XT[b][d][l] bf16 -------------------------
__global__ __launch_bounds__(256) void k_xt(const float* __restrict__ X,
                                            __hip_bfloat16* __restrict__ XT) {
    int b = blockIdx.z;
    int l0 = blockIdx.x * 64, d0 = blockIdx.y * 64;
    __shared__ float s[64][65];
    const float* xb = X + (size_t)b * LL * DD;
    int t = threadIdx.x;
    #pragma unroll
    for (int i = 0; i < 16; ++i) {
        int e = i * 256 + t;
        int lr = e >> 6, dc = e & 63;
        s[lr][dc] = xb[(size_t)(l0 + lr) * DD + d0 + dc];
    }
    __syncthreads();
    __hip_bfloat16* xt = XT + (size_t)b * DD * LL;
    #pragma unroll
    for (int i = 0; i < 16; ++i) {
        int e = i * 256 + t;
        int dr = e >> 6, lc = e & 63;
        xt[(size_t)(d0 + dr) * LL + l0 + lc] = __float2bfloat16(s[lc][dr]);
    }
}

// ---------------- TX[b] = T[64x512] @ XT[b] (contraction over l) -------------------------
__global__ __launch_bounds__(256) void k_tx(const __hip_bfloat16* __restrict__ Tb,
        const __hip_bfloat16* __restrict__ XT, __hip_bfloat16* __restrict__ TX) {
    __shared__ __hip_bfloat16 Ts[64 * 32];
    __shared__ __hip_bfloat16 Xs[128 * 32];
    int b = blockIdx.x, n0 = blockIdx.y * 128;
    int t = threadIdx.x, w = t >> 6, ln = t & 63;
    const __hip_bfloat16* xb = XT + (size_t)b * DD * LL;
    f32x4 acc[4][2] = {};
    for (int k0 = 0; k0 < 512; k0 += 32) {
        {
            int row = w * 16 + (ln >> 2), q = ln & 3;
            gload_lds16(Tb + row * 512 + k0 + q * 8, (char*)Ts + w * 1024);
        }
        #pragma unroll
        for (int i = 0; i < 2; ++i) {
            int s = i * 256 + t;
            int row = s >> 2, q = s & 3;
            gload_lds16(xb + (size_t)(n0 + row) * LL + k0 + q * 8,
                        (char*)Xs + i * 4096 + w * 1024);
        }
        __syncthreads();
        int lr = ln & 15, kc = (ln >> 4) * 8;
        bf16x8 af[4], bfr[2];
        #pragma unroll
        for (int mi = 0; mi < 4; ++mi)
            af[mi] = *(const bf16x8*)&Ts[(mi * 16 + lr) * 32 + kc];
        #pragma unroll
        for (int ni = 0; ni < 2; ++ni)
            bfr[ni] = *(const bf16x8*)&Xs[(w * 32 + ni * 16 + lr) * 32 + kc];
        #pragma unroll
        for (int mi = 0; mi < 4; ++mi)
            #pragma unroll
            for (int ni = 0; ni < 2; ++ni)
                acc[mi][ni] = __builtin_amdgcn_mfma_f32_16x16x32_bf16(
                    af[mi], bfr[ni], acc[mi][ni], 0, 0, 0);
        __syncthreads();
    }
    int rb = (ln >> 4) * 4, cb = ln & 15;
    #pragma unroll
    for (int mi = 0; mi < 4; ++mi)
        #pragma unroll
        for (int ni = 0; ni < 2; ++ni)
            #pragma unroll
            for (int j = 0; j < 4; ++j) {
                int m = mi * 16 + rb + j;
                int col = n0 + w * 32 + ni * 16 + cb;
                TX[(size_t)(b * 64 + m) * 512 + col] =
                    __float2bfloat16(acc[mi][ni][j]);
            }
}

// ---------------- SW = Sk(64k x 512l) @ WoT^T; written transposed SWT[dc][k] -------------
__global__ __launch_bounds__(256) void k_swt(const __hip_bfloat16* __restrict__ Sk,
        const __hip_bfloat16* __restrict__ WT, __hip_bfloat16* __restrict__ SWT) {
    __shared__ __hip_bfloat16 Ts[64 * 32];
    __shared__ __hip_bfloat16 Xs[128 * 32];
    int n0 = blockIdx.x * 128;
    int t = threadIdx.x, w = t >> 6, ln = t & 63;
    f32x4 acc[4][2] = {};
    for (int k0 = 0; k0 < 512; k0 += 32) {
        {
            int row = w * 16 + (ln >> 2), q = ln & 3;
            gload_lds16(Sk + row * 512 + k0 + q * 8, (char*)Ts + w * 1024);
        }
        #pragma unroll
        for (int i = 0; i < 2; ++i) {
            int s = i * 256 + t;
            int row = s >> 2, q = s & 3;
            gload_lds16(WT + (size_t)(n0 + row) * 512 + k0 + q * 8,
                        (char*)Xs + i * 4096 + w * 1024);
        }
        __syncthreads();
        int lr = ln & 15, kc = (ln >> 4) * 8;
        bf16x8 af[4], bfr[2];
        #pragma unroll
        for (int mi = 0; mi < 4; ++mi)
            af[mi] = *(const bf16x8*)&Ts[(mi * 16 + lr) * 32 + kc];
        #pragma unroll
        for (int ni = 0; ni < 2; ++ni)
            bfr[ni] = *(const bf16x8*)&Xs[(w * 32 + ni * 16 + lr) * 32 + kc];
        #pragma unroll
        for (int mi = 0; mi < 4; ++mi)
            #pragma unroll
            for (int ni = 0; ni < 2; ++ni)
                acc[mi][ni] = __builtin_amdgcn_mfma_f32_16x16x32_bf16(
                    af[mi], bfr[ni], acc[mi][ni], 0, 0, 0);
        __syncthreads();
    }
    int rb = (ln >> 4) * 4, cb = ln & 15;
    #pragma unroll
    for (int mi = 0; mi < 4; ++mi)
        #pragma unroll
        for (int ni = 0; ni < 2; ++ni)
            #pragma unroll
            for (int j = 0; j < 4; ++j) {
                int k = mi * 16 + rb + j;
                int col = n0 + w * 32 + ni * 16 + cb;   // dc
                SWT[(size_t)col * 64 + k] = __float2bfloat16(acc[mi][ni][j]);
            }
}

// ---------------- XG = TX @ Wq (+bias for im==0), scatter to [hm][e*32+b] ----------------
__global__ __launch_bounds__(256) void k_xg(const __hip_bfloat16* __restrict__ A,
        const __hip_bfloat16* __restrict__ Bt, const float* __restrict__ bq,
        float* __restrict__ XGr, float* __restrict__ XGi, Modes md) {
    __shared__ __hip_bfloat16 As[128 * 32];
    __shared__ __hip_bfloat16 Bs[128 * 32];
    int t = threadIdx.x;
    int m0 = blockIdx.x * 128, n0 = blockIdx.y * 128;
    int w = t >> 6, ln = t & 63;
    int wr = w >> 1, wc = w & 1;
    const int K = 512;
    f32x4 acc[4][4] = {};
    for (int k0 = 0; k0 < K; k0 += 32) {
        #pragma unroll
        for (int i = 0; i < 2; ++i) {
            int s = i * 256 + t;
            int row = s >> 2, q = s & 3;
            gload_lds16(A + (size_t)(m0 + row) * K + k0 + q * 8,
                        (char*)As + i * 4096 + w * 1024);
            gload_lds16(Bt + (size_t)(n0 + row) * K + k0 + q * 8,
                        (char*)Bs + i * 4096 + w * 1024);
        }
        __syncthreads();
        bf16x8 af[4], bfr[4];
        int lr = ln & 15, kc = (ln >> 4) * 8;
        #pragma unroll
        for (int mi = 0; mi < 4; ++mi)
            af[mi] = *(const bf16x8*)&As[(wr * 64 + mi * 16 + lr) * 32 + kc];
        #pragma unroll
        for (int ni = 0; ni < 4; ++ni)
            bfr[ni] = *(const bf16x8*)&Bs[(wc * 64 + ni * 16 + lr) * 32 + kc];
        #pragma unroll
        for (int mi = 0; mi < 4; ++mi)
            #pragma unroll
            for (int ni = 0; ni < 4; ++ni)
                acc[mi][ni] = __builtin_amdgcn_mfma_f32_16x16x32_bf16(
                    af[mi], bfr[ni], acc[mi][ni], 0, 0, 0);
        __syncthreads();
    }
    int rb = (ln >> 4) * 4, cb = ln & 15;
    #pragma unroll
    for (int mi = 0; mi < 4; ++mi) {
        #pragma unroll
        for (int ni = 0; ni < 4; ++ni) {
            int col = n0 + wc * 64 + ni * 16 + cb;
            int h = col >> 6, e = col & 63;
            #pragma unroll
            for (int j = 0; j < 4; ++j) {
                int row = m0 + wr * 64 + mi * 16 + rb + j;
                int b = row >> 6, r = row & 63, m = r >> 1;
                float v = acc[mi][ni][j];
                int off = (h * 32 + m) * 2048 + e * 32 + b;
                if ((r & 1) == 0)
                    XGr[off] = v + (md.v[m] == 0 ? 512.f * bq[col] : 0.f);
                else
                    XGi[off] = -v;
            }
        }
    }
}

// ---------------- bf16 MFMA GEMM: C = epi(A[M,K] @ Bt[N,K]^T + bias) ---------------------
template<int EPI>
__global__ __launch_bounds__(256) void k_mm(const __hip_bfloat16* __restrict__ A,
        const __hip_bfloat16* __restrict__ Bt, const float* __restrict__ bias,
        float* __restrict__ C, __hip_bfloat16* __restrict__ Cb, int M, int N, int K) {
    __shared__ __hip_bfloat16 As[128 * 32];
    __shared__ __hip_bfloat16 Bs[128 * 32];
    int t = threadIdx.x;
    int m0 = blockIdx.x * 128, n0 = blockIdx.y * 128;
    int w = t >> 6, ln = t & 63;
    int wr = w >> 1, wc = w & 1;
    f32x4 acc[4][4] = {};
    for (int k0 = 0; k0 < K; k0 += 32) {
        #pragma unroll
        for (int i = 0; i < 2; ++i) {
            int s = i * 256 + t;
            int row = s >> 2, q = s & 3;
            gload_lds16(A + (size_t)(m0 + row) * K + k0 + q * 8,
                        (char*)As + i * 4096 + w * 1024);
            gload_lds16(Bt + (size_t)(n0 + row) * K + k0 + q * 8,
                        (char*)Bs + i * 4096 + w * 1024);
        }
        __syncthreads();
        bf16x8 af[4], bfr[4];
        int lr = ln & 15, kc = (ln >> 4) * 8;
        #pragma unroll
        for (int mi = 0; mi < 4; ++mi)
            af[mi] = *(const bf16x8*)&As[(wr * 64 + mi * 16 + lr) * 32 + kc];
        #pragma unroll
        for (int ni = 0; ni < 4; ++ni)
            bfr[ni] = *(const bf16x8*)&Bs[(wc * 64 + ni * 16 + lr) * 32 + kc];
        #pragma unroll
        for (int mi = 0; mi < 4; ++mi)
            #pragma unroll
            for (int ni = 0; ni < 4; ++ni)
                acc[mi][ni] = __builtin_amdgcn_mfma_f32_16x16x32_bf16(
                    af[mi], bfr[ni], acc[mi][ni], 0, 0, 0);
        __syncthreads();
    }
    int rb = (ln >> 4) * 4, cb = ln & 15;
    #pragma unroll
    for (int mi = 0; mi < 4; ++mi) {
        #pragma unroll
        for (int ni = 0; ni < 4; ++ni) {
            int col = n0 + wc * 64 + ni * 16 + cb;
            int rowb = m0 + wr * 64 + mi * 16 + rb;
            float bv = (EPI == 0) ? bias[col] : 0.f;
            #pragma unroll
            for (int j = 0; j < 4; ++j) {
                float v = acc[mi][ni][j] + bv;
                size_t off = (size_t)(rowb + j) * N + col;
                if (EPI == 1) Cb[off] = __float2bfloat16(gelu_f(v));
                else C[off] = v;
            }
        }
    }
}

// ---------------- og: per (h,m) complex GEMM -> OGT[b][he][k=2m|2m+1] bf16 ---------------
__global__ __launch_bounds__(256) void k_og(const float* __restrict__ XGr,
        const float* __restrict__ XGi, const float2* __restrict__ WM,
        __hip_bfloat16* __restrict__ OGT) {
    int hm = blockIdx.x;      // h*32+m
    int t = threadIdx.x;
    __shared__ float2 sw[4096];
    __shared__ float sxr[2048], sxi[2048];
    const float2* w = WM + (size_t)hm * 4096;
    for (int i = t; i < 4096; i += 256) sw[i] = w[i];
    const float* xr = XGr + hm * 2048;
    const float* xi = XGi + hm * 2048;
    for (int i = t; i < 2048; i += 256) { sxr[i] = xr[i]; sxi[i] = xi[i]; }
    __syncthreads();
    int b = t >> 3, o0 = (t & 7) * 8;
    float ar[8] = {}, ai[8] = {};
    for (int e = 0; e < 64; ++e) {
        float xrv = sxr[e * 32 + b], xiv = sxi[e * 32 + b];
        #pragma unroll
        for (int j = 0; j < 8; ++j) {
            float2 wv = sw[e * 64 + o0 + j];
            ar[j] = fmaf(xrv, wv.x, fmaf(-xiv, wv.y, ar[j]));
            ai[j] = fmaf(xrv, wv.y, fmaf( xiv, wv.x, ai[j]));
        }
    }
    int h = hm >> 5, m = hm & 31;
    __hip_bfloat16* og = OGT + (size_t)b * (512 * 64);
    #pragma unroll
    for (int j = 0; j < 8; ++j) {
        int he = h * 64 + o0 + j;
        union { __hip_bfloat16 h2[2]; uint32_t u; } pk;
        pk.h2[0] = __float2bfloat16(ar[j]);
        pk.h2[1] = __float2bfloat16(ai[j]);
        *(uint32_t*)&og[he * 64 + 2 * m] = pk.u;   // (2m even -> 4B aligned)
    }
}

// ---------------- new_x[b][he][dc] = OGT[b](512he x 64k) @ SWT^T + bo --------------------
__global__ __launch_bounds__(256) void k_nx(const __hip_bfloat16* __restrict__ OGT,
        const __hip_bfloat16* __restrict__ SWT, const float* __restrict__ bo,
        float* __restrict__ C) {
    __shared__ __hip_bfloat16 As[128 * 32];
    __shared__ __hip_bfloat16 Bs[128 * 32];
    int t = threadIdx.x;
    int m0 = blockIdx.x * 128, n0 = blockIdx.y * 128, b = blockIdx.z;
    int w = t >> 6, ln = t & 63;
    int wr = w >> 1, wc = w & 1;
    const __hip_bfloat16* ab = OGT + (size_t)b * 512 * 64;
    f32x4 acc[4][4] = {};
    for (int k0 = 0; k0 < 64; k0 += 32) {
        #pragma unroll
        for (int i = 0; i < 2; ++i) {
            int s = i * 256 + t;
            int row = s >> 2, q = s & 3;
            gload_lds16(ab + (size_t)(m0 + row) * 64 + k0 + q * 8,
                        (char*)As + i * 4096 + w * 1024);
            gload_lds16(SWT + (size_t)(n0 + row) * 64 + k0 + q * 8,
                        (char*)Bs + i * 4096 + w * 1024);
        }
        __syncthreads();
        bf16x8 af[4], bfr[4];
        int lr = ln & 15, kc = (ln >> 4) * 8;
        #pragma unroll
        for (int mi = 0; mi < 4; ++mi)
            af[mi] = *(const bf16x8*)&As[(wr * 64 + mi * 16 + lr) * 32 + kc];
        #pragma unroll
        for (int ni = 0; ni < 4; ++ni)
            bfr[ni] = *(const bf16x8*)&Bs[(wc * 64 + ni * 16 + lr) * 32 + kc];
        #pragma unroll
        for (int mi = 0; mi < 4; ++mi)
            #pragma unroll
            for (int ni = 0; ni < 4; ++ni)
                acc[mi][ni] = __builtin_amdgcn_mfma_f32_16x16x32_bf16(
                    af[mi], bfr[ni], acc[mi][ni], 0, 0, 0);
        __syncthreads();
    }
    int rb = (ln >> 4) * 4, cb = ln & 15;
    #pragma unroll
    for (int mi = 0; mi < 4; ++mi) {
        #pragma unroll
        for (int ni = 0; ni < 4; ++ni) {
            int col = n0 + wc * 64 + ni * 16 + cb;
            int he = m0 + wr * 64 + mi * 16 + rb;
            float bv = bo[col];
            #pragma unroll
            for (int j = 0; j < 4; ++j)
                C[((size_t)b * 512 + he + j) * 512 + col] = acc[mi][ni][j] + bv;
        }
    }
}

// ---------------- s = P + Q; out = s - movavg25(s); dual fp32+bf16, L-chunked ------------
__global__ void k_add_decomp(const float* __restrict__ P, const float* __restrict__ Q,
                             float* __restrict__ Out, __hip_bfloat16* __restrict__ Outb) {
    int b = blockIdx.x >> 3;
    int l0 = (blockIdx.x & 7) * 64;
    int d = threadIdx.x;
    const float* p = P + (size_t)b * LL * DD + d;
    const float* q = Q + (size_t)b * LL * DD + d;
    float* o = Out + (size_t)b * LL * DD + d;
    __hip_bfloat16* ob = Outb + (size_t)b * LL * DD + d;
    float sum = 0.f;
    for (int j = l0 - 12; j <= l0 + 12; ++j) {
        int jc = j < 0 ? 0 : (j > 511 ? 511 : j);
        sum += p[jc * DD] + q[jc * DD];
    }
    for (int l = l0; l < l0 + 64; ++l) {
        float sv = p[l * DD] + q[l * DD];
        float r = sv - sum * (1.0f / 25.0f);
        o[l * DD] = r;
        ob[l * DD] = __float2bfloat16(r);
        int lp = l + 13 > 511 ? 511 : l + 13;
        int lm = l - 12 < 0 ? 0 : l - 12;
        sum += (p[lp * DD] + q[lp * DD]) - (p[lm * DD] + q[lm * DD]);
    }
}

// ---------------- LayerNorm over D ----------------
__global__ void k_ln(const float* __restrict__ Xin, const float* __restrict__ lw,
                     const float* __restrict__ lb, float* __restrict__ Out) {
    int row = blockIdx.x;
    int t = threadIdx.x;
    const float4* x4 = (const float4*)(Xin + (size_t)row * DD);
    float4 v0 = x4[t], v1 = x4[t + 64];
    float s = v0.x + v0.y + v0.z + v0.w + v1.x + v1.y + v1.z + v1.w;
    #pragma unroll
    for (int o = 32; o; o >>= 1) s += __shfl_down(s, o);
    float mu = __shfl(s, 0) * (1.0f / 512.0f);
    float d0 = v0.x - mu, d1 = v0.y - mu, d2 = v0.z - mu, d3 = v0.w - mu;
    float d4 = v1.x - mu, d5 = v1.y - mu, d6 = v1.z - mu, d7 = v1.w - mu;
    float vs = d0*d0 + d1*d1 + d2*d2 + d3*d3 + d4*d4 + d5*d5 + d6*d6 + d7*d7;
    #pragma unroll
    for (int o = 32; o; o >>= 1) vs += __shfl_down(vs, o);
    float var = __shfl(vs, 0) * (1.0f / 512.0f);
    float rstd = rsqrtf(var + 1e-5f);
    float4 w0 = ((const float4*)lw)[t], w1 = ((const float4*)lw)[t + 64];
    float4 b0 = ((const float4*)lb)[t], b1 = ((const float4*)lb)[t + 64];
    float4 r0, r1;
    r0.x = d0 * rstd * w0.x + b0.x; r0.y = d1 * rstd * w0.y + b0.y;
    r0.z = d2 * rstd * w0.z + b0.z; r0.w = d3 * rstd * w0.w + b0.w;
    r1.x = d4 * rstd * w1.x + b1.x; r1.y = d5 * rstd * w1.y + b1.y;
    r1.z = d6 * rstd * w1.z + b1.z; r1.w = d7 * rstd * w1.w + b1.w;
    float4* o4 = (float4*)(Out + (size_t)row * DD);
    o4[t] = r0; o4[t + 64] = r1;
}

// ---------------- column (temporal) mean over L per (b,d) ----------------
__global__ void k_colmean(const float* __restrict__ A, float* __restrict__ CM) {
    int tid = blockIdx.x * blockDim.x + threadIdx.x;
    int b = tid >> 9, d = tid & 511;
    const float* a = A + (size_t)b * LL * DD + d;
    float s = 0.f;
    for (int l = 0; l < LL; ++l) s += a[l * DD];
    CM[tid] = s * (1.0f / 512.0f);
}

__global__ void k_gelu_sub(float* __restrict__ A, const float* __restrict__ CM) {
    int i = blockIdx.x * 256 + threadIdx.x;
    int b = i >> 18, d = i & 511;
    float v = A[i] - CM[(b << 9) | d];
    A[i] = gelu_f(v);
}

// ---------------- final projection [B, L*D] @ [L*D, 10] ----------------
__global__ __launch_bounds__(256) void k_proj_partial(const float* __restrict__ A,
        const float* __restrict__ PW, float* __restrict__ PP) {
    int b = blockIdx.x, c = blockIdx.y;
    int t = threadIdx.x;
    float acc[NCC] = {};
    const float* a = A + (size_t)b * LL * DD;
    int i0 = c * 16384, i1 = i0 + 16384;
    for (int i = i0 + t; i < i1; i += 256) {
        float v = a[i];
        const float* w = PW + (size_t)i * NCC;
        #pragma unroll
        for (int n = 0; n < NCC; ++n) acc[n] = fmaf(v, w[n], acc[n]);
    }
    __shared__ float red[4][NCC];
    int lane = t & 63, wv = t >> 6;
    #pragma unroll
    for (int n = 0; n < NCC; ++n) {
        float s = acc[n];
        #pragma unroll
        for (int o = 32; o; o >>= 1) s += __shfl_down(s, o);
        if (lane == 0) red[wv][n] = s;
    }
    __syncthreads();
    if (t < NCC) {
        PP[(b * 16 + c) * NCC + t] = red[0][t] + red[1][t] + red[2][t] + red[3][t];
    }
}

__global__ void k_proj_final(const float* __restrict__ PP, const float* __restrict__ pb,
                             float* __restrict__ out) {
    int t = threadIdx.x;
    if (t >= BB * NCC) return;
    int b = t / NCC, n = t % NCC;
    float s = pb[n];
    for (int c = 0; c < 16; ++c) s += PP[(b * 16 + c) * NCC + n];
    out[t] = s;
}

// ---------------- numpy legacy RandomState(0) modes replication ----------------
static void compute_modes(int* out) {
    static uint32_t mt[624];
    uint32_t s = 0u;
    mt[0] = s;
    for (int i = 1; i < 624; ++i)
        mt[i] = 1812433253u * (mt[i - 1] ^ (mt[i - 1] >> 30)) + (uint32_t)i;
    int mti = 624;
    auto genrand = [&]() -> uint32_t {
        if (mti >= 624) {
            for (int k = 0; k < 624; ++k) {
                uint32_t y = (mt[k] & 0x80000000u) | (mt[(k + 1) % 624] & 0x7fffffffu);
                mt[k] = mt[(k + 397) % 624] ^ (y >> 1) ^ ((y & 1u) ? 2567483615u : 0u);
            }
            mti = 0;
        }
        uint32_t y = mt[mti++];
        y ^= y >> 11;
        y ^= (y << 7) & 2636928640u;
        y ^= (y << 15) & 4022730752u;
        y ^= y >> 18;
        return y;
    };
    int idx[256];
    for (int i = 0; i < 256; ++i) idx[i] = i;
    for (int i = 255; i >= 1; --i) {
        uint32_t mx = (uint32_t)i;
        uint32_t mask = mx;
        mask |= mask >> 1; mask |= mask >> 2; mask |= mask >> 4;
        mask |= mask >> 8; mask |= mask >> 16;
        uint32_t j;
        while ((j = (genrand() & mask)) > mx) {}
        int tmp = idx[i]; idx[i] = idx[j]; idx[j] = tmp;
    }
    int sel[NM];
    for (int i = 0; i < NM; ++i) sel[i] = idx[i];
    std::sort(sel, sel + NM);
    for (int i = 0; i < NM; ++i) out[i] = sel[i];
}

extern "C" void kernel_launch(void* const* d_in, const int* in_sizes, int n_in,
                              void* d_out, int out_size, void* d_ws, size_t ws_size,
                              hipStream_t stream) {
    const float* xe  = (const float*)d_in[0];
    const float* tw  = (const float*)d_in[1];
    const float* Wq  = (const float*)d_in[2];
    const float* bq  = (const float*)d_in[3];
    const float* Wo  = (const float*)d_in[8];
    const float* bo  = (const float*)d_in[9];
    const float* fwr = (const float*)d_in[10];
    const float* fwi = (const float*)d_in[11];
    const float* W1  = (const float*)d_in[12];
    const float* W2  = (const float*)d_in[13];
    const float* lw  = (const float*)d_in[14];
    const float* lb  = (const float*)d_in[15];
    const float* pw  = (const float*)d_in[16];
    const float* pb  = (const float*)d_in[17];
    float* out = (float*)d_out;

    const size_t NX = (size_t)BB * LL * DD;        // 8388608
    const size_t NHF = (size_t)BB * LL * NDFF;     // 33554432
    const size_t NXG = (size_t)BB * NH * EHH * NM; // 524288
    const size_t NWT = (size_t)NDFF * DD;          // 1048576
    const size_t NWM = (size_t)NH * NM * EHH * EHH;// 1048576 float2

    char* wsb = (char*)d_ws;
    size_t off = 0;
    float* X1  = (float*)(wsb + off); off += NX * 4;
    float* X2  = (float*)(wsb + off); off += NX * 4;
    float* TB  = (float*)(wsb + off); off += NX * 4;
    float* XGr = (float*)(wsb + off); off += NXG * 4;
    float* XGi = (float*)(wsb + off); off += NXG * 4;
    __hip_bfloat16* X1b = (__hip_bfloat16*)(wsb + off); off += NX * 2;
    __hip_bfloat16* X2b = (__hip_bfloat16*)(wsb + off); off += NX * 2;
    __hip_bfloat16* HMb = (__hip_bfloat16*)(wsb + off); off += NHF * 2;
    __hip_bfloat16* WT  = (__hip_bfloat16*)(wsb + off); off += NWT * 2;
    float2* WM          = (float2*)(wsb + off);         off += NWM * 8;
    __hip_bfloat16* TXb = (__hip_bfloat16*)(wsb + off); off += (size_t)BB * 64 * 512 * 2;
    __hip_bfloat16* Tb  = (__hip_bfloat16*)(wsb + off); off += (size_t)64 * 512 * 2;
    __hip_bfloat16* OGT = (__hip_bfloat16*)(wsb + off); off += (size_t)BB * 512 * 64 * 2;
    __hip_bfloat16* Sk  = (__hip_bfloat16*)(wsb + off); off += (size_t)64 * 512 * 2;
    __hip_bfloat16* SWT = (__hip_bfloat16*)(wsb + off); off += (size_t)512 * 64 * 2;
    if (ws_size < off) return;

    // XTb (16.8 MB) aliases TB (33.5 MB): TB is dead from layer start until k_nx writes it.
    __hip_bfloat16* XTb = (__hip_bfloat16*)TB;

    Modes mi;
    compute_modes(mi.v);

    k_embed<<<dim3(16, 2, BB), 256, 0, stream>>>(xe, tw, X1, X1b);
    k_tgen<<<64, 64, 0, stream>>>(Tb, mi);
    k_sgen<<<64, 64, 0, stream>>>(Sk);

    float* cur = X1;            float* alt = X2;
    __hip_bfloat16* curb = X1b; __hip_bfloat16* altb = X2b;
    const int M = BB * LL;      // 16384

    for (int li = 0; li < NEL; ++li) {
        // ---- fourier weight transpose for this layer ----
        k_wfm<<<NH * EHH, 256, 0, stream>>>(fwr, fwi, WM, li);
        // ---- X^T bf16 ----
        k_xt<<<dim3(8, 8, BB), 256, 0, stream>>>(cur, XTb);
        // ---- TX = T @ X[b] (contraction over l) ----
        k_tx<<<dim3(BB, 4), 256, 0, stream>>>(Tb, XTb, TXb);
        // ---- XG = TX @ Wq (+bias), scattered into [hm][e*32+b] ----
        k_wt<<<dim3(DD / 32, DD / 32), 256, 0, stream>>>(Wq + (size_t)li * DD * DD, WT, DD, DD);
        k_xg<<<dim3(16, 4), 256, 0, stream>>>(TXb, WT, bq + li * DD, XGr, XGi, mi);
        // ---- per-(h,m) complex GEMM -> OGT[b][he][k] bf16 ----
        k_og<<<NH * NM, 256, 0, stream>>>(XGr, XGi, WM, OGT);
        // ---- SW = S^T @ Wo (batch-independent, 64x512), stored transposed ----
        k_wt<<<dim3(DD / 32, DD / 32), 256, 0, stream>>>(Wo + (size_t)li * DD * DD, WT, DD, DD);
        k_swt<<<4, 256, 0, stream>>>(Sk, WT, SWT);
        // ---- new_x[b][he][dc] = OGT[b] @ SWT^T + bo -> TB ----
        k_nx<<<dim3(4, 4, BB), 256, 0, stream>>>(OGT, SWT, bo + li * DD, TB);
        // ---- x = decomp(x + new_x) ----
        k_add_decomp<<<BB * 8, DD, 0, stream>>>(cur, TB, alt, altb);
        { float* t_ = cur; cur = alt; alt = t_; }
        { __hip_bfloat16* t_ = curb; curb = altb; altb = t_; }
        // ---- FFN ----
        k_wt<<<dim3(NDFF / 32, DD / 32), 256, 0, stream>>>(W1 + (size_t)li * DD * NDFF, WT, DD, NDFF);
        k_mm<1><<<dim3(M / 128, NDFF / 128), 256, 0, stream>>>(curb, WT, nullptr,
                                                               nullptr, HMb, M, NDFF, DD);
        k_wt<<<dim3(DD / 32, NDFF / 32), 256, 0, stream>>>(W2 + (size_t)li * NDFF * DD, WT, NDFF, DD);
        k_mm<2><<<dim3(M / 128, DD / 128), 256, 0, stream>>>(HMb, WT, nullptr,
                                                             TB, nullptr, M, DD, NDFF);
        k_add_decomp<<<BB * 8, DD, 0, stream>>>(cur, TB, alt, altb);
        { float* t_ = cur; cur = alt; alt = t_; }
        { __hip_bfloat16* t_ = curb; curb = altb; altb = t_; }
    }

    // ---- final: LayerNorm -> subtract temporal mean -> gelu -> projection ----
    k_ln<<<BB * LL, 64, 0, stream>>>(cur, lw, lb, TB);
    float* CM = XGr;
    float* PP = XGi;
    k_colmean<<<64, 256, 0, stream>>>(TB, CM);
    k_gelu_sub<<<32768, 256, 0, stream>>>(TB, CM);
    k_proj_partial<<<dim3(BB, 16), 256, 0, stream>>>(TB, pw, PP);
    k_proj_final<<<1, 320, 0, stream>>>(PP, pb, out);
}

// Round 7
// 985.172 us; speedup vs baseline: 5.8944x; 1.0633x over previous
//
#include <hip/hip_runtime.h>
#include <hip/hip_bf16.h>
#include <stdint.h>
#include <algorithm>

#define BB  32
#define LL  512
#define NCI 21
#define DD  512
#define NH  8
#define EHH 64
#define NDFF 2048
#define NM  32
#define NEL 3
#define NCC 10

struct Modes { int v[NM]; };

typedef __bf16 bf16x8 __attribute__((ext_vector_type(8)));
typedef float f32x4 __attribute__((ext_vector_type(4)));

__device__ __forceinline__ float gelu_f(float x) {
    return 0.5f * x * (1.0f + erff(x * 0.7071067811865475f));
}

__device__ __forceinline__ void gload_lds16(const void* g, void* l) {
    __builtin_amdgcn_global_load_lds((const __attribute__((address_space(1))) void*)g,
                                     (__attribute__((address_space(3))) void*)l, 16, 0, 0);
}

// ---------------- embedding: circular conv1d(k=3) + positional encoding (dual write) -----
__global__ void k_embed(const float* __restrict__ xe, const float* __restrict__ tw,
                        float* __restrict__ X, __hip_bfloat16* __restrict__ Xb) {
    int lc = blockIdx.x;
    int dh = blockIdx.y;
    int b  = blockIdx.z;
    int t  = threadIdx.x;
    int d  = dh * 256 + t;
    __shared__ float s_xe[34][NCI];
    int l0 = lc * 32;
    for (int i = t; i < 34 * NCI; i += 256) {
        int r = i / NCI, c = i % NCI;
        int ls = (l0 - 1 + r + LL) & (LL - 1);
        s_xe[r][c] = xe[(b * LL + ls) * NCI + c];
    }
    __syncthreads();
    int a = d & ~1;
    float freq = expf((float)a * (-9.210340371976184f / 512.0f));
    for (int li = 0; li < 32; ++li) {
        int l = l0 + li;
        float acc = 0.f;
        #pragma unroll
        for (int k = 0; k < 3; ++k)
            for (int c = 0; c < NCI; ++c)
                acc = fmaf(s_xe[li + k][c], tw[(k * NCI + c) * DD + d], acc);
        float v = (float)l * freq;
        float pe = (d & 1) ? cosf(v) : sinf(v);
        float r = acc + pe;
        size_t off = ((size_t)(b * LL + l)) * DD + d;
        X[off] = r;
        Xb[off] = __float2bfloat16(r);
    }
}

// ---------------- weight convert+transpose: W[K][N] fp32 -> WT[N][K] bf16 ----------------
__global__ void k_wt(const float* __restrict__ W, __hip_bfloat16* __restrict__ WT,
                     int K, int N) {
    __shared__ float s[32][33];
    int bx = blockIdx.x;
    int by = blockIdx.y;
    int t = threadIdx.x;
    int r = t >> 5, c = t & 31;
    #pragma unroll
    for (int i = 0; i < 4; ++i)
        s[r + i * 8][c] = W[(size_t)(by * 32 + r + i * 8) * N + bx * 32 + c];
    __syncthreads();
    #pragma unroll
    for (int i = 0; i < 4; ++i) {
        int n = bx * 32 + r + i * 8;
        WT[(size_t)n * K + by * 32 + c] = __float2bfloat16(s[c][r + i * 8]);
    }
}

// ---------------- fourier weight transpose: fw[h,e,o,m] -> WM[h][m][e][o] float2 ---------
__global__ void k_wfm(const float* __restrict__ fwr, const float* __restrict__ fwi,
                      float2* __restrict__ WM, int li) {
    int blk = blockIdx.x;        // h*64 + e
    int h = blk >> 6, e = blk & 63;
    int t = threadIdx.x;
    __shared__ float2 s[32][65];
    const float* br = fwr + (((size_t)(li * NH + h) * EHH + e) * EHH) * NM;
    const float* bi = fwi + (((size_t)(li * NH + h) * EHH + e) * EHH) * NM;
    for (int i = t; i < 2048; i += 256) {
        int o = i >> 5, m = i & 31;
        s[m][o] = make_float2(br[i], bi[i]);
    }
    __syncthreads();
    int mr = t >> 6, o = t & 63;
    for (int m = mr; m < 32; m += 4)
        WM[((size_t)(h * 32 + m)) * 4096 + e * 64 + o] = s[m][o];
}

// ---------------- twiddle matrix: T[2m][l]=cos(w0*im*l), T[2m+1][l]=sin ------------------
__global__ void k_tgen(__hip_bfloat16* __restrict__ Tb, Modes md) {
    int r = blockIdx.x;          // 64
    int m = r >> 1;
    int im = md.v[m];
    const float w0 = 6.283185307179586f / 512.0f;
    for (int l = threadIdx.x; l < LL; l += 64) {
        int red = (im * l) & 511;
        float ang = w0 * (float)red;
        float v = (r & 1) ? sinf(ang) : cosf(ang);
        Tb[r * 512 + l] = __float2bfloat16(v);
    }
}

// ---------------- synthesis matrix (k-major): Sk[k][l] ----------------------------------
__global__ void k_sgen(__hip_bfloat16* __restrict__ Sk) {
    int k = blockIdx.x;          // 64
    int m = k >> 1;
    const float w0 = 6.283185307179586f / 512.0f;
    for (int l = threadIdx.x; l < LL; l += 64) {
        int red = (m * l) & 511;
        float ang = w0 * (float)red;
        float v;
        if ((k & 1) == 0) v = cosf(ang) * (m == 0 ? (1.0f / 512.0f) : (2.0f / 512.0f));
        else              v = -sinf(ang) * (2.0f / 512.0f);
        Sk[k * 512 + l] = __float2bfloat16(v);
    }
}

// ---------------- transpose: X[b][l][d] fp32 -> XT[b][d][l] bf16 -------------------------
__global__ __launch_bounds__(256) void k_xt(const float* __restrict__ X,
                                            __hip_bfloat16* __restrict__ XT) {
    int b = blockIdx.z;
    int l0 = blockIdx.x * 64, d0 = blockIdx.y * 64;
    __shared__ float s[64][65];
    const float* xb = X + (size_t)b * LL * DD;
    int t = threadIdx.x;
    #pragma unroll
    for (int i = 0; i < 16; ++i) {
        int e = i * 256 + t;
        int lr = e >> 6, dc = e & 63;
        s[lr][dc] = xb[(size_t)(l0 + lr) * DD + d0 + dc];
    }
    __syncthreads();
    __hip_bfloat16* xt = XT + (size_t)b * DD * LL;
    #pragma unroll
    for (int i = 0; i < 16; ++i) {
        int e = i * 256 + t;
        int dr = e >> 6, lc = e & 63;
        xt[(size_t)(d0 + dr) * LL + l0 + lc] = __float2bfloat16(s[lc][dr]);
    }
}

// ---------------- TX[b] = T[64x512] @ XT[b] (contraction over l) -------------------------
__global__ __launch_bounds__(256) void k_tx(const __hip_bfloat16* __restrict__ Tb,
        const __hip_bfloat16* __restrict__ XT, __hip_bfloat16* __restrict__ TX) {
    __shared__ __hip_bfloat16 Ts[64 * 32];
    __shared__ __hip_bfloat16 Xs[128 * 32];
    int b = blockIdx.x, n0 = blockIdx.y * 128;
    int t = threadIdx.x, w = t >> 6, ln = t & 63;
    const __hip_bfloat16* xb = XT + (size_t)b * DD * LL;
    f32x4 acc[4][2] = {};
    for (int k0 = 0; k0 < 512; k0 += 32) {
        {
            int row = w * 16 + (ln >> 2), q = ln & 3;
            gload_lds16(Tb + row * 512 + k0 + q * 8, (char*)Ts + w * 1024);
        }
        #pragma unroll
        for (int i = 0; i < 2; ++i) {
            int s = i * 256 + t;
            int row = s >> 2, q = s & 3;
            gload_lds16(xb + (size_t)(n0 + row) * LL + k0 + q * 8,
                        (char*)Xs + i * 4096 + w * 1024);
        }
        __syncthreads();
        int lr = ln & 15, kc = (ln >> 4) * 8;
        bf16x8 af[4], bfr[2];
        #pragma unroll
        for (int mi = 0; mi < 4; ++mi)
            af[mi] = *(const bf16x8*)&Ts[(mi * 16 + lr) * 32 + kc];
        #pragma unroll
        for (int ni = 0; ni < 2; ++ni)
            bfr[ni] = *(const bf16x8*)&Xs[(w * 32 + ni * 16 + lr) * 32 + kc];
        #pragma unroll
        for (int mi = 0; mi < 4; ++mi)
            #pragma unroll
            for (int ni = 0; ni < 2; ++ni)
                acc[mi][ni] = __builtin_amdgcn_mfma_f32_16x16x32_bf16(
                    af[mi], bfr[ni], acc[mi][ni], 0, 0, 0);
        __syncthreads();
    }
    int rb = (ln >> 4) * 4, cb = ln & 15;
    #pragma unroll
    for (int mi = 0; mi < 4; ++mi)
        #pragma unroll
        for (int ni = 0; ni < 2; ++ni)
            #pragma unroll
            for (int j = 0; j < 4; ++j) {
                int m = mi * 16 + rb + j;
                int col = n0 + w * 32 + ni * 16 + cb;
                TX[(size_t)(b * 64 + m) * 512 + col] =
                    __float2bfloat16(acc[mi][ni][j]);
            }
}

// ---------------- SW = Sk(64k x 512l) @ WoT^T; written transposed SWT[dc][k] -------------
__global__ __launch_bounds__(256) void k_swt(const __hip_bfloat16* __restrict__ Sk,
        const __hip_bfloat16* __restrict__ WT, __hip_bfloat16* __restrict__ SWT) {
    __shared__ __hip_bfloat16 Ts[64 * 32];
    __shared__ __hip_bfloat16 Xs[128 * 32];
    int n0 = blockIdx.x * 128;
    int t = threadIdx.x, w = t >> 6, ln = t & 63;
    f32x4 acc[4][2] = {};
    for (int k0 = 0; k0 < 512; k0 += 32) {
        {
            int row = w * 16 + (ln >> 2), q = ln & 3;
            gload_lds16(Sk + row * 512 + k0 + q * 8, (char*)Ts + w * 1024);
        }
        #pragma unroll
        for (int i = 0; i < 2; ++i) {
            int s = i * 256 + t;
            int row = s >> 2, q = s & 3;
            gload_lds16(WT + (size_t)(n0 + row) * 512 + k0 + q * 8,
                        (char*)Xs + i * 4096 + w * 1024);
        }
        __syncthreads();
        int lr = ln & 15, kc = (ln >> 4) * 8;
        bf16x8 af[4], bfr[2];
        #pragma unroll
        for (int mi = 0; mi < 4; ++mi)
            af[mi] = *(const bf16x8*)&Ts[(mi * 16 + lr) * 32 + kc];
        #pragma unroll
        for (int ni = 0; ni < 2; ++ni)
            bfr[ni] = *(const bf16x8*)&Xs[(w * 32 + ni * 16 + lr) * 32 + kc];
        #pragma unroll
        for (int mi = 0; mi < 4; ++mi)
            #pragma unroll
            for (int ni = 0; ni < 2; ++ni)
                acc[mi][ni] = __builtin_amdgcn_mfma_f32_16x16x32_bf16(
                    af[mi], bfr[ni], acc[mi][ni], 0, 0, 0);
        __syncthreads();
    }
    int rb = (ln >> 4) * 4, cb = ln & 15;
    #pragma unroll
    for (int mi = 0; mi < 4; ++mi)
        #pragma unroll
        for (int ni = 0; ni < 2; ++ni)
            #pragma unroll
            for (int j = 0; j < 4; ++j) {
                int k = mi * 16 + rb + j;
                int col = n0 + w * 32 + ni * 16 + cb;   // dc
                SWT[(size_t)col * 64 + k] = __float2bfloat16(acc[mi][ni][j]);
            }
}

// ---------------- XG = TX @ Wq (+bias for im==0), scatter to [hm][e*32+b] ----------------
__global__ __launch_bounds__(256) void k_xg(const __hip_bfloat16* __restrict__ A,
        const __hip_bfloat16* __restrict__ Bt, const float* __restrict__ bq,
        float* __restrict__ XGr, float* __restrict__ XGi, Modes md) {
    __shared__ __hip_bfloat16 As[128 * 32];
    __shared__ __hip_bfloat16 Bs[128 * 32];
    int t = threadIdx.x;
    int m0 = blockIdx.x * 128, n0 = blockIdx.y * 128;
    int w = t >> 6, ln = t & 63;
    int wr = w >> 1, wc = w & 1;
    const int K = 512;
    f32x4 acc[4][4] = {};
    for (int k0 = 0; k0 < K; k0 += 32) {
        #pragma unroll
        for (int i = 0; i < 2; ++i) {
            int s = i * 256 + t;
            int row = s >> 2, q = s & 3;
            gload_lds16(A + (size_t)(m0 + row) * K + k0 + q * 8,
                        (char*)As + i * 4096 + w * 1024);
            gload_lds16(Bt + (size_t)(n0 + row) * K + k0 + q * 8,
                        (char*)Bs + i * 4096 + w * 1024);
        }
        __syncthreads();
        bf16x8 af[4], bfr[4];
        int lr = ln & 15, kc = (ln >> 4) * 8;
        #pragma unroll
        for (int mi = 0; mi < 4; ++mi)
            af[mi] = *(const bf16x8*)&As[(wr * 64 + mi * 16 + lr) * 32 + kc];
        #pragma unroll
        for (int ni = 0; ni < 4; ++ni)
            bfr[ni] = *(const bf16x8*)&Bs[(wc * 64 + ni * 16 + lr) * 32 + kc];
        #pragma unroll
        for (int mi = 0; mi < 4; ++mi)
            #pragma unroll
            for (int ni = 0; ni < 4; ++ni)
                acc[mi][ni] = __builtin_amdgcn_mfma_f32_16x16x32_bf16(
                    af[mi], bfr[ni], acc[mi][ni], 0, 0, 0);
        __syncthreads();
    }
    int rb = (ln >> 4) * 4, cb = ln & 15;
    #pragma unroll
    for (int mi = 0; mi < 4; ++mi) {
        #pragma unroll
        for (int ni = 0; ni < 4; ++ni) {
            int col = n0 + wc * 64 + ni * 16 + cb;
            int h = col >> 6, e = col & 63;
            #pragma unroll
            for (int j = 0; j < 4; ++j) {
                int row = m0 + wr * 64 + mi * 16 + rb + j;
                int b = row >> 6, r = row & 63, m = r >> 1;
                float v = acc[mi][ni][j];
                int off = (h * 32 + m) * 2048 + e * 32 + b;
                if ((r & 1) == 0)
                    XGr[off] = v + (md.v[m] == 0 ? 512.f * bq[col] : 0.f);
                else
                    XGi[off] = -v;
            }
        }
    }
}

// ---------------- FFN GEMM: 2-phase dbuf, BK=64, 512 thr (8 waves 2x4), XOR-swizzled LDS -
// EPI 1: gelu -> bf16 Cb; EPI 2: fp32 C.
template<int BM, int BN, int EPI>
__global__ __launch_bounds__(512, 2) void k_ffn(const __hip_bfloat16* __restrict__ A,
        const __hip_bfloat16* __restrict__ Bt, float* __restrict__ C,
        __hip_bfloat16* __restrict__ Cb, int M, int N, int K) {
    constexpr int WRM = BM / 2;          // per-wave rows
    constexpr int WCN = BN / 4;          // per-wave cols
    constexpr int FM = WRM / 16;
    constexpr int FN = WCN / 16;
    constexpr int ABUF = (BM + BN) * 64; // elements per dbuf
    __shared__ __hip_bfloat16 lds[2 * ABUF];
    int t = threadIdx.x, w = t >> 6, ln = t & 63;
    int wr = w >> 2, wc = w & 3;         // 2 x 4 wave grid
    int lr = ln & 15, kc16 = ln >> 4;
    int m0 = blockIdx.x * BM, n0 = blockIdx.y * BN;
    f32x4 acc[FM][FN] = {};

    auto STAGE = [&](int buf, int kt) {
        int kb = kt * 64;
        char* ldsA = (char*)lds + buf * ABUF * 2;
        char* ldsB = ldsA + BM * 128;
        #pragma unroll
        for (int i = 0; i < BM / 64; ++i) {
            int c = i * 512 + t;
            int row = c >> 3, q = c & 7;
            int slot = q ^ (row & 7);
            gload_lds16(A + (size_t)(m0 + row) * K + kb + slot * 8,
                        ldsA + (i * 512 + w * 64) * 16);
        }
        #pragma unroll
        for (int i = 0; i < BN / 64; ++i) {
            int c = i * 512 + t;
            int row = c >> 3, q = c & 7;
            int slot = q ^ (row & 7);
            gload_lds16(Bt + (size_t)(n0 + row) * K + kb + slot * 8,
                        ldsB + (i * 512 + w * 64) * 16);
        }
    };

    STAGE(0, 0);
    __syncthreads();
    int NT = K / 64;
    int cur = 0;
    for (int kt = 0; kt < NT; ++kt) {
        if (kt + 1 < NT) STAGE(cur ^ 1, kt + 1);
        const __hip_bfloat16* As = lds + cur * ABUF;
        const __hip_bfloat16* Bs = As + BM * 64;
        __builtin_amdgcn_s_setprio(1);
        #pragma unroll
        for (int ks = 0; ks < 2; ++ks) {
            bf16x8 a[FM], b[FN];
            #pragma unroll
            for (int mi = 0; mi < FM; ++mi) {
                int row = wr * WRM + mi * 16 + lr;
                int s = (ks * 4 + kc16) ^ (row & 7);
                a[mi] = *(const bf16x8*)&As[row * 64 + s * 8];
            }
            #pragma unroll
            for (int ni = 0; ni < FN; ++ni) {
                int row = wc * WCN + ni * 16 + lr;
                int s = (ks * 4 + kc16) ^ (row & 7);
                b[ni] = *(const bf16x8*)&Bs[row * 64 + s * 8];
            }
            #pragma unroll
            for (int mi = 0; mi < FM; ++mi)
                #pragma unroll
                for (int ni = 0; ni < FN; ++ni)
                    acc[mi][ni] = __builtin_amdgcn_mfma_f32_16x16x32_bf16(
                        a[mi], b[ni], acc[mi][ni], 0, 0, 0);
        }
        __builtin_amdgcn_s_setprio(0);
        __syncthreads();
        cur ^= 1;
    }
    int rb = kc16 * 4;
    #pragma unroll
    for (int mi = 0; mi < FM; ++mi) {
        #pragma unroll
        for (int ni = 0; ni < FN; ++ni) {
            int col = n0 + wc * WCN + ni * 16 + lr;
            int rowb = m0 + wr * WRM + mi * 16 + rb;
            #pragma unroll
            for (int j = 0; j < 4; ++j) {
                float v = acc[mi][ni][j];
                size_t off = (size_t)(rowb + j) * N + col;
                if (EPI == 1) Cb[off] = __float2bfloat16(gelu_f(v));
                else C[off] = v;
            }
        }
    }
}

// ---------------- og: per (h,m) complex GEMM -> OGT[b][he][k=2m|2m+1] bf16 ---------------
__global__ __launch_bounds__(256) void k_og(const float* __restrict__ XGr,
        const float* __restrict__ XGi, const float2* __restrict__ WM,
        __hip_bfloat16* __restrict__ OGT) {
    int hm = blockIdx.x;      // h*32+m
    int t = threadIdx.x;
    __shared__ float2 sw[4096];
    __shared__ float sxr[2048], sxi[2048];
    const float2* w = WM + (size_t)hm * 4096;
    for (int i = t; i < 4096; i += 256) sw[i] = w[i];
    const float* xr = XGr + hm * 2048;
    const float* xi = XGi + hm * 2048;
    for (int i = t; i < 2048; i += 256) { sxr[i] = xr[i]; sxi[i] = xi[i]; }
    __syncthreads();
    int b = t >> 3, o0 = (t & 7) * 8;
    float ar[8] = {}, ai[8] = {};
    for (int e = 0; e < 64; ++e) {
        float xrv = sxr[e * 32 + b], xiv = sxi[e * 32 + b];
        #pragma unroll
        for (int j = 0; j < 8; ++j) {
            float2 wv = sw[e * 64 + o0 + j];
            ar[j] = fmaf(xrv, wv.x, fmaf(-xiv, wv.y, ar[j]));
            ai[j] = fmaf(xrv, wv.y, fmaf( xiv, wv.x, ai[j]));
        }
    }
    int h = hm >> 5, m = hm & 31;
    __hip_bfloat16* og = OGT + (size_t)b * (512 * 64);
    #pragma unroll
    for (int j = 0; j < 8; ++j) {
        int he = h * 64 + o0 + j;
        union { __hip_bfloat16 h2[2]; uint32_t u; } pk;
        pk.h2[0] = __float2bfloat16(ar[j]);
        pk.h2[1] = __float2bfloat16(ai[j]);
        *(uint32_t*)&og[he * 64 + 2 * m] = pk.u;
    }
}

// ---------------- new_x[b][he][dc] = OGT[b](512he x 64k) @ SWT^T + bo --------------------
__global__ __launch_bounds__(256) void k_nx(const __hip_bfloat16* __restrict__ OGT,
        const __hip_bfloat16* __restrict__ SWT, const float* __restrict__ bo,
        float* __restrict__ C) {
    __shared__ __hip_bfloat16 As[128 * 32];
    __shared__ __hip_bfloat16 Bs[128 * 32];
    int t = threadIdx.x;
    int m0 = blockIdx.x * 128, n0 = blockIdx.y * 128, b = blockIdx.z;
    int w = t >> 6, ln = t & 63;
    int wr = w >> 1, wc = w & 1;
    const __hip_bfloat16* ab = OGT + (size_t)b * 512 * 64;
    f32x4 acc[4][4] = {};
    for (int k0 = 0; k0 < 64; k0 += 32) {
        #pragma unroll
        for (int i = 0; i < 2; ++i) {
            int s = i * 256 + t;
            int row = s >> 2, q = s & 3;
            gload_lds16(ab + (size_t)(m0 + row) * 64 + k0 + q * 8,
                        (char*)As + i * 4096 + w * 1024);
            gload_lds16(SWT + (size_t)(n0 + row) * 64 + k0 + q * 8,
                        (char*)Bs + i * 4096 + w * 1024);
        }
        __syncthreads();
        bf16x8 af[4], bfr[4];
        int lr = ln & 15, kc = (ln >> 4) * 8;
        #pragma unroll
        for (int mi = 0; mi < 4; ++mi)
            af[mi] = *(const bf16x8*)&As[(wr * 64 + mi * 16 + lr) * 32 + kc];
        #pragma unroll
        for (int ni = 0; ni < 4; ++ni)
            bfr[ni] = *(const bf16x8*)&Bs[(wc * 64 + ni * 16 + lr) * 32 + kc];
        #pragma unroll
        for (int mi = 0; mi < 4; ++mi)
            #pragma unroll
            for (int ni = 0; ni < 4; ++ni)
                acc[mi][ni] = __builtin_amdgcn_mfma_f32_16x16x32_bf16(
                    af[mi], bfr[ni], acc[mi][ni], 0, 0, 0);
        __syncthreads();
    }
    int rb = (ln >> 4) * 4, cb = ln & 15;
    #pragma unroll
    for (int mi = 0; mi < 4; ++mi) {
        #pragma unroll
        for (int ni = 0; ni < 4; ++ni) {
            int col = n0 + wc * 64 + ni * 16 + cb;
            int he = m0 + wr * 64 + mi * 16 + rb;
            float bv = bo[col];
            #pragma unroll
            for (int j = 0; j < 4; ++j)
                C[((size_t)b * 512 + he + j) * 512 + col] = acc[mi][ni][j] + bv;
        }
    }
}

// ---------------- s = P + Q; out = s - movavg25(s); dual fp32+bf16, L-chunked ------------
__global__ void k_add_decomp(const float* __restrict__ P, const float* __restrict__ Q,
                             float* __restrict__ Out, __hip_bfloat16* __restrict__ Outb) {
    int b = blockIdx.x >> 3;
    int l0 = (blockIdx.x & 7) * 64;
    int d = threadIdx.x;
    const float* p = P + (size_t)b * LL * DD + d;
    const float* q = Q + (size_t)b * LL * DD + d;
    float* o = Out + (size_t)b * LL * DD + d;
    __hip_bfloat16* ob = Outb + (size_t)b * LL * DD + d;
    float sum = 0.f;
    for (int j = l0 - 12; j <= l0 + 12; ++j) {
        int jc = j < 0 ? 0 : (j > 511 ? 511 : j);
        sum += p[jc * DD] + q[jc * DD];
    }
    for (int l = l0; l < l0 + 64; ++l) {
        float sv = p[l * DD] + q[l * DD];
        float r = sv - sum * (1.0f / 25.0f);
        o[l * DD] = r;
        ob[l * DD] = __float2bfloat16(r);
        int lp = l + 13 > 511 ? 511 : l + 13;
        int lm = l - 12 < 0 ? 0 : l - 12;
        sum += (p[lp * DD] + q[lp * DD]) - (p[lm * DD] + q[lm * DD]);
    }
}

// ---------------- LayerNorm over D ----------------
__global__ void k_ln(const float* __restrict__ Xin, const float* __restrict__ lw,
                     const float* __restrict__ lb, float* __restrict__ Out) {
    int row = blockIdx.x;
    int t = threadIdx.x;
    const float4* x4 = (const float4*)(Xin + (size_t)row * DD);
    float4 v0 = x4[t], v1 = x4[t + 64];
    float s = v0.x + v0.y + v0.z + v0.w + v1.x + v1.y + v1.z + v1.w;
    #pragma unroll
    for (int o = 32; o; o >>= 1) s += __shfl_down(s, o);
    float mu = __shfl(s, 0) * (1.0f / 512.0f);
    float d0 = v0.x - mu, d1 = v0.y - mu, d2 = v0.z - mu, d3 = v0.w - mu;
    float d4 = v1.x - mu, d5 = v1.y - mu, d6 = v1.z - mu, d7 = v1.w - mu;
    float vs = d0*d0 + d1*d1 + d2*d2 + d3*d3 + d4*d4 + d5*d5 + d6*d6 + d7*d7;
    #pragma unroll
    for (int o = 32; o; o >>= 1) vs += __shfl_down(vs, o);
    float var = __shfl(vs, 0) * (1.0f / 512.0f);
    float rstd = rsqrtf(var + 1e-5f);
    float4 w0 = ((const float4*)lw)[t], w1 = ((const float4*)lw)[t + 64];
    float4 b0 = ((const float4*)lb)[t], b1 = ((const float4*)lb)[t + 64];
    float4 r0, r1;
    r0.x = d0 * rstd * w0.x + b0.x; r0.y = d1 * rstd * w0.y + b0.y;
    r0.z = d2 * rstd * w0.z + b0.z; r0.w = d3 * rstd * w0.w + b0.w;
    r1.x = d4 * rstd * w1.x + b1.x; r1.y = d5 * rstd * w1.y + b1.y;
    r1.z = d6 * rstd * w1.z + b1.z; r1.w = d7 * rstd * w1.w + b1.w;
    float4* o4 = (float4*)(Out + (size_t)row * DD);
    o4[t] = r0; o4[t + 64] = r1;
}

// ---------------- column (temporal) mean over L per (b,d) ----------------
__global__ void k_colmean(const float* __restrict__ A, float* __restrict__ CM) {
    int tid = blockIdx.x * blockDim.x + threadIdx.x;
    int b = tid >> 9, d = tid & 511;
    const float* a = A + (size_t)b * LL * DD + d;
    float s = 0.f;
    for (int l = 0; l < LL; ++l) s += a[l * DD];
    CM[tid] = s * (1.0f / 512.0f);
}

__global__ void k_gelu_sub(float* __restrict__ A, const float* __restrict__ CM) {
    int i = blockIdx.x * 256 + threadIdx.x;
    int b = i >> 18, d = i & 511;
    float v = A[i] - CM[(b << 9) | d];
    A[i] = gelu_f(v);
}

// ---------------- final projection [B, L*D] @ [L*D, 10] ----------------
__global__ __launch_bounds__(256) void k_proj_partial(const float* __restrict__ A,
        const float* __restrict__ PW, float* __restrict__ PP) {
    int b = blockIdx.x, c = blockIdx.y;
    int t = threadIdx.x;
    float acc[NCC] = {};
    const float* a = A + (size_t)b * LL * DD;
    int i0 = c * 16384, i1 = i0 + 16384;
    for (int i = i0 + t; i < i1; i += 256) {
        float v = a[i];
        const float* w = PW + (size_t)i * NCC;
        #pragma unroll
        for (int n = 0; n < NCC; ++n) acc[n] = fmaf(v, w[n], acc[n]);
    }
    __shared__ float red[4][NCC];
    int lane = t & 63, wv = t >> 6;
    #pragma unroll
    for (int n = 0; n < NCC; ++n) {
        float s = acc[n];
        #pragma unroll
        for (int o = 32; o; o >>= 1) s += __shfl_down(s, o);
        if (lane == 0) red[wv][n] = s;
    }
    __syncthreads();
    if (t < NCC) {
        PP[(b * 16 + c) * NCC + t] = red[0][t] + red[1][t] + red[2][t] + red[3][t];
    }
}

__global__ void k_proj_final(const float* __restrict__ PP, const float* __restrict__ pb,
                             float* __restrict__ out) {
    int t = threadIdx.x;
    if (t >= BB * NCC) return;
    int b = t / NCC, n = t % NCC;
    float s = pb[n];
    for (int c = 0; c < 16; ++c) s += PP[(b * 16 + c) * NCC + n];
    out[t] = s;
}

// ---------------- numpy legacy RandomState(0) modes replication ----------------
static void compute_modes(int* out) {
    static uint32_t mt[624];
    uint32_t s = 0u;
    mt[0] = s;
    for (int i = 1; i < 624; ++i)
        mt[i] = 1812433253u * (mt[i - 1] ^ (mt[i - 1] >> 30)) + (uint32_t)i;
    int mti = 624;
    auto genrand = [&]() -> uint32_t {
        if (mti >= 624) {
            for (int k = 0; k < 624; ++k) {
                uint32_t y = (mt[k] & 0x80000000u) | (mt[(k + 1) % 624] & 0x7fffffffu);
                mt[k] = mt[(k + 397) % 624] ^ (y >> 1) ^ ((y & 1u) ? 2567483615u : 0u);
            }
            mti = 0;
        }
        uint32_t y = mt[mti++];
        y ^= y >> 11;
        y ^= (y << 7) & 2636928640u;
        y ^= (y << 15) & 4022730752u;
        y ^= y >> 18;
        return y;
    };
    int idx[256];
    for (int i = 0; i < 256; ++i) idx[i] = i;
    for (int i = 255; i >= 1; --i) {
        uint32_t mx = (uint32_t)i;
        uint32_t mask = mx;
        mask |= mask >> 1; mask |= mask >> 2; mask |= mask >> 4;
        mask |= mask >> 8; mask |= mask >> 16;
        uint32_t j;
        while ((j = (genrand() & mask)) > mx) {}
        int tmp = idx[i]; idx[i] = idx[j]; idx[j] = tmp;
    }
    int sel[NM];
    for (int i = 0; i < NM; ++i) sel[i] = idx[i];
    std::sort(sel, sel + NM);
    for (int i = 0; i < NM; ++i) out[i] = sel[i];
}

extern "C" void kernel_launch(void* const* d_in, const int* in_sizes, int n_in,
                              void* d_out, int out_size, void* d_ws, size_t ws_size,
                              hipStream_t stream) {
    const float* xe  = (const float*)d_in[0];
    const float* tw  = (const float*)d_in[1];
    const float* Wq  = (const float*)d_in[2];
    const float* bq  = (const float*)d_in[3];
    const float* Wo  = (const float*)d_in[8];
    const float* bo  = (const float*)d_in[9];
    const float* fwr = (const float*)d_in[10];
    const float* fwi = (const float*)d_in[11];
    const float* W1  = (const float*)d_in[12];
    const float* W2  = (const float*)d_in[13];
    const float* lw  = (const float*)d_in[14];
    const float* lb  = (const float*)d_in[15];
    const float* pw  = (const float*)d_in[16];
    const float* pb  = (const float*)d_in[17];
    float* out = (float*)d_out;

    const size_t NX = (size_t)BB * LL * DD;        // 8388608
    const size_t NHF = (size_t)BB * LL * NDFF;     // 33554432
    const size_t NXG = (size_t)BB * NH * EHH * NM; // 524288
    const size_t NWM = (size_t)NH * NM * EHH * EHH;// 1048576 float2

    char* wsb = (char*)d_ws;
    size_t off = 0;
    float* X1  = (float*)(wsb + off); off += NX * 4;
    float* X2  = (float*)(wsb + off); off += NX * 4;
    float* TB  = (float*)(wsb + off); off += NX * 4;
    float* XGr = (float*)(wsb + off); off += NXG * 4;
    float* XGi = (float*)(wsb + off); off += NXG * 4;
    __hip_bfloat16* X1b = (__hip_bfloat16*)(wsb + off); off += NX * 2;
    __hip_bfloat16* X2b = (__hip_bfloat16*)(wsb + off); off += NX * 2;
    __hip_bfloat16* HMb = (__hip_bfloat16*)(wsb + off); off += NHF * 2;
    __hip_bfloat16* WT  = (__hip_bfloat16*)(wsb + off); off += (size_t)DD * DD * 2;
    float2* WM          = (float2*)(wsb + off);         off += NWM * 8;
    __hip_bfloat16* TXb = (__hip_bfloat16*)(wsb + off); off += (size_t)BB * 64 * 512 * 2;
    __hip_bfloat16* Tb  = (__hip_bfloat16*)(wsb + off); off += (size_t)64 * 512 * 2;
    __hip_bfloat16* OGT = (__hip_bfloat16*)(wsb + off); off += (size_t)BB * 512 * 64 * 2;
    __hip_bfloat16* Sk  = (__hip_bfloat16*)(wsb + off); off += (size_t)64 * 512 * 2;
    __hip_bfloat16* WTq = (__hip_bfloat16*)(wsb + off); off += (size_t)NEL * DD * DD * 2;
    __hip_bfloat16* WT1 = (__hip_bfloat16*)(wsb + off); off += (size_t)NEL * DD * NDFF * 2;
    __hip_bfloat16* WT2 = (__hip_bfloat16*)(wsb + off); off += (size_t)NEL * NDFF * DD * 2;
    __hip_bfloat16* SW3 = (__hip_bfloat16*)(wsb + off); off += (size_t)NEL * DD * 64 * 2;
    if (ws_size < off) return;

    // XTb (16.8 MB) aliases TB (33.5 MB): TB is dead from layer start until k_nx writes it.
    __hip_bfloat16* XTb = (__hip_bfloat16*)TB;

    Modes mi;
    compute_modes(mi.v);

    // ---- upfront: embedding, twiddle/synthesis tables, ALL weight preps ----
    k_embed<<<dim3(16, 2, BB), 256, 0, stream>>>(xe, tw, X1, X1b);
    k_tgen<<<64, 64, 0, stream>>>(Tb, mi);
    k_sgen<<<64, 64, 0, stream>>>(Sk);
    for (int li = 0; li < NEL; ++li) {
        k_wt<<<dim3(16, 16), 256, 0, stream>>>(Wq + (size_t)li * DD * DD,
                                               WTq + (size_t)li * DD * DD, DD, DD);
        k_wt<<<dim3(64, 16), 256, 0, stream>>>(W1 + (size_t)li * DD * NDFF,
                                               WT1 + (size_t)li * DD * NDFF, DD, NDFF);
        k_wt<<<dim3(16, 64), 256, 0, stream>>>(W2 + (size_t)li * NDFF * DD,
                                               WT2 + (size_t)li * NDFF * DD, NDFF, DD);
        k_wt<<<dim3(16, 16), 256, 0, stream>>>(Wo + (size_t)li * DD * DD, WT, DD, DD);
        k_swt<<<4, 256, 0, stream>>>(Sk, WT, SW3 + (size_t)li * DD * 64);
    }

    float* cur = X1;            float* alt = X2;
    __hip_bfloat16* curb = X1b; __hip_bfloat16* altb = X2b;
    const int M = BB * LL;      // 16384

    for (int li = 0; li < NEL; ++li) {
        k_wfm<<<NH * EHH, 256, 0, stream>>>(fwr, fwi, WM, li);
        k_xt<<<dim3(8, 8, BB), 256, 0, stream>>>(cur, XTb);
        k_tx<<<dim3(BB, 4), 256, 0, stream>>>(Tb, XTb, TXb);
        k_xg<<<dim3(16, 4), 256, 0, stream>>>(TXb, WTq + (size_t)li * DD * DD,
                                              bq + li * DD, XGr, XGi, mi);
        k_og<<<NH * NM, 256, 0, stream>>>(XGr, XGi, WM, OGT);
        k_nx<<<dim3(4, 4, BB), 256, 0, stream>>>(OGT, SW3 + (size_t)li * DD * 64,
                                                 bo + li * DD, TB);
        k_add_decomp<<<BB * 8, DD, 0, stream>>>(cur, TB, alt, altb);
        { float* t_ = cur; cur = alt; alt = t_; }
        { __hip_bfloat16* t_ = curb; curb = altb; altb = t_; }
        // ---- FFN: 2-phase dbuf MFMA GEMMs ----
        k_ffn<256, 256, 1><<<dim3(M / 256, NDFF / 256), 512, 0, stream>>>(
            curb, WT1 + (size_t)li * DD * NDFF, nullptr, HMb, M, NDFF, DD);
        k_ffn<128, 256, 2><<<dim3(M / 128, DD / 256), 512, 0, stream>>>(
            HMb, WT2 + (size_t)li * NDFF * DD, TB, nullptr, M, DD, NDFF);
        k_add_decomp<<<BB * 8, DD, 0, stream>>>(cur, TB, alt, altb);
        { float* t_ = cur; cur = alt; alt = t_; }
        { __hip_bfloat16* t_ = curb; curb = altb; altb = t_; }
    }

    // ---- final: LayerNorm -> subtract temporal mean -> gelu -> projection ----
    k_ln<<<BB * LL, 64, 0, stream>>>(cur, lw, lb, TB);
    float* CM = XGr;
    float* PP = XGi;
    k_colmean<<<64, 256, 0, stream>>>(TB, CM);
    k_gelu_sub<<<32768, 256, 0, stream>>>(TB, CM);
    k_proj_partial<<<dim3(BB, 16), 256, 0, stream>>>(TB, pw, PP);
    k_proj_final<<<1, 320, 0, stream>>>(PP, pb, out);
}

// Round 8
// 939.508 us; speedup vs baseline: 6.1809x; 1.0486x over previous
//
#include <hip/hip_runtime.h>
#include <hip/hip_bf16.h>
#include <stdint.h>
#include <algorithm>

#define BB  32
#define LL  512
#define NCI 21
#define DD  512
#define NH  8
#define EHH 64
#define NDFF 2048
#define NM  32
#define NEL 3
#define NCC 10

struct Modes { int v[NM]; };

typedef __bf16 bf16x8 __attribute__((ext_vector_type(8)));
typedef float f32x4 __attribute__((ext_vector_type(4)));

// A&S 7.1.26 erf, |eps| <= 1.5e-7, branchless
__device__ __forceinline__ float erf_poly(float x) {
    float ax = fabsf(x);
    float t = 1.0f / fmaf(0.3275911f, ax, 1.0f);
    float y = t * fmaf(t, fmaf(t, fmaf(t, fmaf(t, 1.061405429f, -1.453152027f),
                                       1.421413741f), -0.284496736f), 0.254829592f);
    float r = 1.0f - y * __expf(-ax * ax);
    return copysignf(r, x);
}

__device__ __forceinline__ float gelu_f(float x) {
    return 0.5f * x * (1.0f + erf_poly(x * 0.7071067811865475f));
}

__device__ __forceinline__ void gload_lds16(const void* g, void* l) {
    __builtin_amdgcn_global_load_lds((const __attribute__((address_space(1))) void*)g,
                                     (__attribute__((address_space(3))) void*)l, 16, 0, 0);
}

// ---------------- embedding: circular conv1d(k=3) + positional encoding (dual write) -----
__global__ void k_embed(const float* __restrict__ xe, const float* __restrict__ tw,
                        float* __restrict__ X, __hip_bfloat16* __restrict__ Xb) {
    int lc = blockIdx.x;
    int dh = blockIdx.y;
    int b  = blockIdx.z;
    int t  = threadIdx.x;
    int d  = dh * 256 + t;
    __shared__ float s_xe[34][NCI];
    int l0 = lc * 32;
    for (int i = t; i < 34 * NCI; i += 256) {
        int r = i / NCI, c = i % NCI;
        int ls = (l0 - 1 + r + LL) & (LL - 1);
        s_xe[r][c] = xe[(b * LL + ls) * NCI + c];
    }
    __syncthreads();
    int a = d & ~1;
    float freq = expf((float)a * (-9.210340371976184f / 512.0f));
    for (int li = 0; li < 32; ++li) {
        int l = l0 + li;
        float acc = 0.f;
        #pragma unroll
        for (int k = 0; k < 3; ++k)
            for (int c = 0; c < NCI; ++c)
                acc = fmaf(s_xe[li + k][c], tw[(k * NCI + c) * DD + d], acc);
        float v = (float)l * freq;
        float pe = (d & 1) ? cosf(v) : sinf(v);
        float r = acc + pe;
        size_t off = ((size_t)(b * LL + l)) * DD + d;
        X[off] = r;
        Xb[off] = __float2bfloat16(r);
    }
}

// ---------------- weight convert+transpose: W[K][N] fp32 -> WT[N][K] bf16 ----------------
__global__ void k_wt(const float* __restrict__ W, __hip_bfloat16* __restrict__ WT,
                     int K, int N) {
    __shared__ float s[32][33];
    int bx = blockIdx.x;
    int by = blockIdx.y;
    int t = threadIdx.x;
    int r = t >> 5, c = t & 31;
    #pragma unroll
    for (int i = 0; i < 4; ++i)
        s[r + i * 8][c] = W[(size_t)(by * 32 + r + i * 8) * N + bx * 32 + c];
    __syncthreads();
    #pragma unroll
    for (int i = 0; i < 4; ++i) {
        int n = bx * 32 + r + i * 8;
        WT[(size_t)n * K + by * 32 + c] = __float2bfloat16(s[c][r + i * 8]);
    }
}

// ---------------- fourier weight transpose: fw[h,e,o,m] -> WM[h][m][e][o] float2 ---------
__global__ void k_wfm(const float* __restrict__ fwr, const float* __restrict__ fwi,
                      float2* __restrict__ WM, int li) {
    int blk = blockIdx.x;        // h*64 + e
    int h = blk >> 6, e = blk & 63;
    int t = threadIdx.x;
    __shared__ float2 s[32][65];
    const float* br = fwr + (((size_t)(li * NH + h) * EHH + e) * EHH) * NM;
    const float* bi = fwi + (((size_t)(li * NH + h) * EHH + e) * EHH) * NM;
    for (int i = t; i < 2048; i += 256) {
        int o = i >> 5, m = i & 31;
        s[m][o] = make_float2(br[i], bi[i]);
    }
    __syncthreads();
    int mr = t >> 6, o = t & 63;
    for (int m = mr; m < 32; m += 4)
        WM[((size_t)(h * 32 + m)) * 4096 + e * 64 + o] = s[m][o];
}

// ---------------- twiddle matrix: T[2m][l]=cos(w0*im*l), T[2m+1][l]=sin ------------------
__global__ void k_tgen(__hip_bfloat16* __restrict__ Tb, Modes md) {
    int r = blockIdx.x;          // 64
    int m = r >> 1;
    int im = md.v[m];
    const float w0 = 6.283185307179586f / 512.0f;
    for (int l = threadIdx.x; l < LL; l += 64) {
        int red = (im * l) & 511;
        float ang = w0 * (float)red;
        float v = (r & 1) ? sinf(ang) : cosf(ang);
        Tb[r * 512 + l] = __float2bfloat16(v);
    }
}

// ---------------- synthesis matrix (k-major): Sk[k][l] ----------------------------------
__global__ void k_sgen(__hip_bfloat16* __restrict__ Sk) {
    int k = blockIdx.x;          // 64
    int m = k >> 1;
    const float w0 = 6.283185307179586f / 512.0f;
    for (int l = threadIdx.x; l < LL; l += 64) {
        int red = (m * l) & 511;
        float ang = w0 * (float)red;
        float v;
        if ((k & 1) == 0) v = cosf(ang) * (m == 0 ? (1.0f / 512.0f) : (2.0f / 512.0f));
        else              v = -sinf(ang) * (2.0f / 512.0f);
        Sk[k * 512 + l] = __float2bfloat16(v);
    }
}

// ---------------- transpose: X[b][l][d] fp32 -> XT[b][d][l] bf16 -------------------------
__global__ __launch_bounds__(256) void k_xt(const float* __restrict__ X,
                                            __hip_bfloat16* __restrict__ XT) {
    int b = blockIdx.z;
    int l0 = blockIdx.x * 64, d0 = blockIdx.y * 64;
    __shared__ float s[64][65];
    const float* xb = X + (size_t)b * LL * DD;
    int t = threadIdx.x;
    #pragma unroll
    for (int i = 0; i < 16; ++i) {
        int e = i * 256 + t;
        int lr = e >> 6, dc = e & 63;
        s[lr][dc] = xb[(size_t)(l0 + lr) * DD + d0 + dc];
    }
    __syncthreads();
    __hip_bfloat16* xt = XT + (size_t)b * DD * LL;
    #pragma unroll
    for (int i = 0; i < 16; ++i) {
        int e = i * 256 + t;
        int dr = e >> 6, lc = e & 63;
        xt[(size_t)(d0 + dr) * LL + l0 + lc] = __float2bfloat16(s[lc][dr]);
    }
}

// ---------------- TX[b] = T[64x512] @ XT[b] (contraction over l) -------------------------
__global__ __launch_bounds__(256) void k_tx(const __hip_bfloat16* __restrict__ Tb,
        const __hip_bfloat16* __restrict__ XT, __hip_bfloat16* __restrict__ TX) {
    __shared__ __hip_bfloat16 Ts[64 * 32];
    __shared__ __hip_bfloat16 Xs[128 * 32];
    int b = blockIdx.x, n0 = blockIdx.y * 128;
    int t = threadIdx.x, w = t >> 6, ln = t & 63;
    const __hip_bfloat16* xb = XT + (size_t)b * DD * LL;
    f32x4 acc[4][2] = {};
    for (int k0 = 0; k0 < 512; k0 += 32) {
        {
            int row = w * 16 + (ln >> 2), q = ln & 3;
            gload_lds16(Tb + row * 512 + k0 + q * 8, (char*)Ts + w * 1024);
        }
        #pragma unroll
        for (int i = 0; i < 2; ++i) {
            int s = i * 256 + t;
            int row = s >> 2, q = s & 3;
            gload_lds16(xb + (size_t)(n0 + row) * LL + k0 + q * 8,
                        (char*)Xs + i * 4096 + w * 1024);
        }
        __syncthreads();
        int lr = ln & 15, kc = (ln >> 4) * 8;
        bf16x8 af[4], bfr[2];
        #pragma unroll
        for (int mi = 0; mi < 4; ++mi)
            af[mi] = *(const bf16x8*)&Ts[(mi * 16 + lr) * 32 + kc];
        #pragma unroll
        for (int ni = 0; ni < 2; ++ni)
            bfr[ni] = *(const bf16x8*)&Xs[(w * 32 + ni * 16 + lr) * 32 + kc];
        #pragma unroll
        for (int mi = 0; mi < 4; ++mi)
            #pragma unroll
            for (int ni = 0; ni < 2; ++ni)
                acc[mi][ni] = __builtin_amdgcn_mfma_f32_16x16x32_bf16(
                    af[mi], bfr[ni], acc[mi][ni], 0, 0, 0);
        __syncthreads();
    }
    int rb = (ln >> 4) * 4, cb = ln & 15;
    #pragma unroll
    for (int mi = 0; mi < 4; ++mi)
        #pragma unroll
        for (int ni = 0; ni < 2; ++ni)
            #pragma unroll
            for (int j = 0; j < 4; ++j) {
                int m = mi * 16 + rb + j;
                int col = n0 + w * 32 + ni * 16 + cb;
                TX[(size_t)(b * 64 + m) * 512 + col] =
                    __float2bfloat16(acc[mi][ni][j]);
            }
}

// ---------------- SW = Sk(64k x 512l) @ WoT^T; written transposed SWT[dc][k] -------------
__global__ __launch_bounds__(256) void k_swt(const __hip_bfloat16* __restrict__ Sk,
        const __hip_bfloat16* __restrict__ WT, __hip_bfloat16* __restrict__ SWT) {
    __shared__ __hip_bfloat16 Ts[64 * 32];
    __shared__ __hip_bfloat16 Xs[128 * 32];
    int n0 = blockIdx.x * 128;
    int t = threadIdx.x, w = t >> 6, ln = t & 63;
    f32x4 acc[4][2] = {};
    for (int k0 = 0; k0 < 512; k0 += 32) {
        {
            int row = w * 16 + (ln >> 2), q = ln & 3;
            gload_lds16(Sk + row * 512 + k0 + q * 8, (char*)Ts + w * 1024);
        }
        #pragma unroll
        for (int i = 0; i < 2; ++i) {
            int s = i * 256 + t;
            int row = s >> 2, q = s & 3;
            gload_lds16(WT + (size_t)(n0 + row) * 512 + k0 + q * 8,
                        (char*)Xs + i * 4096 + w * 1024);
        }
        __syncthreads();
        int lr = ln & 15, kc = (ln >> 4) * 8;
        bf16x8 af[4], bfr[2];
        #pragma unroll
        for (int mi = 0; mi < 4; ++mi)
            af[mi] = *(const bf16x8*)&Ts[(mi * 16 + lr) * 32 + kc];
        #pragma unroll
        for (int ni = 0; ni < 2; ++ni)
            bfr[ni] = *(const bf16x8*)&Xs[(w * 32 + ni * 16 + lr) * 32 + kc];
        #pragma unroll
        for (int mi = 0; mi < 4; ++mi)
            #pragma unroll
            for (int ni = 0; ni < 2; ++ni)
                acc[mi][ni] = __builtin_amdgcn_mfma_f32_16x16x32_bf16(
                    af[mi], bfr[ni], acc[mi][ni], 0, 0, 0);
        __syncthreads();
    }
    int rb = (ln >> 4) * 4, cb = ln & 15;
    #pragma unroll
    for (int mi = 0; mi < 4; ++mi)
        #pragma unroll
        for (int ni = 0; ni < 2; ++ni)
            #pragma unroll
            for (int j = 0; j < 4; ++j) {
                int k = mi * 16 + rb + j;
                int col = n0 + w * 32 + ni * 16 + cb;   // dc
                SWT[(size_t)col * 64 + k] = __float2bfloat16(acc[mi][ni][j]);
            }
}

// ---------------- XG = TX @ Wq (+bias for im==0), scatter to [hm][e*32+b] ----------------
__global__ __launch_bounds__(256) void k_xg(const __hip_bfloat16* __restrict__ A,
        const __hip_bfloat16* __restrict__ Bt, const float* __restrict__ bq,
        float* __restrict__ XGr, float* __restrict__ XGi, Modes md) {
    __shared__ __hip_bfloat16 As[128 * 32];
    __shared__ __hip_bfloat16 Bs[128 * 32];
    int t = threadIdx.x;
    int m0 = blockIdx.x * 128, n0 = blockIdx.y * 128;
    int w = t >> 6, ln = t & 63;
    int wr = w >> 1, wc = w & 1;
    const int K = 512;
    f32x4 acc[4][4] = {};
    for (int k0 = 0; k0 < K; k0 += 32) {
        #pragma unroll
        for (int i = 0; i < 2; ++i) {
            int s = i * 256 + t;
            int row = s >> 2, q = s & 3;
            gload_lds16(A + (size_t)(m0 + row) * K + k0 + q * 8,
                        (char*)As + i * 4096 + w * 1024);
            gload_lds16(Bt + (size_t)(n0 + row) * K + k0 + q * 8,
                        (char*)Bs + i * 4096 + w * 1024);
        }
        __syncthreads();
        bf16x8 af[4], bfr[4];
        int lr = ln & 15, kc = (ln >> 4) * 8;
        #pragma unroll
        for (int mi = 0; mi < 4; ++mi)
            af[mi] = *(const bf16x8*)&As[(wr * 64 + mi * 16 + lr) * 32 + kc];
        #pragma unroll
        for (int ni = 0; ni < 4; ++ni)
            bfr[ni] = *(const bf16x8*)&Bs[(wc * 64 + ni * 16 + lr) * 32 + kc];
        #pragma unroll
        for (int mi = 0; mi < 4; ++mi)
            #pragma unroll
            for (int ni = 0; ni < 4; ++ni)
                acc[mi][ni] = __builtin_amdgcn_mfma_f32_16x16x32_bf16(
                    af[mi], bfr[ni], acc[mi][ni], 0, 0, 0);
        __syncthreads();
    }
    int rb = (ln >> 4) * 4, cb = ln & 15;
    #pragma unroll
    for (int mi = 0; mi < 4; ++mi) {
        #pragma unroll
        for (int ni = 0; ni < 4; ++ni) {
            int col = n0 + wc * 64 + ni * 16 + cb;
            int h = col >> 6, e = col & 63;
            #pragma unroll
            for (int j = 0; j < 4; ++j) {
                int row = m0 + wr * 64 + mi * 16 + rb + j;
                int b = row >> 6, r = row & 63, m = r >> 1;
                float v = acc[mi][ni][j];
                int off = (h * 32 + m) * 2048 + e * 32 + b;
                if ((r & 1) == 0)
                    XGr[off] = v + (md.v[m] == 0 ? 512.f * bq[col] : 0.f);
                else
                    XGi[off] = -v;
            }
        }
    }
}

// ---------------- FFN GEMM: 2-deep counted-vmcnt pipeline, BK=64, 512 thr, XOR swizzle ---
// EPI 1: gelu -> bf16 Cb; EPI 2: fp32 C.
template<int BM, int BN, int EPI>
__global__ __launch_bounds__(512, 2) void k_ffn(const __hip_bfloat16* __restrict__ A,
        const __hip_bfloat16* __restrict__ Bt, float* __restrict__ C,
        __hip_bfloat16* __restrict__ Cb, int M, int N, int K) {
    constexpr int WRM = BM / 2;
    constexpr int WCN = BN / 4;
    constexpr int FM = WRM / 16;
    constexpr int FN = WCN / 16;
    constexpr int TILE = (BM + BN) * 64;       // elements per buffer
    constexpr int NL = (BM + BN) / 64;         // VMEM loads per thread per STAGE
    __shared__ __hip_bfloat16 lds[2 * TILE];
    int t = threadIdx.x, w = t >> 6, ln = t & 63;
    int wr = w >> 2, wc = w & 3;               // 2 x 4 wave grid
    int lr = ln & 15, kc16 = ln >> 4;
    int m0 = blockIdx.x * BM, n0 = blockIdx.y * BN;
    f32x4 acc[FM][FN] = {};
    int NT = K / 64;

    auto STAGE = [&](int buf, int kt) {
        int kb = kt * 64;
        char* ldsA = (char*)lds + buf * TILE * 2;
        char* ldsB = ldsA + BM * 128;
        #pragma unroll
        for (int i = 0; i < BM / 64; ++i) {
            int c = i * 512 + t;
            int row = c >> 3, q = c & 7;
            int slot = q ^ (row & 7);
            gload_lds16(A + (size_t)(m0 + row) * K + kb + slot * 8,
                        ldsA + (i * 512 + w * 64) * 16);
        }
        #pragma unroll
        for (int i = 0; i < BN / 64; ++i) {
            int c = i * 512 + t;
            int row = c >> 3, q = c & 7;
            int slot = q ^ (row & 7);
            gload_lds16(Bt + (size_t)(n0 + row) * K + kb + slot * 8,
                        ldsB + (i * 512 + w * 64) * 16);
        }
    };

    STAGE(0, 0);
    STAGE(1, 1);
    int cur = 0;
    for (int kt = 0; kt < NT; ++kt) {
        // wait until tile kt's loads landed (tile kt+1's NL loads may stay in flight)
        if (kt + 1 < NT) {
            if constexpr (NL == 8) asm volatile("s_waitcnt vmcnt(8)" ::: "memory");
            else                   asm volatile("s_waitcnt vmcnt(6)" ::: "memory");
        } else {
            asm volatile("s_waitcnt vmcnt(0)" ::: "memory");
        }
        __builtin_amdgcn_sched_barrier(0);
        __builtin_amdgcn_s_barrier();
        __builtin_amdgcn_sched_barrier(0);
        const __hip_bfloat16* As = lds + cur * TILE;
        const __hip_bfloat16* Bs = As + BM * 64;
        __builtin_amdgcn_s_setprio(1);
        #pragma unroll
        for (int ks = 0; ks < 2; ++ks) {
            bf16x8 a[FM], b[FN];
            #pragma unroll
            for (int mi = 0; mi < FM; ++mi) {
                int row = wr * WRM + mi * 16 + lr;
                int s = (ks * 4 + kc16) ^ (row & 7);
                a[mi] = *(const bf16x8*)&As[row * 64 + s * 8];
            }
            #pragma unroll
            for (int ni = 0; ni < FN; ++ni) {
                int row = wc * WCN + ni * 16 + lr;
                int s = (ks * 4 + kc16) ^ (row & 7);
                b[ni] = *(const bf16x8*)&Bs[row * 64 + s * 8];
            }
            #pragma unroll
            for (int mi = 0; mi < FM; ++mi)
                #pragma unroll
                for (int ni = 0; ni < FN; ++ni)
                    acc[mi][ni] = __builtin_amdgcn_mfma_f32_16x16x32_bf16(
                        a[mi], b[ni], acc[mi][ni], 0, 0, 0);
        }
        __builtin_amdgcn_s_setprio(0);
        // all waves done READING buf[cur] before it is overwritten
        __builtin_amdgcn_sched_barrier(0);
        __builtin_amdgcn_s_barrier();
        __builtin_amdgcn_sched_barrier(0);
        if (kt + 2 < NT) STAGE(cur, kt + 2);
        cur ^= 1;
    }
    int rb = kc16 * 4;
    #pragma unroll
    for (int mi = 0; mi < FM; ++mi) {
        #pragma unroll
        for (int ni = 0; ni < FN; ++ni) {
            int col = n0 + wc * WCN + ni * 16 + lr;
            int rowb = m0 + wr * WRM + mi * 16 + rb;
            #pragma unroll
            for (int j = 0; j < 4; ++j) {
                float v = acc[mi][ni][j];
                size_t off = (size_t)(rowb + j) * N + col;
                if (EPI == 1) Cb[off] = __float2bfloat16(gelu_f(v));
                else C[off] = v;
            }
        }
    }
}

// ---------------- og: per (h,m) complex GEMM -> OGT[b][he][k=2m|2m+1] bf16 ---------------
__global__ __launch_bounds__(256) void k_og(const float* __restrict__ XGr,
        const float* __restrict__ XGi, const float2* __restrict__ WM,
        __hip_bfloat16* __restrict__ OGT) {
    int hm = blockIdx.x;      // h*32+m
    int t = threadIdx.x;
    __shared__ float2 sw[4096];
    __shared__ float sxr[2048], sxi[2048];
    const float2* w = WM + (size_t)hm * 4096;
    for (int i = t; i < 4096; i += 256) sw[i] = w[i];
    const float* xr = XGr + hm * 2048;
    const float* xi = XGi + hm * 2048;
    for (int i = t; i < 2048; i += 256) { sxr[i] = xr[i]; sxi[i] = xi[i]; }
    __syncthreads();
    int b = t >> 3, o0 = (t & 7) * 8;
    float ar[8] = {}, ai[8] = {};
    for (int e = 0; e < 64; ++e) {
        float xrv = sxr[e * 32 + b], xiv = sxi[e * 32 + b];
        #pragma unroll
        for (int j = 0; j < 8; ++j) {
            float2 wv = sw[e * 64 + o0 + j];
            ar[j] = fmaf(xrv, wv.x, fmaf(-xiv, wv.y, ar[j]));
            ai[j] = fmaf(xrv, wv.y, fmaf( xiv, wv.x, ai[j]));
        }
    }
    int h = hm >> 5, m = hm & 31;
    __hip_bfloat16* og = OGT + (size_t)b * (512 * 64);
    #pragma unroll
    for (int j = 0; j < 8; ++j) {
        int he = h * 64 + o0 + j;
        union { __hip_bfloat16 h2[2]; uint32_t u; } pk;
        pk.h2[0] = __float2bfloat16(ar[j]);
        pk.h2[1] = __float2bfloat16(ai[j]);
        *(uint32_t*)&og[he * 64 + 2 * m] = pk.u;
    }
}

// ---------------- new_x[b][he][dc] = OGT[b](512he x 64k) @ SWT^T + bo --------------------
__global__ __launch_bounds__(256) void k_nx(const __hip_bfloat16* __restrict__ OGT,
        const __hip_bfloat16* __restrict__ SWT, const float* __restrict__ bo,
        float* __restrict__ C) {
    __shared__ __hip_bfloat16 As[128 * 32];
    __shared__ __hip_bfloat16 Bs[128 * 32];
    int t = threadIdx.x;
    int m0 = blockIdx.x * 128, n0 = blockIdx.y * 128, b = blockIdx.z;
    int w = t >> 6, ln = t & 63;
    int wr = w >> 1, wc = w & 1;
    const __hip_bfloat16* ab = OGT + (size_t)b * 512 * 64;
    f32x4 acc[4][4] = {};
    for (int k0 = 0; k0 < 64; k0 += 32) {
        #pragma unroll
        for (int i = 0; i < 2; ++i) {
            int s = i * 256 + t;
            int row = s >> 2, q = s & 3;
            gload_lds16(ab + (size_t)(m0 + row) * 64 + k0 + q * 8,
                        (char*)As + i * 4096 + w * 1024);
            gload_lds16(SWT + (size_t)(n0 + row) * 64 + k0 + q * 8,
                        (char*)Bs + i * 4096 + w * 1024);
        }
        __syncthreads();
        bf16x8 af[4], bfr[4];
        int lr = ln & 15, kc = (ln >> 4) * 8;
        #pragma unroll
        for (int mi = 0; mi < 4; ++mi)
            af[mi] = *(const bf16x8*)&As[(wr * 64 + mi * 16 + lr) * 32 + kc];
        #pragma unroll
        for (int ni = 0; ni < 4; ++ni)
            bfr[ni] = *(const bf16x8*)&Bs[(wc * 64 + ni * 16 + lr) * 32 + kc];
        #pragma unroll
        for (int mi = 0; mi < 4; ++mi)
            #pragma unroll
            for (int ni = 0; ni < 4; ++ni)
                acc[mi][ni] = __builtin_amdgcn_mfma_f32_16x16x32_bf16(
                    af[mi], bfr[ni], acc[mi][ni], 0, 0, 0);
        __syncthreads();
    }
    int rb = (ln >> 4) * 4, cb = ln & 15;
    #pragma unroll
    for (int mi = 0; mi < 4; ++mi) {
        #pragma unroll
        for (int ni = 0; ni < 4; ++ni) {
            int col = n0 + wc * 64 + ni * 16 + cb;
            int he = m0 + wr * 64 + mi * 16 + rb;
            float bv = bo[col];
            #pragma unroll
            for (int j = 0; j < 4; ++j)
                C[((size_t)b * 512 + he + j) * 512 + col] = acc[mi][ni][j] + bv;
        }
    }
}

// ---------------- s = P + Q; out = s - movavg25(s); dual fp32+bf16, L-chunked ------------
__global__ void k_add_decomp(const float* __restrict__ P, const float* __restrict__ Q,
                             float* __restrict__ Out, __hip_bfloat16* __restrict__ Outb) {
    int b = blockIdx.x >> 3;
    int l0 = (blockIdx.x & 7) * 64;
    int d = threadIdx.x;
    const float* p = P + (size_t)b * LL * DD + d;
    const float* q = Q + (size_t)b * LL * DD + d;
    float* o = Out + (size_t)b * LL * DD + d;
    __hip_bfloat16* ob = Outb + (size_t)b * LL * DD + d;
    float sum = 0.f;
    for (int j = l0 - 12; j <= l0 + 12; ++j) {
        int jc = j < 0 ? 0 : (j > 511 ? 511 : j);
        sum += p[jc * DD] + q[jc * DD];
    }
    for (int l = l0; l < l0 + 64; ++l) {
        float sv = p[l * DD] + q[l * DD];
        float r = sv - sum * (1.0f / 25.0f);
        o[l * DD] = r;
        ob[l * DD] = __float2bfloat16(r);
        int lp = l + 13 > 511 ? 511 : l + 13;
        int lm = l - 12 < 0 ? 0 : l - 12;
        sum += (p[lp * DD] + q[lp * DD]) - (p[lm * DD] + q[lm * DD]);
    }
}

// ---------------- LayerNorm over D ----------------
__global__ void k_ln(const float* __restrict__ Xin, const float* __restrict__ lw,
                     const float* __restrict__ lb, float* __restrict__ Out) {
    int row = blockIdx.x;
    int t = threadIdx.x;
    const float4* x4 = (const float4*)(Xin + (size_t)row * DD);
    float4 v0 = x4[t], v1 = x4[t + 64];
    float s = v0.x + v0.y + v0.z + v0.w + v1.x + v1.y + v1.z + v1.w;
    #pragma unroll
    for (int o = 32; o; o >>= 1) s += __shfl_down(s, o);
    float mu = __shfl(s, 0) * (1.0f / 512.0f);
    float d0 = v0.x - mu, d1 = v0.y - mu, d2 = v0.z - mu, d3 = v0.w - mu;
    float d4 = v1.x - mu, d5 = v1.y - mu, d6 = v1.z - mu, d7 = v1.w - mu;
    float vs = d0*d0 + d1*d1 + d2*d2 + d3*d3 + d4*d4 + d5*d5 + d6*d6 + d7*d7;
    #pragma unroll
    for (int o = 32; o; o >>= 1) vs += __shfl_down(vs, o);
    float var = __shfl(vs, 0) * (1.0f / 512.0f);
    float rstd = rsqrtf(var + 1e-5f);
    float4 w0 = ((const float4*)lw)[t], w1 = ((const float4*)lw)[t + 64];
    float4 b0 = ((const float4*)lb)[t], b1 = ((const float4*)lb)[t + 64];
    float4 r0, r1;
    r0.x = d0 * rstd * w0.x + b0.x; r0.y = d1 * rstd * w0.y + b0.y;
    r0.z = d2 * rstd * w0.z + b0.z; r0.w = d3 * rstd * w0.w + b0.w;
    r1.x = d4 * rstd * w1.x + b1.x; r1.y = d5 * rstd * w1.y + b1.y;
    r1.z = d6 * rstd * w1.z + b1.z; r1.w = d7 * rstd * w1.w + b1.w;
    float4* o4 = (float4*)(Out + (size_t)row * DD);
    o4[t] = r0; o4[t + 64] = r1;
}

// ---------------- column (temporal) mean over L per (b,d): 256 blocks, 4-way L-split -----
__global__ void k_colmean(const float* __restrict__ A, float* __restrict__ CM) {
    int col0 = blockIdx.x * 64;          // 256 blocks cover 16384 columns
    int part = threadIdx.x >> 6;         // 0..3
    int cl = threadIdx.x & 63;
    int col = col0 + cl;
    int b = col >> 9, d = col & 511;
    const float* a = A + (size_t)b * LL * DD + d;
    float s = 0.f;
    for (int l = part * 128; l < part * 128 + 128; ++l) s += a[l * DD];
    __shared__ float red[4][64];
    red[part][cl] = s;
    __syncthreads();
    if (threadIdx.x < 64) {
        float v = red[0][cl] + red[1][cl] + red[2][cl] + red[3][cl];
        CM[col0 + cl] = v * (1.0f / 512.0f);
    }
}

__global__ void k_gelu_sub(float* __restrict__ A, const float* __restrict__ CM) {
    int i = blockIdx.x * 256 + threadIdx.x;
    int b = i >> 18, d = i & 511;
    float v = A[i] - CM[(b << 9) | d];
    A[i] = gelu_f(v);
}

// ---------------- final projection [B, L*D] @ [L*D, 10] ----------------
__global__ __launch_bounds__(256) void k_proj_partial(const float* __restrict__ A,
        const float* __restrict__ PW, float* __restrict__ PP) {
    int b = blockIdx.x, c = blockIdx.y;
    int t = threadIdx.x;
    float acc[NCC] = {};
    const float* a = A + (size_t)b * LL * DD;
    int i0 = c * 16384, i1 = i0 + 16384;
    for (int i = i0 + t; i < i1; i += 256) {
        float v = a[i];
        const float* w = PW + (size_t)i * NCC;
        #pragma unroll
        for (int n = 0; n < NCC; ++n) acc[n] = fmaf(v, w[n], acc[n]);
    }
    __shared__ float red[4][NCC];
    int lane = t & 63, wv = t >> 6;
    #pragma unroll
    for (int n = 0; n < NCC; ++n) {
        float s = acc[n];
        #pragma unroll
        for (int o = 32; o; o >>= 1) s += __shfl_down(s, o);
        if (lane == 0) red[wv][n] = s;
    }
    __syncthreads();
    if (t < NCC) {
        PP[(b * 16 + c) * NCC + t] = red[0][t] + red[1][t] + red[2][t] + red[3][t];
    }
}

__global__ void k_proj_final(const float* __restrict__ PP, const float* __restrict__ pb,
                             float* __restrict__ out) {
    int t = threadIdx.x;
    if (t >= BB * NCC) return;
    int b = t / NCC, n = t % NCC;
    float s = pb[n];
    for (int c = 0; c < 16; ++c) s += PP[(b * 16 + c) * NCC + n];
    out[t] = s;
}

// ---------------- numpy legacy RandomState(0) modes replication ----------------
static void compute_modes(int* out) {
    static uint32_t mt[624];
    uint32_t s = 0u;
    mt[0] = s;
    for (int i = 1; i < 624; ++i)
        mt[i] = 1812433253u * (mt[i - 1] ^ (mt[i - 1] >> 30)) + (uint32_t)i;
    int mti = 624;
    auto genrand = [&]() -> uint32_t {
        if (mti >= 624) {
            for (int k = 0; k < 624; ++k) {
                uint32_t y = (mt[k] & 0x80000000u) | (mt[(k + 1) % 624] & 0x7fffffffu);
                mt[k] = mt[(k + 397) % 624] ^ (y >> 1) ^ ((y & 1u) ? 2567483615u : 0u);
            }
            mti = 0;
        }
        uint32_t y = mt[mti++];
        y ^= y >> 11;
        y ^= (y << 7) & 2636928640u;
        y ^= (y << 15) & 4022730752u;
        y ^= y >> 18;
        return y;
    };
    int idx[256];
    for (int i = 0; i < 256; ++i) idx[i] = i;
    for (int i = 255; i >= 1; --i) {
        uint32_t mx = (uint32_t)i;
        uint32_t mask = mx;
        mask |= mask >> 1; mask |= mask >> 2; mask |= mask >> 4;
        mask |= mask >> 8; mask |= mask >> 16;
        uint32_t j;
        while ((j = (genrand() & mask)) > mx) {}
        int tmp = idx[i]; idx[i] = idx[j]; idx[j] = tmp;
    }
    int sel[NM];
    for (int i = 0; i < NM; ++i) sel[i] = idx[i];
    std::sort(sel, sel + NM);
    for (int i = 0; i < NM; ++i) out[i] = sel[i];
}

extern "C" void kernel_launch(void* const* d_in, const int* in_sizes, int n_in,
                              void* d_out, int out_size, void* d_ws, size_t ws_size,
                              hipStream_t stream) {
    const float* xe  = (const float*)d_in[0];
    const float* tw  = (const float*)d_in[1];
    const float* Wq  = (const float*)d_in[2];
    const float* bq  = (const float*)d_in[3];
    const float* Wo  = (const float*)d_in[8];
    const float* bo  = (const float*)d_in[9];
    const float* fwr = (const float*)d_in[10];
    const float* fwi = (const float*)d_in[11];
    const float* W1  = (const float*)d_in[12];
    const float* W2  = (const float*)d_in[13];
    const float* lw  = (const float*)d_in[14];
    const float* lb  = (const float*)d_in[15];
    const float* pw  = (const float*)d_in[16];
    const float* pb  = (const float*)d_in[17];
    float* out = (float*)d_out;

    const size_t NX = (size_t)BB * LL * DD;        // 8388608
    const size_t NHF = (size_t)BB * LL * NDFF;     // 33554432
    const size_t NXG = (size_t)BB * NH * EHH * NM; // 524288
    const size_t NWM = (size_t)NH * NM * EHH * EHH;// 1048576 float2

    char* wsb = (char*)d_ws;
    size_t off = 0;
    float* X1  = (float*)(wsb + off); off += NX * 4;
    float* X2  = (float*)(wsb + off); off += NX * 4;
    float* TB  = (float*)(wsb + off); off += NX * 4;
    float* XGr = (float*)(wsb + off); off += NXG * 4;
    float* XGi = (float*)(wsb + off); off += NXG * 4;
    __hip_bfloat16* X1b = (__hip_bfloat16*)(wsb + off); off += NX * 2;
    __hip_bfloat16* X2b = (__hip_bfloat16*)(wsb + off); off += NX * 2;
    __hip_bfloat16* HMb = (__hip_bfloat16*)(wsb + off); off += NHF * 2;
    __hip_bfloat16* WT  = (__hip_bfloat16*)(wsb + off); off += (size_t)DD * DD * 2;
    float2* WM          = (float2*)(wsb + off);         off += NWM * 8;
    __hip_bfloat16* TXb = (__hip_bfloat16*)(wsb + off); off += (size_t)BB * 64 * 512 * 2;
    __hip_bfloat16* Tb  = (__hip_bfloat16*)(wsb + off); off += (size_t)64 * 512 * 2;
    __hip_bfloat16* OGT = (__hip_bfloat16*)(wsb + off); off += (size_t)BB * 512 * 64 * 2;
    __hip_bfloat16* Sk  = (__hip_bfloat16*)(wsb + off); off += (size_t)64 * 512 * 2;
    __hip_bfloat16* WTq = (__hip_bfloat16*)(wsb + off); off += (size_t)NEL * DD * DD * 2;
    __hip_bfloat16* WT1 = (__hip_bfloat16*)(wsb + off); off += (size_t)NEL * DD * NDFF * 2;
    __hip_bfloat16* WT2 = (__hip_bfloat16*)(wsb + off); off += (size_t)NEL * NDFF * DD * 2;
    __hip_bfloat16* SW3 = (__hip_bfloat16*)(wsb + off); off += (size_t)NEL * DD * 64 * 2;
    if (ws_size < off) return;

    // XTb (16.8 MB) aliases TB (33.5 MB): TB is dead from layer start until k_nx writes it.
    __hip_bfloat16* XTb = (__hip_bfloat16*)TB;

    Modes mi;
    compute_modes(mi.v);

    // ---- upfront: embedding, twiddle/synthesis tables, ALL weight preps ----
    k_embed<<<dim3(16, 2, BB), 256, 0, stream>>>(xe, tw, X1, X1b);
    k_tgen<<<64, 64, 0, stream>>>(Tb, mi);
    k_sgen<<<64, 64, 0, stream>>>(Sk);
    for (int li = 0; li < NEL; ++li) {
        k_wt<<<dim3(16, 16), 256, 0, stream>>>(Wq + (size_t)li * DD * DD,
                                               WTq + (size_t)li * DD * DD, DD, DD);
        k_wt<<<dim3(64, 16), 256, 0, stream>>>(W1 + (size_t)li * DD * NDFF,
                                               WT1 + (size_t)li * DD * NDFF, DD, NDFF);
        k_wt<<<dim3(16, 64), 256, 0, stream>>>(W2 + (size_t)li * NDFF * DD,
                                               WT2 + (size_t)li * NDFF * DD, NDFF, DD);
        k_wt<<<dim3(16, 16), 256, 0, stream>>>(Wo + (size_t)li * DD * DD, WT, DD, DD);
        k_swt<<<4, 256, 0, stream>>>(Sk, WT, SW3 + (size_t)li * DD * 64);
    }

    float* cur = X1;            float* alt = X2;
    __hip_bfloat16* curb = X1b; __hip_bfloat16* altb = X2b;
    const int M = BB * LL;      // 16384

    for (int li = 0; li < NEL; ++li) {
        k_wfm<<<NH * EHH, 256, 0, stream>>>(fwr, fwi, WM, li);
        k_xt<<<dim3(8, 8, BB), 256, 0, stream>>>(cur, XTb);
        k_tx<<<dim3(BB, 4), 256, 0, stream>>>(Tb, XTb, TXb);
        k_xg<<<dim3(16, 4), 256, 0, stream>>>(TXb, WTq + (size_t)li * DD * DD,
                                              bq + li * DD, XGr, XGi, mi);
        k_og<<<NH * NM, 256, 0, stream>>>(XGr, XGi, WM, OGT);
        k_nx<<<dim3(4, 4, BB), 256, 0, stream>>>(OGT, SW3 + (size_t)li * DD * 64,
                                                 bo + li * DD, TB);
        k_add_decomp<<<BB * 8, DD, 0, stream>>>(cur, TB, alt, altb);
        { float* t_ = cur; cur = alt; alt = t_; }
        { __hip_bfloat16* t_ = curb; curb = altb; altb = t_; }
        // ---- FFN: counted-vmcnt pipelined MFMA GEMMs ----
        k_ffn<256, 256, 1><<<dim3(M / 256, NDFF / 256), 512, 0, stream>>>(
            curb, WT1 + (size_t)li * DD * NDFF, nullptr, HMb, M, NDFF, DD);
        k_ffn<128, 256, 2><<<dim3(M / 128, DD / 256), 512, 0, stream>>>(
            HMb, WT2 + (size_t)li * NDFF * DD, TB, nullptr, M, DD, NDFF);
        k_add_decomp<<<BB * 8, DD, 0, stream>>>(cur, TB, alt, altb);
        { float* t_ = cur; cur = alt; alt = t_; }
        { __hip_bfloat16* t_ = curb; curb = altb; altb = t_; }
    }

    // ---- final: LayerNorm -> subtract temporal mean -> gelu -> projection ----
    k_ln<<<BB * LL, 64, 0, stream>>>(cur, lw, lb, TB);
    float* CM = XGr;
    float* PP = XGi;
    k_colmean<<<256, 256, 0, stream>>>(TB, CM);
    k_gelu_sub<<<32768, 256, 0, stream>>>(TB, CM);
    k_proj_partial<<<dim3(BB, 16), 256, 0, stream>>>(TB, pw, PP);
    k_proj_final<<<1, 320, 0, stream>>>(PP, pb, out);
}

// Round 9
// 936.254 us; speedup vs baseline: 6.2024x; 1.0035x over previous
//
#include <hip/hip_runtime.h>
#include <hip/hip_bf16.h>
#include <stdint.h>
#include <algorithm>

#define BB  32
#define LL  512
#define NCI 21
#define DD  512
#define NH  8
#define EHH 64
#define NDFF 2048
#define NM  32
#define NEL 3
#define NCC 10

struct Modes { int v[NM]; };

typedef __bf16 bf16x8 __attribute__((ext_vector_type(8)));
typedef float f32x4 __attribute__((ext_vector_type(4)));

// A&S 7.1.26 erf, |eps| <= 1.5e-7, branchless
__device__ __forceinline__ float erf_poly(float x) {
    float ax = fabsf(x);
    float t = 1.0f / fmaf(0.3275911f, ax, 1.0f);
    float y = t * fmaf(t, fmaf(t, fmaf(t, fmaf(t, 1.061405429f, -1.453152027f),
                                       1.421413741f), -0.284496736f), 0.254829592f);
    float r = 1.0f - y * __expf(-ax * ax);
    return copysignf(r, x);
}

__device__ __forceinline__ float gelu_f(float x) {
    return 0.5f * x * (1.0f + erf_poly(x * 0.7071067811865475f));
}

__device__ __forceinline__ void gload_lds16(const void* g, void* l) {
    __builtin_amdgcn_global_load_lds((const __attribute__((address_space(1))) void*)g,
                                     (__attribute__((address_space(3))) void*)l, 16, 0, 0);
}

// ---------------- positional-encoding table PE[l][d] (b-independent, 262K sin/cos) ------
__global__ void k_pegen(float* __restrict__ PE) {
    int l = blockIdx.x;              // 512
    for (int d = threadIdx.x; d < DD; d += 256) {
        int a = d & ~1;
        float freq = expf((float)a * (-9.210340371976184f / 512.0f));
        float v = (float)l * freq;
        PE[l * DD + d] = (d & 1) ? cosf(v) : sinf(v);
    }
}

// ---------------- embedding: conv1d(k=3, circular) + PE table; tw held in registers -----
__global__ __launch_bounds__(256) void k_embed(const float* __restrict__ xe,
        const float* __restrict__ tw, const float* __restrict__ PE,
        float* __restrict__ X, __hip_bfloat16* __restrict__ Xb) {
    int lc = blockIdx.x, dh = blockIdx.y, b = blockIdx.z;
    int t = threadIdx.x;
    int d = dh * 256 + t;
    __shared__ float s_xe[34][NCI];
    int l0 = lc * 32;
    for (int i = t; i < 34 * NCI; i += 256) {
        int r = i / NCI, c = i % NCI;
        int ls = (l0 - 1 + r + LL) & (LL - 1);
        s_xe[r][c] = xe[(b * LL + ls) * NCI + c];
    }
    float twr[63];
    #pragma unroll
    for (int kc = 0; kc < 63; ++kc) twr[kc] = tw[kc * DD + d];
    __syncthreads();
    for (int li = 0; li < 32; ++li) {
        int l = l0 + li;
        float acc = 0.f;
        #pragma unroll
        for (int k = 0; k < 3; ++k)
            #pragma unroll
            for (int c = 0; c < NCI; ++c)
                acc = fmaf(s_xe[li + k][c], twr[k * NCI + c], acc);
        float r = acc + PE[l * DD + d];
        size_t off = ((size_t)(b * LL + l)) * DD + d;
        X[off] = r;
        Xb[off] = __float2bfloat16(r);
    }
}

// ---------------- weight convert+transpose: W[K][N] fp32 -> WT[N][K] bf16 ----------------
__global__ void k_wt(const float* __restrict__ W, __hip_bfloat16* __restrict__ WT,
                     int K, int N) {
    __shared__ float s[32][33];
    int bx = blockIdx.x;
    int by = blockIdx.y;
    int t = threadIdx.x;
    int r = t >> 5, c = t & 31;
    #pragma unroll
    for (int i = 0; i < 4; ++i)
        s[r + i * 8][c] = W[(size_t)(by * 32 + r + i * 8) * N + bx * 32 + c];
    __syncthreads();
    #pragma unroll
    for (int i = 0; i < 4; ++i) {
        int n = bx * 32 + r + i * 8;
        WT[(size_t)n * K + by * 32 + c] = __float2bfloat16(s[c][r + i * 8]);
    }
}

// ---------------- fourier weight transpose: fw[h,e,o,m] -> WM[h][m][e][o] float2 ---------
__global__ void k_wfm(const float* __restrict__ fwr, const float* __restrict__ fwi,
                      float2* __restrict__ WM, int li) {
    int blk = blockIdx.x;        // h*64 + e
    int h = blk >> 6, e = blk & 63;
    int t = threadIdx.x;
    __shared__ float2 s[32][65];
    const float* br = fwr + (((size_t)(li * NH + h) * EHH + e) * EHH) * NM;
    const float* bi = fwi + (((size_t)(li * NH + h) * EHH + e) * EHH) * NM;
    for (int i = t; i < 2048; i += 256) {
        int o = i >> 5, m = i & 31;
        s[m][o] = make_float2(br[i], bi[i]);
    }
    __syncthreads();
    int mr = t >> 6, o = t & 63;
    for (int m = mr; m < 32; m += 4)
        WM[((size_t)(h * 32 + m)) * 4096 + e * 64 + o] = s[m][o];
}

// ---------------- twiddle matrix: T[2m][l]=cos(w0*im*l), T[2m+1][l]=sin ------------------
__global__ void k_tgen(__hip_bfloat16* __restrict__ Tb, Modes md) {
    int r = blockIdx.x;          // 64
    int m = r >> 1;
    int im = md.v[m];
    const float w0 = 6.283185307179586f / 512.0f;
    for (int l = threadIdx.x; l < LL; l += 64) {
        int red = (im * l) & 511;
        float ang = w0 * (float)red;
        float v = (r & 1) ? sinf(ang) : cosf(ang);
        Tb[r * 512 + l] = __float2bfloat16(v);
    }
}

// ---------------- synthesis matrix (k-major): Sk[k][l] ----------------------------------
__global__ void k_sgen(__hip_bfloat16* __restrict__ Sk) {
    int k = blockIdx.x;          // 64
    int m = k >> 1;
    const float w0 = 6.283185307179586f / 512.0f;
    for (int l = threadIdx.x; l < LL; l += 64) {
        int red = (m * l) & 511;
        float ang = w0 * (float)red;
        float v;
        if ((k & 1) == 0) v = cosf(ang) * (m == 0 ? (1.0f / 512.0f) : (2.0f / 512.0f));
        else              v = -sinf(ang) * (2.0f / 512.0f);
        Sk[k * 512 + l] = __float2bfloat16(v);
    }
}

// ---------------- transpose: X[b][l][d] fp32 -> XT[b][d][l] bf16 -------------------------
__global__ __launch_bounds__(256) void k_xt(const float* __restrict__ X,
                                            __hip_bfloat16* __restrict__ XT) {
    int b = blockIdx.z;
    int l0 = blockIdx.x * 64, d0 = blockIdx.y * 64;
    __shared__ float s[64][65];
    const float* xb = X + (size_t)b * LL * DD;
    int t = threadIdx.x;
    #pragma unroll
    for (int i = 0; i < 16; ++i) {
        int e = i * 256 + t;
        int lr = e >> 6, dc = e & 63;
        s[lr][dc] = xb[(size_t)(l0 + lr) * DD + d0 + dc];
    }
    __syncthreads();
    __hip_bfloat16* xt = XT + (size_t)b * DD * LL;
    #pragma unroll
    for (int i = 0; i < 16; ++i) {
        int e = i * 256 + t;
        int dr = e >> 6, lc = e & 63;
        xt[(size_t)(d0 + dr) * LL + l0 + lc] = __float2bfloat16(s[lc][dr]);
    }
}

// ---------------- TX[b] = T[64x512] @ XT[b] (contraction over l) -------------------------
__global__ __launch_bounds__(256) void k_tx(const __hip_bfloat16* __restrict__ Tb,
        const __hip_bfloat16* __restrict__ XT, __hip_bfloat16* __restrict__ TX) {
    __shared__ __hip_bfloat16 Ts[64 * 32];
    __shared__ __hip_bfloat16 Xs[128 * 32];
    int b = blockIdx.x, n0 = blockIdx.y * 128;
    int t = threadIdx.x, w = t >> 6, ln = t & 63;
    const __hip_bfloat16* xb = XT + (size_t)b * DD * LL;
    f32x4 acc[4][2] = {};
    for (int k0 = 0; k0 < 512; k0 += 32) {
        {
            int row = w * 16 + (ln >> 2), q = ln & 3;
            gload_lds16(Tb + row * 512 + k0 + q * 8, (char*)Ts + w * 1024);
        }
        #pragma unroll
        for (int i = 0; i < 2; ++i) {
            int s = i * 256 + t;
            int row = s >> 2, q = s & 3;
            gload_lds16(xb + (size_t)(n0 + row) * LL + k0 + q * 8,
                        (char*)Xs + i * 4096 + w * 1024);
        }
        __syncthreads();
        int lr = ln & 15, kc = (ln >> 4) * 8;
        bf16x8 af[4], bfr[2];
        #pragma unroll
        for (int mi = 0; mi < 4; ++mi)
            af[mi] = *(const bf16x8*)&Ts[(mi * 16 + lr) * 32 + kc];
        #pragma unroll
        for (int ni = 0; ni < 2; ++ni)
            bfr[ni] = *(const bf16x8*)&Xs[(w * 32 + ni * 16 + lr) * 32 + kc];
        #pragma unroll
        for (int mi = 0; mi < 4; ++mi)
            #pragma unroll
            for (int ni = 0; ni < 2; ++ni)
                acc[mi][ni] = __builtin_amdgcn_mfma_f32_16x16x32_bf16(
                    af[mi], bfr[ni], acc[mi][ni], 0, 0, 0);
        __syncthreads();
    }
    int rb = (ln >> 4) * 4, cb = ln & 15;
    #pragma unroll
    for (int mi = 0; mi < 4; ++mi)
        #pragma unroll
        for (int ni = 0; ni < 2; ++ni)
            #pragma unroll
            for (int j = 0; j < 4; ++j) {
                int m = mi * 16 + rb + j;
                int col = n0 + w * 32 + ni * 16 + cb;
                TX[(size_t)(b * 64 + m) * 512 + col] =
                    __float2bfloat16(acc[mi][ni][j]);
            }
}

// ---------------- SW = Sk(64k x 512l) @ WoT^T; written transposed SWT[dc][k] -------------
__global__ __launch_bounds__(256) void k_swt(const __hip_bfloat16* __restrict__ Sk,
        const __hip_bfloat16* __restrict__ WT, __hip_bfloat16* __restrict__ SWT) {
    __shared__ __hip_bfloat16 Ts[64 * 32];
    __shared__ __hip_bfloat16 Xs[128 * 32];
    int n0 = blockIdx.x * 128;
    int t = threadIdx.x, w = t >> 6, ln = t & 63;
    f32x4 acc[4][2] = {};
    for (int k0 = 0; k0 < 512; k0 += 32) {
        {
            int row = w * 16 + (ln >> 2), q = ln & 3;
            gload_lds16(Sk + row * 512 + k0 + q * 8, (char*)Ts + w * 1024);
        }
        #pragma unroll
        for (int i = 0; i < 2; ++i) {
            int s = i * 256 + t;
            int row = s >> 2, q = s & 3;
            gload_lds16(WT + (size_t)(n0 + row) * 512 + k0 + q * 8,
                        (char*)Xs + i * 4096 + w * 1024);
        }
        __syncthreads();
        int lr = ln & 15, kc = (ln >> 4) * 8;
        bf16x8 af[4], bfr[2];
        #pragma unroll
        for (int mi = 0; mi < 4; ++mi)
            af[mi] = *(const bf16x8*)&Ts[(mi * 16 + lr) * 32 + kc];
        #pragma unroll
        for (int ni = 0; ni < 2; ++ni)
            bfr[ni] = *(const bf16x8*)&Xs[(w * 32 + ni * 16 + lr) * 32 + kc];
        #pragma unroll
        for (int mi = 0; mi < 4; ++mi)
            #pragma unroll
            for (int ni = 0; ni < 2; ++ni)
                acc[mi][ni] = __builtin_amdgcn_mfma_f32_16x16x32_bf16(
                    af[mi], bfr[ni], acc[mi][ni], 0, 0, 0);
        __syncthreads();
    }
    int rb = (ln >> 4) * 4, cb = ln & 15;
    #pragma unroll
    for (int mi = 0; mi < 4; ++mi)
        #pragma unroll
        for (int ni = 0; ni < 2; ++ni)
            #pragma unroll
            for (int j = 0; j < 4; ++j) {
                int k = mi * 16 + rb + j;
                int col = n0 + w * 32 + ni * 16 + cb;   // dc
                SWT[(size_t)col * 64 + k] = __float2bfloat16(acc[mi][ni][j]);
            }
}

// ---------------- XG = TX @ Wq (+bias for im==0), scatter to [hm][e*32+b] ----------------
__global__ __launch_bounds__(256) void k_xg(const __hip_bfloat16* __restrict__ A,
        const __hip_bfloat16* __restrict__ Bt, const float* __restrict__ bq,
        float* __restrict__ XGr, float* __restrict__ XGi, Modes md) {
    __shared__ __hip_bfloat16 As[128 * 32];
    __shared__ __hip_bfloat16 Bs[128 * 32];
    int t = threadIdx.x;
    int m0 = blockIdx.x * 128, n0 = blockIdx.y * 128;
    int w = t >> 6, ln = t & 63;
    int wr = w >> 1, wc = w & 1;
    const int K = 512;
    f32x4 acc[4][4] = {};
    for (int k0 = 0; k0 < K; k0 += 32) {
        #pragma unroll
        for (int i = 0; i < 2; ++i) {
            int s = i * 256 + t;
            int row = s >> 2, q = s & 3;
            gload_lds16(A + (size_t)(m0 + row) * K + k0 + q * 8,
                        (char*)As + i * 4096 + w * 1024);
            gload_lds16(Bt + (size_t)(n0 + row) * K + k0 + q * 8,
                        (char*)Bs + i * 4096 + w * 1024);
        }
        __syncthreads();
        bf16x8 af[4], bfr[4];
        int lr = ln & 15, kc = (ln >> 4) * 8;
        #pragma unroll
        for (int mi = 0; mi < 4; ++mi)
            af[mi] = *(const bf16x8*)&As[(wr * 64 + mi * 16 + lr) * 32 + kc];
        #pragma unroll
        for (int ni = 0; ni < 4; ++ni)
            bfr[ni] = *(const bf16x8*)&Bs[(wc * 64 + ni * 16 + lr) * 32 + kc];
        #pragma unroll
        for (int mi = 0; mi < 4; ++mi)
            #pragma unroll
            for (int ni = 0; ni < 4; ++ni)
                acc[mi][ni] = __builtin_amdgcn_mfma_f32_16x16x32_bf16(
                    af[mi], bfr[ni], acc[mi][ni], 0, 0, 0);
        __syncthreads();
    }
    int rb = (ln >> 4) * 4, cb = ln & 15;
    #pragma unroll
    for (int mi = 0; mi < 4; ++mi) {
        #pragma unroll
        for (int ni = 0; ni < 4; ++ni) {
            int col = n0 + wc * 64 + ni * 16 + cb;
            int h = col >> 6, e = col & 63;
            #pragma unroll
            for (int j = 0; j < 4; ++j) {
                int row = m0 + wr * 64 + mi * 16 + rb + j;
                int b = row >> 6, r = row & 63, m = r >> 1;
                float v = acc[mi][ni][j];
                int off = (h * 32 + m) * 2048 + e * 32 + b;
                if ((r & 1) == 0)
                    XGr[off] = v + (md.v[m] == 0 ? 512.f * bq[col] : 0.f);
                else
                    XGi[off] = -v;
            }
        }
    }
}

// ---------------- FFN GEMM: 3-buffer 1-barrier counted-vmcnt pipeline, BK=64, 512 thr ----
// STAGE(kt+2) issued BEFORE compute(kt): fetch fully overlaps MFMA. XOR-swizzled LDS.
// EPI 1: gelu -> bf16 Cb; EPI 2: fp32 C.
template<int BM, int BN, int WGM, int WGN, int EPI>
__global__ __launch_bounds__(512, 2) void k_ffn(const __hip_bfloat16* __restrict__ A,
        const __hip_bfloat16* __restrict__ Bt, float* __restrict__ C,
        __hip_bfloat16* __restrict__ Cb, int M, int N, int K) {
    constexpr int WRM = BM / WGM;              // 64
    constexpr int WCN = BN / WGN;              // 64
    constexpr int FM = WRM / 16;               // 4
    constexpr int FN = WCN / 16;               // 4
    constexpr int TILE = (BM + BN) * 64;       // elements per buffer
    __shared__ __hip_bfloat16 lds[3 * TILE];   // 144 KB
    int t = threadIdx.x, w = t >> 6, ln = t & 63;
    int wr = w / WGN, wc = w % WGN;
    int lr = ln & 15, kc16 = ln >> 4;
    int m0 = blockIdx.x * BM, n0 = blockIdx.y * BN;
    f32x4 acc[FM][FN] = {};
    int NT = K / 64;

    auto STAGE = [&](int buf, int kt) {
        int kb = kt * 64;
        char* ldsA = (char*)(lds + buf * TILE);
        char* ldsB = ldsA + BM * 128;
        #pragma unroll
        for (int i = 0; i < BM / 64; ++i) {
            int c = i * 512 + t;
            int row = c >> 3, q = c & 7;
            int slot = q ^ (row & 7);
            gload_lds16(A + (size_t)(m0 + row) * K + kb + slot * 8,
                        ldsA + (i * 512 + w * 64) * 16);
        }
        #pragma unroll
        for (int i = 0; i < BN / 64; ++i) {
            int c = i * 512 + t;
            int row = c >> 3, q = c & 7;
            int slot = q ^ (row & 7);
            gload_lds16(Bt + (size_t)(n0 + row) * K + kb + slot * 8,
                        ldsB + (i * 512 + w * 64) * 16);
        }
    };

    STAGE(0, 0);
    STAGE(1, 1);
    for (int kt = 0; kt < NT; ++kt) {
        // tile kt landed (next tile's 6 loads may stay in flight)
        if (kt + 1 < NT) asm volatile("s_waitcnt vmcnt(6)" ::: "memory");
        else             asm volatile("s_waitcnt vmcnt(0)" ::: "memory");
        __builtin_amdgcn_sched_barrier(0);
        __builtin_amdgcn_s_barrier();      // also orders: readers of buf[(kt+2)%3]
        __builtin_amdgcn_sched_barrier(0); // (= tile kt-1's compute) are done
        if (kt + 2 < NT) STAGE((kt + 2) % 3, kt + 2);
        const __hip_bfloat16* As = lds + (kt % 3) * TILE;
        const __hip_bfloat16* Bs = As + BM * 64;
        __builtin_amdgcn_s_setprio(1);
        #pragma unroll
        for (int ks = 0; ks < 2; ++ks) {
            bf16x8 a[FM], b[FN];
            #pragma unroll
            for (int mi = 0; mi < FM; ++mi) {
                int row = wr * WRM + mi * 16 + lr;
                int s = (ks * 4 + kc16) ^ (row & 7);
                a[mi] = *(const bf16x8*)&As[row * 64 + s * 8];
            }
            #pragma unroll
            for (int ni = 0; ni < FN; ++ni) {
                int row = wc * WCN + ni * 16 + lr;
                int s = (ks * 4 + kc16) ^ (row & 7);
                b[ni] = *(const bf16x8*)&Bs[row * 64 + s * 8];
            }
            #pragma unroll
            for (int mi = 0; mi < FM; ++mi)
                #pragma unroll
                for (int ni = 0; ni < FN; ++ni)
                    acc[mi][ni] = __builtin_amdgcn_mfma_f32_16x16x32_bf16(
                        a[mi], b[ni], acc[mi][ni], 0, 0, 0);
        }
        __builtin_amdgcn_s_setprio(0);
    }
    int rb = kc16 * 4;
    #pragma unroll
    for (int mi = 0; mi < FM; ++mi) {
        #pragma unroll
        for (int ni = 0; ni < FN; ++ni) {
            int col = n0 + wc * WCN + ni * 16 + lr;
            int rowb = m0 + wr * WRM + mi * 16 + rb;
            #pragma unroll
            for (int j = 0; j < 4; ++j) {
                float v = acc[mi][ni][j];
                size_t off = (size_t)(rowb + j) * N + col;
                if (EPI == 1) Cb[off] = __float2bfloat16(gelu_f(v));
                else C[off] = v;
            }
        }
    }
}

// ---------------- og: per (h,m) complex GEMM -> OGT[b][he][k=2m|2m+1] bf16 ---------------
__global__ __launch_bounds__(256) void k_og(const float* __restrict__ XGr,
        const float* __restrict__ XGi, const float2* __restrict__ WM,
        __hip_bfloat16* __restrict__ OGT) {
    int hm = blockIdx.x;      // h*32+m
    int t = threadIdx.x;
    __shared__ float2 sw[4096];
    __shared__ float sxr[2048], sxi[2048];
    const float2* w = WM + (size_t)hm * 4096;
    for (int i = t; i < 4096; i += 256) sw[i] = w[i];
    const float* xr = XGr + hm * 2048;
    const float* xi = XGi + hm * 2048;
    for (int i = t; i < 2048; i += 256) { sxr[i] = xr[i]; sxi[i] = xi[i]; }
    __syncthreads();
    int b = t >> 3, o0 = (t & 7) * 8;
    float ar[8] = {}, ai[8] = {};
    for (int e = 0; e < 64; ++e) {
        float xrv = sxr[e * 32 + b], xiv = sxi[e * 32 + b];
        #pragma unroll
        for (int j = 0; j < 8; ++j) {
            float2 wv = sw[e * 64 + o0 + j];
            ar[j] = fmaf(xrv, wv.x, fmaf(-xiv, wv.y, ar[j]));
            ai[j] = fmaf(xrv, wv.y, fmaf( xiv, wv.x, ai[j]));
        }
    }
    int h = hm >> 5, m = hm & 31;
    __hip_bfloat16* og = OGT + (size_t)b * (512 * 64);
    #pragma unroll
    for (int j = 0; j < 8; ++j) {
        int he = h * 64 + o0 + j;
        union { __hip_bfloat16 h2[2]; uint32_t u; } pk;
        pk.h2[0] = __float2bfloat16(ar[j]);
        pk.h2[1] = __float2bfloat16(ai[j]);
        *(uint32_t*)&og[he * 64 + 2 * m] = pk.u;
    }
}

// ---------------- new_x[b][he][dc] = OGT[b](512he x 64k) @ SWT^T + bo --------------------
__global__ __launch_bounds__(256) void k_nx(const __hip_bfloat16* __restrict__ OGT,
        const __hip_bfloat16* __restrict__ SWT, const float* __restrict__ bo,
        float* __restrict__ C) {
    __shared__ __hip_bfloat16 As[128 * 32];
    __shared__ __hip_bfloat16 Bs[128 * 32];
    int t = threadIdx.x;
    int m0 = blockIdx.x * 128, n0 = blockIdx.y * 128, b = blockIdx.z;
    int w = t >> 6, ln = t & 63;
    int wr = w >> 1, wc = w & 1;
    const __hip_bfloat16* ab = OGT + (size_t)b * 512 * 64;
    f32x4 acc[4][4] = {};
    for (int k0 = 0; k0 < 64; k0 += 32) {
        #pragma unroll
        for (int i = 0; i < 2; ++i) {
            int s = i * 256 + t;
            int row = s >> 2, q = s & 3;
            gload_lds16(ab + (size_t)(m0 + row) * 64 + k0 + q * 8,
                        (char*)As + i * 4096 + w * 1024);
            gload_lds16(SWT + (size_t)(n0 + row) * 64 + k0 + q * 8,
                        (char*)Bs + i * 4096 + w * 1024);
        }
        __syncthreads();
        bf16x8 af[4], bfr[4];
        int lr = ln & 15, kc = (ln >> 4) * 8;
        #pragma unroll
        for (int mi = 0; mi < 4; ++mi)
            af[mi] = *(const bf16x8*)&As[(wr * 64 + mi * 16 + lr) * 32 + kc];
        #pragma unroll
        for (int ni = 0; ni < 4; ++ni)
            bfr[ni] = *(const bf16x8*)&Bs[(wc * 64 + ni * 16 + lr) * 32 + kc];
        #pragma unroll
        for (int mi = 0; mi < 4; ++mi)
            #pragma unroll
            for (int ni = 0; ni < 4; ++ni)
                acc[mi][ni] = __builtin_amdgcn_mfma_f32_16x16x32_bf16(
                    af[mi], bfr[ni], acc[mi][ni], 0, 0, 0);
        __syncthreads();
    }
    int rb = (ln >> 4) * 4, cb = ln & 15;
    #pragma unroll
    for (int mi = 0; mi < 4; ++mi) {
        #pragma unroll
        for (int ni = 0; ni < 4; ++ni) {
            int col = n0 + wc * 64 + ni * 16 + cb;
            int he = m0 + wr * 64 + mi * 16 + rb;
            float bv = bo[col];
            #pragma unroll
            for (int j = 0; j < 4; ++j)
                C[((size_t)b * 512 + he + j) * 512 + col] = acc[mi][ni][j] + bv;
        }
    }
}

// ---------------- s = P + Q; out = s - movavg25(s); dual fp32+bf16, L-chunked ------------
__global__ void k_add_decomp(const float* __restrict__ P, const float* __restrict__ Q,
                             float* __restrict__ Out, __hip_bfloat16* __restrict__ Outb) {
    int b = blockIdx.x >> 3;
    int l0 = (blockIdx.x & 7) * 64;
    int d = threadIdx.x;
    const float* p = P + (size_t)b * LL * DD + d;
    const float* q = Q + (size_t)b * LL * DD + d;
    float* o = Out + (size_t)b * LL * DD + d;
    __hip_bfloat16* ob = Outb + (size_t)b * LL * DD + d;
    float sum = 0.f;
    for (int j = l0 - 12; j <= l0 + 12; ++j) {
        int jc = j < 0 ? 0 : (j > 511 ? 511 : j);
        sum += p[jc * DD] + q[jc * DD];
    }
    for (int l = l0; l < l0 + 64; ++l) {
        float sv = p[l * DD] + q[l * DD];
        float r = sv - sum * (1.0f / 25.0f);
        o[l * DD] = r;
        ob[l * DD] = __float2bfloat16(r);
        int lp = l + 13 > 511 ? 511 : l + 13;
        int lm = l - 12 < 0 ? 0 : l - 12;
        sum += (p[lp * DD] + q[lp * DD]) - (p[lm * DD] + q[lm * DD]);
    }
}

// ---------------- LayerNorm over D ----------------
__global__ void k_ln(const float* __restrict__ Xin, const float* __restrict__ lw,
                     const float* __restrict__ lb, float* __restrict__ Out) {
    int row = blockIdx.x;
    int t = threadIdx.x;
    const float4* x4 = (const float4*)(Xin + (size_t)row * DD);
    float4 v0 = x4[t], v1 = x4[t + 64];
    float s = v0.x + v0.y + v0.z + v0.w + v1.x + v1.y + v1.z + v1.w;
    #pragma unroll
    for (int o = 32; o; o >>= 1) s += __shfl_down(s, o);
    float mu = __shfl(s, 0) * (1.0f / 512.0f);
    float d0 = v0.x - mu, d1 = v0.y - mu, d2 = v0.z - mu, d3 = v0.w - mu;
    float d4 = v1.x - mu, d5 = v1.y - mu, d6 = v1.z - mu, d7 = v1.w - mu;
    float vs = d0*d0 + d1*d1 + d2*d2 + d3*d3 + d4*d4 + d5*d5 + d6*d6 + d7*d7;
    #pragma unroll
    for (int o = 32; o; o >>= 1) vs += __shfl_down(vs, o);
    float var = __shfl(vs, 0) * (1.0f / 512.0f);
    float rstd = rsqrtf(var + 1e-5f);
    float4 w0 = ((const float4*)lw)[t], w1 = ((const float4*)lw)[t + 64];
    float4 b0 = ((const float4*)lb)[t], b1 = ((const float4*)lb)[t + 64];
    float4 r0, r1;
    r0.x = d0 * rstd * w0.x + b0.x; r0.y = d1 * rstd * w0.y + b0.y;
    r0.z = d2 * rstd * w0.z + b0.z; r0.w = d3 * rstd * w0.w + b0.w;
    r1.x = d4 * rstd * w1.x + b1.x; r1.y = d5 * rstd * w1.y + b1.y;
    r1.z = d6 * rstd * w1.z + b1.z; r1.w = d7 * rstd * w1.w + b1.w;
    float4* o4 = (float4*)(Out + (size_t)row * DD);
    o4[t] = r0; o4[t + 64] = r1;
}

// ---------------- column (temporal) mean over L per (b,d): 256 blocks, 4-way L-split -----
__global__ void k_colmean(const float* __restrict__ A, float* __restrict__ CM) {
    int col0 = blockIdx.x * 64;
    int part = threadIdx.x >> 6;
    int cl = threadIdx.x & 63;
    int col = col0 + cl;
    int b = col >> 9, d = col & 511;
    const float* a = A + (size_t)b * LL * DD + d;
    float s = 0.f;
    for (int l = part * 128; l < part * 128 + 128; ++l) s += a[l * DD];
    __shared__ float red[4][64];
    red[part][cl] = s;
    __syncthreads();
    if (threadIdx.x < 64) {
        float v = red[0][cl] + red[1][cl] + red[2][cl] + red[3][cl];
        CM[col0 + cl] = v * (1.0f / 512.0f);
    }
}

__global__ void k_gelu_sub(float* __restrict__ A, const float* __restrict__ CM) {
    int i = blockIdx.x * 256 + threadIdx.x;
    int b = i >> 18, d = i & 511;
    float v = A[i] - CM[(b << 9) | d];
    A[i] = gelu_f(v);
}

// ---------------- final projection [B, L*D] @ [L*D, 10] ----------------
__global__ __launch_bounds__(256) void k_proj_partial(const float* __restrict__ A,
        const float* __restrict__ PW, float* __restrict__ PP) {
    int b = blockIdx.x, c = blockIdx.y;
    int t = threadIdx.x;
    float acc[NCC] = {};
    const float* a = A + (size_t)b * LL * DD;
    int i0 = c * 16384, i1 = i0 + 16384;
    for (int i = i0 + t; i < i1; i += 256) {
        float v = a[i];
        const float* w = PW + (size_t)i * NCC;
        #pragma unroll
        for (int n = 0; n < NCC; ++n) acc[n] = fmaf(v, w[n], acc[n]);
    }
    __shared__ float red[4][NCC];
    int lane = t & 63, wv = t >> 6;
    #pragma unroll
    for (int n = 0; n < NCC; ++n) {
        float s = acc[n];
        #pragma unroll
        for (int o = 32; o; o >>= 1) s += __shfl_down(s, o);
        if (lane == 0) red[wv][n] = s;
    }
    __syncthreads();
    if (t < NCC) {
        PP[(b * 16 + c) * NCC + t] = red[0][t] + red[1][t] + red[2][t] + red[3][t];
    }
}

__global__ void k_proj_final(const float* __restrict__ PP, const float* __restrict__ pb,
                             float* __restrict__ out) {
    int t = threadIdx.x;
    if (t >= BB * NCC) return;
    int b = t / NCC, n = t % NCC;
    float s = pb[n];
    for (int c = 0; c < 16; ++c) s += PP[(b * 16 + c) * NCC + n];
    out[t] = s;
}

// ---------------- numpy legacy RandomState(0) modes replication ----------------
static void compute_modes(int* out) {
    static uint32_t mt[624];
    uint32_t s = 0u;
    mt[0] = s;
    for (int i = 1; i < 624; ++i)
        mt[i] = 1812433253u * (mt[i - 1] ^ (mt[i - 1] >> 30)) + (uint32_t)i;
    int mti = 624;
    auto genrand = [&]() -> uint32_t {
        if (mti >= 624) {
            for (int k = 0; k < 624; ++k) {
                uint32_t y = (mt[k] & 0x80000000u) | (mt[(k + 1) % 624] & 0x7fffffffu);
                mt[k] = mt[(k + 397) % 624] ^ (y >> 1) ^ ((y & 1u) ? 2567483615u : 0u);
            }
            mti = 0;
        }
        uint32_t y = mt[mti++];
        y ^= y >> 11;
        y ^= (y << 7) & 2636928640u;
        y ^= (y << 15) & 4022730752u;
        y ^= y >> 18;
        return y;
    };
    int idx[256];
    for (int i = 0; i < 256; ++i) idx[i] = i;
    for (int i = 255; i >= 1; --i) {
        uint32_t mx = (uint32_t)i;
        uint32_t mask = mx;
        mask |= mask >> 1; mask |= mask >> 2; mask |= mask >> 4;
        mask |= mask >> 8; mask |= mask >> 16;
        uint32_t j;
        while ((j = (genrand() & mask)) > mx) {}
        int tmp = idx[i]; idx[i] = idx[j]; idx[j] = tmp;
    }
    int sel[NM];
    for (int i = 0; i < NM; ++i) sel[i] = idx[i];
    std::sort(sel, sel + NM);
    for (int i = 0; i < NM; ++i) out[i] = sel[i];
}

extern "C" void kernel_launch(void* const* d_in, const int* in_sizes, int n_in,
                              void* d_out, int out_size, void* d_ws, size_t ws_size,
                              hipStream_t stream) {
    const float* xe  = (const float*)d_in[0];
    const float* tw  = (const float*)d_in[1];
    const float* Wq  = (const float*)d_in[2];
    const float* bq  = (const float*)d_in[3];
    const float* Wo  = (const float*)d_in[8];
    const float* bo  = (const float*)d_in[9];
    const float* fwr = (const float*)d_in[10];
    const float* fwi = (const float*)d_in[11];
    const float* W1  = (const float*)d_in[12];
    const float* W2  = (const float*)d_in[13];
    const float* lw  = (const float*)d_in[14];
    const float* lb  = (const float*)d_in[15];
    const float* pw  = (const float*)d_in[16];
    const float* pb  = (const float*)d_in[17];
    float* out = (float*)d_out;

    const size_t NX = (size_t)BB * LL * DD;        // 8388608
    const size_t NHF = (size_t)BB * LL * NDFF;     // 33554432
    const size_t NXG = (size_t)BB * NH * EHH * NM; // 524288
    const size_t NWM = (size_t)NH * NM * EHH * EHH;// 1048576 float2

    char* wsb = (char*)d_ws;
    size_t off = 0;
    float* X1  = (float*)(wsb + off); off += NX * 4;
    float* X2  = (float*)(wsb + off); off += NX * 4;
    float* TB  = (float*)(wsb + off); off += NX * 4;
    float* XGr = (float*)(wsb + off); off += NXG * 4;
    float* XGi = (float*)(wsb + off); off += NXG * 4;
    __hip_bfloat16* X1b = (__hip_bfloat16*)(wsb + off); off += NX * 2;
    __hip_bfloat16* X2b = (__hip_bfloat16*)(wsb + off); off += NX * 2;
    __hip_bfloat16* HMb = (__hip_bfloat16*)(wsb + off); off += NHF * 2;
    __hip_bfloat16* WT  = (__hip_bfloat16*)(wsb + off); off += (size_t)DD * DD * 2;
    float2* WM          = (float2*)(wsb + off);         off += NWM * 8;
    __hip_bfloat16* TXb = (__hip_bfloat16*)(wsb + off); off += (size_t)BB * 64 * 512 * 2;
    __hip_bfloat16* Tb  = (__hip_bfloat16*)(wsb + off); off += (size_t)64 * 512 * 2;
    __hip_bfloat16* OGT = (__hip_bfloat16*)(wsb + off); off += (size_t)BB * 512 * 64 * 2;
    __hip_bfloat16* Sk  = (__hip_bfloat16*)(wsb + off); off += (size_t)64 * 512 * 2;
    __hip_bfloat16* WTq = (__hip_bfloat16*)(wsb + off); off += (size_t)NEL * DD * DD * 2;
    __hip_bfloat16* WT1 = (__hip_bfloat16*)(wsb + off); off += (size_t)NEL * DD * NDFF * 2;
    __hip_bfloat16* WT2 = (__hip_bfloat16*)(wsb + off); off += (size_t)NEL * NDFF * DD * 2;
    __hip_bfloat16* SW3 = (__hip_bfloat16*)(wsb + off); off += (size_t)NEL * DD * 64 * 2;
    float* PE           = (float*)(wsb + off);          off += (size_t)LL * DD * 4;
    if (ws_size < off) return;

    // XTb (16.8 MB) aliases TB (33.5 MB): TB is dead from layer start until k_nx writes it.
    __hip_bfloat16* XTb = (__hip_bfloat16*)TB;

    Modes mi;
    compute_modes(mi.v);

    // ---- upfront: PE table, embedding, twiddle/synthesis tables, ALL weight preps ----
    k_pegen<<<512, 256, 0, stream>>>(PE);
    k_embed<<<dim3(16, 2, BB), 256, 0, stream>>>(xe, tw, PE, X1, X1b);
    k_tgen<<<64, 64, 0, stream>>>(Tb, mi);
    k_sgen<<<64, 64, 0, stream>>>(Sk);
    for (int li = 0; li < NEL; ++li) {
        k_wt<<<dim3(16, 16), 256, 0, stream>>>(Wq + (size_t)li * DD * DD,
                                               WTq + (size_t)li * DD * DD, DD, DD);
        k_wt<<<dim3(64, 16), 256, 0, stream>>>(W1 + (size_t)li * DD * NDFF,
                                               WT1 + (size_t)li * DD * NDFF, DD, NDFF);
        k_wt<<<dim3(16, 64), 256, 0, stream>>>(W2 + (size_t)li * NDFF * DD,
                                               WT2 + (size_t)li * NDFF * DD, NDFF, DD);
        k_wt<<<dim3(16, 16), 256, 0, stream>>>(Wo + (size_t)li * DD * DD, WT, DD, DD);
        k_swt<<<4, 256, 0, stream>>>(Sk, WT, SW3 + (size_t)li * DD * 64);
    }

    float* cur = X1;            float* alt = X2;
    __hip_bfloat16* curb = X1b; __hip_bfloat16* altb = X2b;
    const int M = BB * LL;      // 16384

    for (int li = 0; li < NEL; ++li) {
        k_wfm<<<NH * EHH, 256, 0, stream>>>(fwr, fwi, WM, li);
        k_xt<<<dim3(8, 8, BB), 256, 0, stream>>>(cur, XTb);
        k_tx<<<dim3(BB, 4), 256, 0, stream>>>(Tb, XTb, TXb);
        k_xg<<<dim3(16, 4), 256, 0, stream>>>(TXb, WTq + (size_t)li * DD * DD,
                                              bq + li * DD, XGr, XGi, mi);
        k_og<<<NH * NM, 256, 0, stream>>>(XGr, XGi, WM, OGT);
        k_nx<<<dim3(4, 4, BB), 256, 0, stream>>>(OGT, SW3 + (size_t)li * DD * 64,
                                                 bo + li * DD, TB);
        k_add_decomp<<<BB * 8, DD, 0, stream>>>(cur, TB, alt, altb);
        { float* t_ = cur; cur = alt; alt = t_; }
        { __hip_bfloat16* t_ = curb; curb = altb; altb = t_; }
        // ---- FFN: 3-buffer overlapped-fetch MFMA GEMMs ----
        k_ffn<256, 128, 4, 2, 1><<<dim3(M / 256, NDFF / 128), 512, 0, stream>>>(
            curb, WT1 + (size_t)li * DD * NDFF, nullptr, HMb, M, NDFF, DD);
        k_ffn<128, 256, 2, 4, 2><<<dim3(M / 128, DD / 256), 512, 0, stream>>>(
            HMb, WT2 + (size_t)li * NDFF * DD, TB, nullptr, M, DD, NDFF);
        k_add_decomp<<<BB * 8, DD, 0, stream>>>(cur, TB, alt, altb);
        { float* t_ = cur; cur = alt; alt = t_; }
        { __hip_bfloat16* t_ = curb; curb = altb; altb = t_; }
    }

    // ---- final: LayerNorm -> subtract temporal mean -> gelu -> projection ----
    k_ln<<<BB * LL, 64, 0, stream>>>(cur, lw, lb, TB);
    float* CM = XGr;
    float* PP = XGi;
    k_colmean<<<256, 256, 0, stream>>>(TB, CM);
    k_gelu_sub<<<32768, 256, 0, stream>>>(TB, CM);
    k_proj_partial<<<dim3(BB, 16), 256, 0, stream>>>(TB, pw, PP);
    k_proj_final<<<1, 320, 0, stream>>>(PP, pb, out);
}

// Round 10
// 906.194 us; speedup vs baseline: 6.4081x; 1.0332x over previous
//
#include <hip/hip_runtime.h>
#include <hip/hip_bf16.h>
#include <stdint.h>
#include <algorithm>

#define BB  32
#define LL  512
#define NCI 21
#define DD  512
#define NH  8
#define EHH 64
#define NDFF 2048
#define NM  32
#define NEL 3
#define NCC 10

struct Modes { int v[NM]; };

typedef __bf16 bf16x8 __attribute__((ext_vector_type(8)));
typedef float f32x4 __attribute__((ext_vector_type(4)));

// A&S 7.1.26 erf, |eps| <= 1.5e-7, branchless
__device__ __forceinline__ float erf_poly(float x) {
    float ax = fabsf(x);
    float t = 1.0f / fmaf(0.3275911f, ax, 1.0f);
    float y = t * fmaf(t, fmaf(t, fmaf(t, fmaf(t, 1.061405429f, -1.453152027f),
                                       1.421413741f), -0.284496736f), 0.254829592f);
    float r = 1.0f - y * __expf(-ax * ax);
    return copysignf(r, x);
}

__device__ __forceinline__ float gelu_f(float x) {
    return 0.5f * x * (1.0f + erf_poly(x * 0.7071067811865475f));
}

__device__ __forceinline__ void gload_lds16(const void* g, void* l) {
    __builtin_amdgcn_global_load_lds((const __attribute__((address_space(1))) void*)g,
                                     (__attribute__((address_space(3))) void*)l, 16, 0, 0);
}

// ---------------- positional-encoding table PE[l][d] ----------------
__global__ void k_pegen(float* __restrict__ PE) {
    int l = blockIdx.x;              // 512
    for (int d = threadIdx.x; d < DD; d += 256) {
        int a = d & ~1;
        float freq = expf((float)a * (-9.210340371976184f / 512.0f));
        float v = (float)l * freq;
        PE[l * DD + d] = (d & 1) ? cosf(v) : sinf(v);
    }
}

// ---------------- embedding: conv1d(k=3, circular) + PE table; tw held in registers -----
__global__ __launch_bounds__(256) void k_embed(const float* __restrict__ xe,
        const float* __restrict__ tw, const float* __restrict__ PE,
        float* __restrict__ X, __hip_bfloat16* __restrict__ Xb) {
    int lc = blockIdx.x, dh = blockIdx.y, b = blockIdx.z;
    int t = threadIdx.x;
    int d = dh * 256 + t;
    __shared__ float s_xe[34][NCI];
    int l0 = lc * 32;
    for (int i = t; i < 34 * NCI; i += 256) {
        int r = i / NCI, c = i % NCI;
        int ls = (l0 - 1 + r + LL) & (LL - 1);
        s_xe[r][c] = xe[(b * LL + ls) * NCI + c];
    }
    float twr[63];
    #pragma unroll
    for (int kc = 0; kc < 63; ++kc) twr[kc] = tw[kc * DD + d];
    __syncthreads();
    for (int li = 0; li < 32; ++li) {
        int l = l0 + li;
        float acc = 0.f;
        #pragma unroll
        for (int k = 0; k < 3; ++k)
            #pragma unroll
            for (int c = 0; c < NCI; ++c)
                acc = fmaf(s_xe[li + k][c], twr[k * NCI + c], acc);
        float r = acc + PE[l * DD + d];
        size_t off = ((size_t)(b * LL + l)) * DD + d;
        X[off] = r;
        Xb[off] = __float2bfloat16(r);
    }
}

// ---------------- weight convert+transpose: W[K][N] fp32 -> WT[N][K] bf16 ----------------
__global__ void k_wt(const float* __restrict__ W, __hip_bfloat16* __restrict__ WT,
                     int K, int N) {
    __shared__ float s[32][33];
    int bx = blockIdx.x;
    int by = blockIdx.y;
    int t = threadIdx.x;
    int r = t >> 5, c = t & 31;
    #pragma unroll
    for (int i = 0; i < 4; ++i)
        s[r + i * 8][c] = W[(size_t)(by * 32 + r + i * 8) * N + bx * 32 + c];
    __syncthreads();
    #pragma unroll
    for (int i = 0; i < 4; ++i) {
        int n = bx * 32 + r + i * 8;
        WT[(size_t)n * K + by * 32 + c] = __float2bfloat16(s[c][r + i * 8]);
    }
}

// ---------------- fourier weight transpose: fw[h,e,o,m] -> WM[h][m][e][o] float2 ---------
__global__ void k_wfm(const float* __restrict__ fwr, const float* __restrict__ fwi,
                      float2* __restrict__ WM, int li) {
    int blk = blockIdx.x;        // h*64 + e
    int h = blk >> 6, e = blk & 63;
    int t = threadIdx.x;
    __shared__ float2 s[32][65];
    const float* br = fwr + (((size_t)(li * NH + h) * EHH + e) * EHH) * NM;
    const float* bi = fwi + (((size_t)(li * NH + h) * EHH + e) * EHH) * NM;
    for (int i = t; i < 2048; i += 256) {
        int o = i >> 5, m = i & 31;
        s[m][o] = make_float2(br[i], bi[i]);
    }
    __syncthreads();
    int mr = t >> 6, o = t & 63;
    for (int m = mr; m < 32; m += 4)
        WM[((size_t)(h * 32 + m)) * 4096 + e * 64 + o] = s[m][o];
}

// ---------------- twiddle matrix: T[2m][l]=cos(w0*im*l), T[2m+1][l]=sin ------------------
__global__ void k_tgen(__hip_bfloat16* __restrict__ Tb, Modes md) {
    int r = blockIdx.x;          // 64
    int m = r >> 1;
    int im = md.v[m];
    const float w0 = 6.283185307179586f / 512.0f;
    for (int l = threadIdx.x; l < LL; l += 64) {
        int red = (im * l) & 511;
        float ang = w0 * (float)red;
        float v = (r & 1) ? sinf(ang) : cosf(ang);
        Tb[r * 512 + l] = __float2bfloat16(v);
    }
}

// ---------------- synthesis matrix (k-major): Sk[k][l] ----------------------------------
__global__ void k_sgen(__hip_bfloat16* __restrict__ Sk) {
    int k = blockIdx.x;          // 64
    int m = k >> 1;
    const float w0 = 6.283185307179586f / 512.0f;
    for (int l = threadIdx.x; l < LL; l += 64) {
        int red = (m * l) & 511;
        float ang = w0 * (float)red;
        float v;
        if ((k & 1) == 0) v = cosf(ang) * (m == 0 ? (1.0f / 512.0f) : (2.0f / 512.0f));
        else              v = -sinf(ang) * (2.0f / 512.0f);
        Sk[k * 512 + l] = __float2bfloat16(v);
    }
}

// ---------------- transpose: X[b][l][d] fp32 -> XT[b][d][l] bf16 -------------------------
__global__ __launch_bounds__(256) void k_xt(const float* __restrict__ X,
                                            __hip_bfloat16* __restrict__ XT) {
    int b = blockIdx.z;
    int l0 = blockIdx.x * 64, d0 = blockIdx.y * 64;
    __shared__ float s[64][65];
    const float* xb = X + (size_t)b * LL * DD;
    int t = threadIdx.x;
    #pragma unroll
    for (int i = 0; i < 16; ++i) {
        int e = i * 256 + t;
        int lr = e >> 6, dc = e & 63;
        s[lr][dc] = xb[(size_t)(l0 + lr) * DD + d0 + dc];
    }
    __syncthreads();
    __hip_bfloat16* xt = XT + (size_t)b * DD * LL;
    #pragma unroll
    for (int i = 0; i < 16; ++i) {
        int e = i * 256 + t;
        int dr = e >> 6, lc = e & 63;
        xt[(size_t)(d0 + dr) * LL + l0 + lc] = __float2bfloat16(s[lc][dr]);
    }
}

// ---------------- TX[b] = T[64x512] @ XT[b] (contraction over l) -------------------------
__global__ __launch_bounds__(256) void k_tx(const __hip_bfloat16* __restrict__ Tb,
        const __hip_bfloat16* __restrict__ XT, __hip_bfloat16* __restrict__ TX) {
    __shared__ __hip_bfloat16 Ts[64 * 32];
    __shared__ __hip_bfloat16 Xs[128 * 32];
    int b = blockIdx.x, n0 = blockIdx.y * 128;
    int t = threadIdx.x, w = t >> 6, ln = t & 63;
    const __hip_bfloat16* xb = XT + (size_t)b * DD * LL;
    f32x4 acc[4][2] = {};
    for (int k0 = 0; k0 < 512; k0 += 32) {
        {
            int row = w * 16 + (ln >> 2), q = ln & 3;
            gload_lds16(Tb + row * 512 + k0 + q * 8, (char*)Ts + w * 1024);
        }
        #pragma unroll
        for (int i = 0; i < 2; ++i) {
            int s = i * 256 + t;
            int row = s >> 2, q = s & 3;
            gload_lds16(xb + (size_t)(n0 + row) * LL + k0 + q * 8,
                        (char*)Xs + i * 4096 + w * 1024);
        }
        __syncthreads();
        int lr = ln & 15, kc = (ln >> 4) * 8;
        bf16x8 af[4], bfr[2];
        #pragma unroll
        for (int mi = 0; mi < 4; ++mi)
            af[mi] = *(const bf16x8*)&Ts[(mi * 16 + lr) * 32 + kc];
        #pragma unroll
        for (int ni = 0; ni < 2; ++ni)
            bfr[ni] = *(const bf16x8*)&Xs[(w * 32 + ni * 16 + lr) * 32 + kc];
        #pragma unroll
        for (int mi = 0; mi < 4; ++mi)
            #pragma unroll
            for (int ni = 0; ni < 2; ++ni)
                acc[mi][ni] = __builtin_amdgcn_mfma_f32_16x16x32_bf16(
                    af[mi], bfr[ni], acc[mi][ni], 0, 0, 0);
        __syncthreads();
    }
    int rb = (ln >> 4) * 4, cb = ln & 15;
    #pragma unroll
    for (int mi = 0; mi < 4; ++mi)
        #pragma unroll
        for (int ni = 0; ni < 2; ++ni)
            #pragma unroll
            for (int j = 0; j < 4; ++j) {
                int m = mi * 16 + rb + j;
                int col = n0 + w * 32 + ni * 16 + cb;
                TX[(size_t)(b * 64 + m) * 512 + col] =
                    __float2bfloat16(acc[mi][ni][j]);
            }
}

// ---------------- SW = Sk(64k x 512l) @ WoT^T; written transposed SWT[dc][k] -------------
__global__ __launch_bounds__(256) void k_swt(const __hip_bfloat16* __restrict__ Sk,
        const __hip_bfloat16* __restrict__ WT, __hip_bfloat16* __restrict__ SWT) {
    __shared__ __hip_bfloat16 Ts[64 * 32];
    __shared__ __hip_bfloat16 Xs[128 * 32];
    int n0 = blockIdx.x * 128;
    int t = threadIdx.x, w = t >> 6, ln = t & 63;
    f32x4 acc[4][2] = {};
    for (int k0 = 0; k0 < 512; k0 += 32) {
        {
            int row = w * 16 + (ln >> 2), q = ln & 3;
            gload_lds16(Sk + row * 512 + k0 + q * 8, (char*)Ts + w * 1024);
        }
        #pragma unroll
        for (int i = 0; i < 2; ++i) {
            int s = i * 256 + t;
            int row = s >> 2, q = s & 3;
            gload_lds16(WT + (size_t)(n0 + row) * 512 + k0 + q * 8,
                        (char*)Xs + i * 4096 + w * 1024);
        }
        __syncthreads();
        int lr = ln & 15, kc = (ln >> 4) * 8;
        bf16x8 af[4], bfr[2];
        #pragma unroll
        for (int mi = 0; mi < 4; ++mi)
            af[mi] = *(const bf16x8*)&Ts[(mi * 16 + lr) * 32 + kc];
        #pragma unroll
        for (int ni = 0; ni < 2; ++ni)
            bfr[ni] = *(const bf16x8*)&Xs[(w * 32 + ni * 16 + lr) * 32 + kc];
        #pragma unroll
        for (int mi = 0; mi < 4; ++mi)
            #pragma unroll
            for (int ni = 0; ni < 2; ++ni)
                acc[mi][ni] = __builtin_amdgcn_mfma_f32_16x16x32_bf16(
                    af[mi], bfr[ni], acc[mi][ni], 0, 0, 0);
        __syncthreads();
    }
    int rb = (ln >> 4) * 4, cb = ln & 15;
    #pragma unroll
    for (int mi = 0; mi < 4; ++mi)
        #pragma unroll
        for (int ni = 0; ni < 2; ++ni)
            #pragma unroll
            for (int j = 0; j < 4; ++j) {
                int k = mi * 16 + rb + j;
                int col = n0 + w * 32 + ni * 16 + cb;   // dc
                SWT[(size_t)col * 64 + k] = __float2bfloat16(acc[mi][ni][j]);
            }
}

// ---------------- XG = TX @ Wq (+bias for im==0), scatter to [hm][e*32+b] ----------------
__global__ __launch_bounds__(256) void k_xg(const __hip_bfloat16* __restrict__ A,
        const __hip_bfloat16* __restrict__ Bt, const float* __restrict__ bq,
        float* __restrict__ XGr, float* __restrict__ XGi, Modes md) {
    __shared__ __hip_bfloat16 As[128 * 32];
    __shared__ __hip_bfloat16 Bs[128 * 32];
    int t = threadIdx.x;
    int m0 = blockIdx.x * 128, n0 = blockIdx.y * 128;
    int w = t >> 6, ln = t & 63;
    int wr = w >> 1, wc = w & 1;
    const int K = 512;
    f32x4 acc[4][4] = {};
    for (int k0 = 0; k0 < K; k0 += 32) {
        #pragma unroll
        for (int i = 0; i < 2; ++i) {
            int s = i * 256 + t;
            int row = s >> 2, q = s & 3;
            gload_lds16(A + (size_t)(m0 + row) * K + k0 + q * 8,
                        (char*)As + i * 4096 + w * 1024);
            gload_lds16(Bt + (size_t)(n0 + row) * K + k0 + q * 8,
                        (char*)Bs + i * 4096 + w * 1024);
        }
        __syncthreads();
        bf16x8 af[4], bfr[4];
        int lr = ln & 15, kc = (ln >> 4) * 8;
        #pragma unroll
        for (int mi = 0; mi < 4; ++mi)
            af[mi] = *(const bf16x8*)&As[(wr * 64 + mi * 16 + lr) * 32 + kc];
        #pragma unroll
        for (int ni = 0; ni < 4; ++ni)
            bfr[ni] = *(const bf16x8*)&Bs[(wc * 64 + ni * 16 + lr) * 32 + kc];
        #pragma unroll
        for (int mi = 0; mi < 4; ++mi)
            #pragma unroll
            for (int ni = 0; ni < 4; ++ni)
                acc[mi][ni] = __builtin_amdgcn_mfma_f32_16x16x32_bf16(
                    af[mi], bfr[ni], acc[mi][ni], 0, 0, 0);
        __syncthreads();
    }
    int rb = (ln >> 4) * 4, cb = ln & 15;
    #pragma unroll
    for (int mi = 0; mi < 4; ++mi) {
        #pragma unroll
        for (int ni = 0; ni < 4; ++ni) {
            int col = n0 + wc * 64 + ni * 16 + cb;
            int h = col >> 6, e = col & 63;
            #pragma unroll
            for (int j = 0; j < 4; ++j) {
                int row = m0 + wr * 64 + mi * 16 + rb + j;
                int b = row >> 6, r = row & 63, m = r >> 1;
                float v = acc[mi][ni][j];
                int off = (h * 32 + m) * 2048 + e * 32 + b;
                if ((r & 1) == 0)
                    XGr[off] = v + (md.v[m] == 0 ? 512.f * bq[col] : 0.f);
                else
                    XGi[off] = -v;
            }
        }
    }
}

// ---------------- FFN GEMM: 128x128 tile, BK=32, 256 thr, 3-buf counted-vmcnt, 3 blk/CU --
// EPI 1: gelu -> bf16 Cb; EPI 2: fp32 C.
template<int EPI>
__global__ __launch_bounds__(256, 3) void k_ffn(const __hip_bfloat16* __restrict__ A,
        const __hip_bfloat16* __restrict__ Bt, float* __restrict__ C,
        __hip_bfloat16* __restrict__ Cb, int M, int N, int K) {
    constexpr int TILE = 256 * 32;             // (128A+128B) x 32k elements = 16 KB
    __shared__ __hip_bfloat16 lds[3 * TILE];   // 48 KB -> 3 blocks/CU
    int t = threadIdx.x, w = t >> 6, ln = t & 63;
    int wr = w >> 1, wc = w & 1;
    int lr = ln & 15, q16 = ln >> 4;           // q16 in [0,4)
    int m0 = blockIdx.x * 128, n0 = blockIdx.y * 128;
    f32x4 acc[4][4] = {};
    int NT = K / 32;

    auto STAGE = [&](int buf, int kt) {
        int kb = kt * 32;
        char* ldsA = (char*)(lds + buf * TILE);    // A: 128 rows x 64 B
        char* ldsB = ldsA + 128 * 64;
        #pragma unroll
        for (int i = 0; i < 2; ++i) {
            int c = i * 256 + t;
            int row = c >> 2, q = c & 3;
            int slot = q ^ (row & 3);              // pre-swizzled SOURCE, linear dest
            gload_lds16(A + (size_t)(m0 + row) * K + kb + slot * 8,
                        ldsA + (i * 256 + w * 64) * 16);
        }
        #pragma unroll
        for (int i = 0; i < 2; ++i) {
            int c = i * 256 + t;
            int row = c >> 2, q = c & 3;
            int slot = q ^ (row & 3);
            gload_lds16(Bt + (size_t)(n0 + row) * K + kb + slot * 8,
                        ldsB + (i * 256 + w * 64) * 16);
        }
    };

    STAGE(0, 0);
    STAGE(1, 1);
    for (int kt = 0; kt < NT; ++kt) {
        if (kt + 1 < NT) asm volatile("s_waitcnt vmcnt(4)" ::: "memory");
        else             asm volatile("s_waitcnt vmcnt(0)" ::: "memory");
        __builtin_amdgcn_sched_barrier(0);
        __builtin_amdgcn_s_barrier();          // all waves: tile kt ready, kt-1 reads done
        __builtin_amdgcn_sched_barrier(0);
        if (kt + 2 < NT) STAGE((kt + 2) % 3, kt + 2);
        const __hip_bfloat16* As = lds + (kt % 3) * TILE;
        const __hip_bfloat16* Bs = As + 128 * 32;
        bf16x8 a[4], b[4];
        #pragma unroll
        for (int mi = 0; mi < 4; ++mi) {
            int row = wr * 64 + mi * 16 + lr;
            int s = q16 ^ (row & 3);               // swizzled READ (matches source)
            a[mi] = *(const bf16x8*)&As[row * 32 + s * 8];
        }
        #pragma unroll
        for (int ni = 0; ni < 4; ++ni) {
            int row = wc * 64 + ni * 16 + lr;
            int s = q16 ^ (row & 3);
            b[ni] = *(const bf16x8*)&Bs[row * 32 + s * 8];
        }
        __builtin_amdgcn_s_setprio(1);
        #pragma unroll
        for (int mi = 0; mi < 4; ++mi)
            #pragma unroll
            for (int ni = 0; ni < 4; ++ni)
                acc[mi][ni] = __builtin_amdgcn_mfma_f32_16x16x32_bf16(
                    a[mi], b[ni], acc[mi][ni], 0, 0, 0);
        __builtin_amdgcn_s_setprio(0);
    }
    int rb = q16 * 4;
    #pragma unroll
    for (int mi = 0; mi < 4; ++mi) {
        #pragma unroll
        for (int ni = 0; ni < 4; ++ni) {
            int col = n0 + wc * 64 + ni * 16 + lr;
            int rowb = m0 + wr * 64 + mi * 16 + rb;
            #pragma unroll
            for (int j = 0; j < 4; ++j) {
                float v = acc[mi][ni][j];
                size_t off = (size_t)(rowb + j) * N + col;
                if (EPI == 1) Cb[off] = __float2bfloat16(gelu_f(v));
                else C[off] = v;
            }
        }
    }
}

// ---------------- og: per (h,m) complex GEMM -> OGT[b][he][k=2m|2m+1] bf16 ---------------
__global__ __launch_bounds__(256) void k_og(const float* __restrict__ XGr,
        const float* __restrict__ XGi, const float2* __restrict__ WM,
        __hip_bfloat16* __restrict__ OGT) {
    int hm = blockIdx.x;      // h*32+m
    int t = threadIdx.x;
    __shared__ float2 sw[4096];
    __shared__ float sxr[2048], sxi[2048];
    const float2* w = WM + (size_t)hm * 4096;
    for (int i = t; i < 4096; i += 256) sw[i] = w[i];
    const float* xr = XGr + hm * 2048;
    const float* xi = XGi + hm * 2048;
    for (int i = t; i < 2048; i += 256) { sxr[i] = xr[i]; sxi[i] = xi[i]; }
    __syncthreads();
    int b = t >> 3, o0 = (t & 7) * 8;
    float ar[8] = {}, ai[8] = {};
    for (int e = 0; e < 64; ++e) {
        float xrv = sxr[e * 32 + b], xiv = sxi[e * 32 + b];
        #pragma unroll
        for (int j = 0; j < 8; ++j) {
            float2 wv = sw[e * 64 + o0 + j];
            ar[j] = fmaf(xrv, wv.x, fmaf(-xiv, wv.y, ar[j]));
            ai[j] = fmaf(xrv, wv.y, fmaf( xiv, wv.x, ai[j]));
        }
    }
    int h = hm >> 5, m = hm & 31;
    __hip_bfloat16* og = OGT + (size_t)b * (512 * 64);
    #pragma unroll
    for (int j = 0; j < 8; ++j) {
        int he = h * 64 + o0 + j;
        union { __hip_bfloat16 h2[2]; uint32_t u; } pk;
        pk.h2[0] = __float2bfloat16(ar[j]);
        pk.h2[1] = __float2bfloat16(ai[j]);
        *(uint32_t*)&og[he * 64 + 2 * m] = pk.u;
    }
}

// ---------------- new_x[b][he][dc] = OGT[b](512he x 64k) @ SWT^T + bo --------------------
__global__ __launch_bounds__(256) void k_nx(const __hip_bfloat16* __restrict__ OGT,
        const __hip_bfloat16* __restrict__ SWT, const float* __restrict__ bo,
        float* __restrict__ C) {
    __shared__ __hip_bfloat16 As[128 * 32];
    __shared__ __hip_bfloat16 Bs[128 * 32];
    int t = threadIdx.x;
    int m0 = blockIdx.x * 128, n0 = blockIdx.y * 128, b = blockIdx.z;
    int w = t >> 6, ln = t & 63;
    int wr = w >> 1, wc = w & 1;
    const __hip_bfloat16* ab = OGT + (size_t)b * 512 * 64;
    f32x4 acc[4][4] = {};
    for (int k0 = 0; k0 < 64; k0 += 32) {
        #pragma unroll
        for (int i = 0; i < 2; ++i) {
            int s = i * 256 + t;
            int row = s >> 2, q = s & 3;
            gload_lds16(ab + (size_t)(m0 + row) * 64 + k0 + q * 8,
                        (char*)As + i * 4096 + w * 1024);
            gload_lds16(SWT + (size_t)(n0 + row) * 64 + k0 + q * 8,
                        (char*)Bs + i * 4096 + w * 1024);
        }
        __syncthreads();
        bf16x8 af[4], bfr[4];
        int lr = ln & 15, kc = (ln >> 4) * 8;
        #pragma unroll
        for (int mi = 0; mi < 4; ++mi)
            af[mi] = *(const bf16x8*)&As[(wr * 64 + mi * 16 + lr) * 32 + kc];
        #pragma unroll
        for (int ni = 0; ni < 4; ++ni)
            bfr[ni] = *(const bf16x8*)&Bs[(wc * 64 + ni * 16 + lr) * 32 + kc];
        #pragma unroll
        for (int mi = 0; mi < 4; ++mi)
            #pragma unroll
            for (int ni = 0; ni < 4; ++ni)
                acc[mi][ni] = __builtin_amdgcn_mfma_f32_16x16x32_bf16(
                    af[mi], bfr[ni], acc[mi][ni], 0, 0, 0);
        __syncthreads();
    }
    int rb = (ln >> 4) * 4, cb = ln & 15;
    #pragma unroll
    for (int mi = 0; mi < 4; ++mi) {
        #pragma unroll
        for (int ni = 0; ni < 4; ++ni) {
            int col = n0 + wc * 64 + ni * 16 + cb;
            int he = m0 + wr * 64 + mi * 16 + rb;
            float bv = bo[col];
            #pragma unroll
            for (int j = 0; j < 4; ++j)
                C[((size_t)b * 512 + he + j) * 512 + col] = acc[mi][ni][j] + bv;
        }
    }
}

// ---------------- s = P + Q; out = s - movavg25(s); dual fp32+bf16, L-chunked ------------
__global__ void k_add_decomp(const float* __restrict__ P, const float* __restrict__ Q,
                             float* __restrict__ Out, __hip_bfloat16* __restrict__ Outb) {
    int b = blockIdx.x >> 3;
    int l0 = (blockIdx.x & 7) * 64;
    int d = threadIdx.x;
    const float* p = P + (size_t)b * LL * DD + d;
    const float* q = Q + (size_t)b * LL * DD + d;
    float* o = Out + (size_t)b * LL * DD + d;
    __hip_bfloat16* ob = Outb + (size_t)b * LL * DD + d;
    float sum = 0.f;
    for (int j = l0 - 12; j <= l0 + 12; ++j) {
        int jc = j < 0 ? 0 : (j > 511 ? 511 : j);
        sum += p[jc * DD] + q[jc * DD];
    }
    for (int l = l0; l < l0 + 64; ++l) {
        float sv = p[l * DD] + q[l * DD];
        float r = sv - sum * (1.0f / 25.0f);
        o[l * DD] = r;
        ob[l * DD] = __float2bfloat16(r);
        int lp = l + 13 > 511 ? 511 : l + 13;
        int lm = l - 12 < 0 ? 0 : l - 12;
        sum += (p[lp * DD] + q[lp * DD]) - (p[lm * DD] + q[lm * DD]);
    }
}

// ---------------- LayerNorm over D ----------------
__global__ void k_ln(const float* __restrict__ Xin, const float* __restrict__ lw,
                     const float* __restrict__ lb, float* __restrict__ Out) {
    int row = blockIdx.x;
    int t = threadIdx.x;
    const float4* x4 = (const float4*)(Xin + (size_t)row * DD);
    float4 v0 = x4[t], v1 = x4[t + 64];
    float s = v0.x + v0.y + v0.z + v0.w + v1.x + v1.y + v1.z + v1.w;
    #pragma unroll
    for (int o = 32; o; o >>= 1) s += __shfl_down(s, o);
    float mu = __shfl(s, 0) * (1.0f / 512.0f);
    float d0 = v0.x - mu, d1 = v0.y - mu, d2 = v0.z - mu, d3 = v0.w - mu;
    float d4 = v1.x - mu, d5 = v1.y - mu, d6 = v1.z - mu, d7 = v1.w - mu;
    float vs = d0*d0 + d1*d1 + d2*d2 + d3*d3 + d4*d4 + d5*d5 + d6*d6 + d7*d7;
    #pragma unroll
    for (int o = 32; o; o >>= 1) vs += __shfl_down(vs, o);
    float var = __shfl(vs, 0) * (1.0f / 512.0f);
    float rstd = rsqrtf(var + 1e-5f);
    float4 w0 = ((const float4*)lw)[t], w1 = ((const float4*)lw)[t + 64];
    float4 b0 = ((const float4*)lb)[t], b1 = ((const float4*)lb)[t + 64];
    float4 r0, r1;
    r0.x = d0 * rstd * w0.x + b0.x; r0.y = d1 * rstd * w0.y + b0.y;
    r0.z = d2 * rstd * w0.z + b0.z; r0.w = d3 * rstd * w0.w + b0.w;
    r1.x = d4 * rstd * w1.x + b1.x; r1.y = d5 * rstd * w1.y + b1.y;
    r1.z = d6 * rstd * w1.z + b1.z; r1.w = d7 * rstd * w1.w + b1.w;
    float4* o4 = (float4*)(Out + (size_t)row * DD);
    o4[t] = r0; o4[t + 64] = r1;
}

// ---------------- column (temporal) mean over L per (b,d): 256 blocks, 4-way L-split -----
__global__ void k_colmean(const float* __restrict__ A, float* __restrict__ CM) {
    int col0 = blockIdx.x * 64;
    int part = threadIdx.x >> 6;
    int cl = threadIdx.x & 63;
    int col = col0 + cl;
    int b = col >> 9, d = col & 511;
    const float* a = A + (size_t)b * LL * DD + d;
    float s = 0.f;
    for (int l = part * 128; l < part * 128 + 128; ++l) s += a[l * DD];
    __shared__ float red[4][64];
    red[part][cl] = s;
    __syncthreads();
    if (threadIdx.x < 64) {
        float v = red[0][cl] + red[1][cl] + red[2][cl] + red[3][cl];
        CM[col0 + cl] = v * (1.0f / 512.0f);
    }
}

// ---------------- final projection (gelu(A - CM) fused in) -------------------------------
__global__ __launch_bounds__(256) void k_proj_partial(const float* __restrict__ A,
        const float* __restrict__ CM, const float* __restrict__ PW,
        float* __restrict__ PP) {
    int b = blockIdx.x, c = blockIdx.y;
    int t = threadIdx.x;
    float acc[NCC] = {};
    const float* a = A + (size_t)b * LL * DD;
    const float* cm = CM + (b << 9);
    int i0 = c * 16384, i1 = i0 + 16384;
    for (int i = i0 + t; i < i1; i += 256) {
        float v = gelu_f(a[i] - cm[i & 511]);
        const float* w = PW + (size_t)i * NCC;
        #pragma unroll
        for (int n = 0; n < NCC; ++n) acc[n] = fmaf(v, w[n], acc[n]);
    }
    __shared__ float red[4][NCC];
    int lane = t & 63, wv = t >> 6;
    #pragma unroll
    for (int n = 0; n < NCC; ++n) {
        float s = acc[n];
        #pragma unroll
        for (int o = 32; o; o >>= 1) s += __shfl_down(s, o);
        if (lane == 0) red[wv][n] = s;
    }
    __syncthreads();
    if (t < NCC) {
        PP[(b * 16 + c) * NCC + t] = red[0][t] + red[1][t] + red[2][t] + red[3][t];
    }
}

__global__ void k_proj_final(const float* __restrict__ PP, const float* __restrict__ pb,
                             float* __restrict__ out) {
    int t = threadIdx.x;
    if (t >= BB * NCC) return;
    int b = t / NCC, n = t % NCC;
    float s = pb[n];
    for (int c = 0; c < 16; ++c) s += PP[(b * 16 + c) * NCC + n];
    out[t] = s;
}

// ---------------- numpy legacy RandomState(0) modes replication ----------------
static void compute_modes(int* out) {
    static uint32_t mt[624];
    uint32_t s = 0u;
    mt[0] = s;
    for (int i = 1; i < 624; ++i)
        mt[i] = 1812433253u * (mt[i - 1] ^ (mt[i - 1] >> 30)) + (uint32_t)i;
    int mti = 624;
    auto genrand = [&]() -> uint32_t {
        if (mti >= 624) {
            for (int k = 0; k < 624; ++k) {
                uint32_t y = (mt[k] & 0x80000000u) | (mt[(k + 1) % 624] & 0x7fffffffu);
                mt[k] = mt[(k + 397) % 624] ^ (y >> 1) ^ ((y & 1u) ? 2567483615u : 0u);
            }
            mti = 0;
        }
        uint32_t y = mt[mti++];
        y ^= y >> 11;
        y ^= (y << 7) & 2636928640u;
        y ^= (y << 15) & 4022730752u;
        y ^= y >> 18;
        return y;
    };
    int idx[256];
    for (int i = 0; i < 256; ++i) idx[i] = i;
    for (int i = 255; i >= 1; --i) {
        uint32_t mx = (uint32_t)i;
        uint32_t mask = mx;
        mask |= mask >> 1; mask |= mask >> 2; mask |= mask >> 4;
        mask |= mask >> 8; mask |= mask >> 16;
        uint32_t j;
        while ((j = (genrand() & mask)) > mx) {}
        int tmp = idx[i]; idx[i] = idx[j]; idx[j] = tmp;
    }
    int sel[NM];
    for (int i = 0; i < NM; ++i) sel[i] = idx[i];
    std::sort(sel, sel + NM);
    for (int i = 0; i < NM; ++i) out[i] = sel[i];
}

extern "C" void kernel_launch(void* const* d_in, const int* in_sizes, int n_in,
                              void* d_out, int out_size, void* d_ws, size_t ws_size,
                              hipStream_t stream) {
    const float* xe  = (const float*)d_in[0];
    const float* tw  = (const float*)d_in[1];
    const float* Wq  = (const float*)d_in[2];
    const float* bq  = (const float*)d_in[3];
    const float* Wo  = (const float*)d_in[8];
    const float* bo  = (const float*)d_in[9];
    const float* fwr = (const float*)d_in[10];
    const float* fwi = (const float*)d_in[11];
    const float* W1  = (const float*)d_in[12];
    const float* W2  = (const float*)d_in[13];
    const float* lw  = (const float*)d_in[14];
    const float* lb  = (const float*)d_in[15];
    const float* pw  = (const float*)d_in[16];
    const float* pb  = (const float*)d_in[17];
    float* out = (float*)d_out;

    const size_t NX = (size_t)BB * LL * DD;        // 8388608
    const size_t NHF = (size_t)BB * LL * NDFF;     // 33554432
    const size_t NXG = (size_t)BB * NH * EHH * NM; // 524288
    const size_t NWM = (size_t)NH * NM * EHH * EHH;// 1048576 float2

    char* wsb = (char*)d_ws;
    size_t off = 0;
    float* X1  = (float*)(wsb + off); off += NX * 4;
    float* X2  = (float*)(wsb + off); off += NX * 4;
    float* TB  = (float*)(wsb + off); off += NX * 4;
    float* XGr = (float*)(wsb + off); off += NXG * 4;
    float* XGi = (float*)(wsb + off); off += NXG * 4;
    __hip_bfloat16* X1b = (__hip_bfloat16*)(wsb + off); off += NX * 2;
    __hip_bfloat16* X2b = (__hip_bfloat16*)(wsb + off); off += NX * 2;
    __hip_bfloat16* HMb = (__hip_bfloat16*)(wsb + off); off += NHF * 2;
    __hip_bfloat16* WT  = (__hip_bfloat16*)(wsb + off); off += (size_t)DD * DD * 2;
    float2* WM          = (float2*)(wsb + off);         off += NWM * 8;
    __hip_bfloat16* TXb = (__hip_bfloat16*)(wsb + off); off += (size_t)BB * 64 * 512 * 2;
    __hip_bfloat16* Tb  = (__hip_bfloat16*)(wsb + off); off += (size_t)64 * 512 * 2;
    __hip_bfloat16* OGT = (__hip_bfloat16*)(wsb + off); off += (size_t)BB * 512 * 64 * 2;
    __hip_bfloat16* Sk  = (__hip_bfloat16*)(wsb + off); off += (size_t)64 * 512 * 2;
    __hip_bfloat16* WTq = (__hip_bfloat16*)(wsb + off); off += (size_t)NEL * DD * DD * 2;
    __hip_bfloat16* WT1 = (__hip_bfloat16*)(wsb + off); off += (size_t)NEL * DD * NDFF * 2;
    __hip_bfloat16* WT2 = (__hip_bfloat16*)(wsb + off); off += (size_t)NEL * NDFF * DD * 2;
    __hip_bfloat16* SW3 = (__hip_bfloat16*)(wsb + off); off += (size_t)NEL * DD * 64 * 2;
    float* PE           = (float*)(wsb + off);          off += (size_t)LL * DD * 4;
    if (ws_size < off) return;

    // XTb (16.8 MB) aliases TB (33.5 MB): TB is dead from layer start until k_nx writes it.
    __hip_bfloat16* XTb = (__hip_bfloat16*)TB;

    Modes mi;
    compute_modes(mi.v);

    // ---- upfront: PE table, embedding, twiddle/synthesis tables, ALL weight preps ----
    k_pegen<<<512, 256, 0, stream>>>(PE);
    k_embed<<<dim3(16, 2, BB), 256, 0, stream>>>(xe, tw, PE, X1, X1b);
    k_tgen<<<64, 64, 0, stream>>>(Tb, mi);
    k_sgen<<<64, 64, 0, stream>>>(Sk);
    for (int li = 0; li < NEL; ++li) {
        k_wt<<<dim3(16, 16), 256, 0, stream>>>(Wq + (size_t)li * DD * DD,
                                               WTq + (size_t)li * DD * DD, DD, DD);
        k_wt<<<dim3(64, 16), 256, 0, stream>>>(W1 + (size_t)li * DD * NDFF,
                                               WT1 + (size_t)li * DD * NDFF, DD, NDFF);
        k_wt<<<dim3(16, 64), 256, 0, stream>>>(W2 + (size_t)li * NDFF * DD,
                                               WT2 + (size_t)li * NDFF * DD, NDFF, DD);
        k_wt<<<dim3(16, 16), 256, 0, stream>>>(Wo + (size_t)li * DD * DD, WT, DD, DD);
        k_swt<<<4, 256, 0, stream>>>(Sk, WT, SW3 + (size_t)li * DD * 64);
    }

    float* cur = X1;            float* alt = X2;
    __hip_bfloat16* curb = X1b; __hip_bfloat16* altb = X2b;
    const int M = BB * LL;      // 16384

    for (int li = 0; li < NEL; ++li) {
        k_wfm<<<NH * EHH, 256, 0, stream>>>(fwr, fwi, WM, li);
        k_xt<<<dim3(8, 8, BB), 256, 0, stream>>>(cur, XTb);
        k_tx<<<dim3(BB, 4), 256, 0, stream>>>(Tb, XTb, TXb);
        k_xg<<<dim3(16, 4), 256, 0, stream>>>(TXb, WTq + (size_t)li * DD * DD,
                                              bq + li * DD, XGr, XGi, mi);
        k_og<<<NH * NM, 256, 0, stream>>>(XGr, XGi, WM, OGT);
        k_nx<<<dim3(4, 4, BB), 256, 0, stream>>>(OGT, SW3 + (size_t)li * DD * 64,
                                                 bo + li * DD, TB);
        k_add_decomp<<<BB * 8, DD, 0, stream>>>(cur, TB, alt, altb);
        { float* t_ = cur; cur = alt; alt = t_; }
        { __hip_bfloat16* t_ = curb; curb = altb; altb = t_; }
        // ---- FFN: 128x128 3-blk/CU counted-vmcnt MFMA GEMMs ----
        k_ffn<1><<<dim3(M / 128, NDFF / 128), 256, 0, stream>>>(
            curb, WT1 + (size_t)li * DD * NDFF, nullptr, HMb, M, NDFF, DD);
        k_ffn<2><<<dim3(M / 128, DD / 128), 256, 0, stream>>>(
            HMb, WT2 + (size_t)li * NDFF * DD, TB, nullptr, M, DD, NDFF);
        k_add_decomp<<<BB * 8, DD, 0, stream>>>(cur, TB, alt, altb);
        { float* t_ = cur; cur = alt; alt = t_; }
        { __hip_bfloat16* t_ = curb; curb = altb; altb = t_; }
    }

    // ---- final: LayerNorm -> temporal-mean -> fused gelu-sub projection ----
    k_ln<<<BB * LL, 64, 0, stream>>>(cur, lw, lb, TB);
    float* CM = XGr;
    float* PP = XGi;
    k_colmean<<<256, 256, 0, stream>>>(TB, CM);
    k_proj_partial<<<dim3(BB, 16), 256, 0, stream>>>(TB, CM, pw, PP);
    k_proj_final<<<1, 320, 0, stream>>>(PP, pb, out);
}